// Round 10
// baseline (322.441 us; speedup 1.0000x reference)
//
#include <hip/hip_runtime.h>
#include <hip/hip_bf16.h>
#include <cstdint>
#include <cstddef>

typedef unsigned short u16;
typedef unsigned char u8;
typedef long i64;
typedef __bf16 bf16x8 __attribute__((ext_vector_type(8)));
typedef float f32x4 __attribute__((ext_vector_type(4)));
typedef u16 u16x8 __attribute__((ext_vector_type(8)));
typedef u8 u8x16 __attribute__((ext_vector_type(16)));

#define NROWS 15360   // B*C = 512*30
#define KDIM 512
#define BDIM 512
#define CDIM 30
#define TDIM 3
#define EDIM 6

typedef __attribute__((address_space(1))) const unsigned int gu32;
typedef __attribute__((address_space(3))) unsigned int lu32;

__device__ __forceinline__ void gload16(const void* g, void* l) {
  __builtin_amdgcn_global_load_lds((gu32*)g, (lu32*)l, 16, 0, 0);
}

__device__ __forceinline__ float bf2f(u16 u) {
  union { unsigned i; float f; } v; v.i = ((unsigned)u) << 16; return v.f;
}
__device__ __forceinline__ u16 f2bf(float f) {
  union { float f; unsigned i; } v; v.f = f;
  unsigned r = v.i + 0x7fffu + ((v.i >> 16) & 1u);
  return (u16)(r >> 16);
}
// fp8 e4m3fn encode (software, round-nearest; no builtin dependency)
__device__ __forceinline__ u8 f2fp8(float v) {
  union { float f; unsigned u; } x; x.f = v;
  unsigned s = (x.u >> 24) & 0x80;
  x.u &= 0x7fffffffu;
  if (x.f < 0.0009765625f) return (u8)s;          // < 2^-10 -> 0
  if (x.f > 448.f) return (u8)(s | 0x7e);         // clamp to 448
  int e; float m = frexpf(x.f, &e);               // m in [0.5,1)
  if (e < -5) {                                   // subnormal, quantum 2^-9
    int qq = (int)(x.f * 512.f + 0.5f);           // <=8; q==8 encodes min-normal
    return (u8)(s | qq);
  }
  int qq = (int)(m * 16.f + 0.5f);                // in [8,16]
  if (qq == 16) { qq = 8; e++; }
  int E = e + 6;                                  // biased exp, 1..15
  if (E >= 16 || (E == 15 && qq - 8 == 7)) return (u8)(s | 0x7e);
  return (u8)(s | (E << 3) | (qq - 8));
}

// ---------------- merged prep ----------------
// bid 0..3839: cvt X fp32->bf16
// bid 3840..4927: weight tile; mids 8..13 -> fp8 W2q (x64 scale), others bf16 WT
// bid 4928..4959: gate weight col (WgT [32][512], cols 18..31 zero)
// bid 4960..5004: zero logits
__global__ __launch_bounds__(256) void prep_kernel(
    const float* __restrict__ X, u16* __restrict__ Xb,
    const float* __restrict__ fc1, const float* __restrict__ fc2,
    const float* __restrict__ ew1, const float* __restrict__ ew2,
    const float* __restrict__ tw1, u16* __restrict__ wt, u8* __restrict__ w2q,
    const float* __restrict__ wg, u16* __restrict__ WgT,
    float* __restrict__ logits) {
  int bid = blockIdx.x;
  if (bid < 3840) {
    int i = (bid * 256 + threadIdx.x) * 8;
    float4 a = *(const float4*)(X + i);
    float4 b = *(const float4*)(X + i + 4);
    u16x8 v;
    v[0] = f2bf(a.x); v[1] = f2bf(a.y); v[2] = f2bf(a.z); v[3] = f2bf(a.w);
    v[4] = f2bf(b.x); v[5] = f2bf(b.y); v[6] = f2bf(b.z); v[7] = f2bf(b.w);
    *(u16x8*)(Xb + i) = v;
  } else if (bid < 4928) {
    int id = bid - 3840;
    int mid = id >> 6, tile = id & 63;
    const float* src;
    if (mid == 0) src = fc1;
    else if (mid == 1) src = fc2;
    else if (mid < 8) src = ew1 + (size_t)(mid - 2) * 262144;
    else if (mid < 14) src = ew2 + (size_t)(mid - 8) * 262144;
    else src = tw1 + (size_t)(mid - 14) * 262144;
    int tr = (tile >> 3) * 64, tc = (tile & 7) * 64;
    __shared__ float t[64][65];
    int c = threadIdx.x & 63, r0 = threadIdx.x >> 6;
#pragma unroll
    for (int i = 0; i < 16; i++) {
      int r = r0 + i * 4;
      t[r][c] = src[(size_t)(tr + r) * 512 + tc + c];
    }
    __syncthreads();
    if (mid >= 8 && mid < 14) {
      u8* dq = w2q + (size_t)(mid - 8) * 262144;   // [col][k] fp8, x64 scale
#pragma unroll
      for (int i = 0; i < 16; i++) {
        int r = r0 + i * 4;
        dq[(size_t)(tc + r) * 512 + tr + c] = f2fp8(t[c][r] * 64.f);
      }
    } else {
      u16* dst = wt + (size_t)mid * 262144;
#pragma unroll
      for (int i = 0; i < 16; i++) {
        int r = r0 + i * 4;
        dst[(size_t)(tc + r) * 512 + tr + c] = f2bf(t[c][r]);
      }
    }
  } else if (bid < 4960) {
    int col = bid - 4928;
    for (int k = threadIdx.x; k < 512; k += 256) {
      u16 v = 0;
      if (col < 18) {
        int t = col / 6, e = col % 6;
        v = f2bf(wg[(size_t)(t * 512 + k) * 6 + e]);
      }
      WgT[(size_t)col * 512 + k] = v;
    }
  } else {
    int i = (bid - 4960) * 1024 + threadIdx.x * 4;
    float4 z; z.x = 0.f; z.y = 0.f; z.z = 0.f; z.w = 0.f;
    *(float4*)(logits + i) = z;
  }
}

// ===== W1: 128x256 triple-buffer bf16 GEMM, epilogue relu -> fp8(x16) eh =====
__global__ __launch_bounds__(512, 4) void gemm256(
    const u16* __restrict__ A,
    const u16* __restrict__ BT,
    const float* __restrict__ bias,
    u8* __restrict__ Cq,           // [15360][3072] fp8, x16 scale
    int nby) {
  int nwg = gridDim.x;
  int cpx = nwg >> 3;
  int bid = blockIdx.x;
  int swz = (bid & 7) * cpx + (bid >> 3);
  int bx = swz / nby, by = swz % nby;
  int brow = bx * 128, bcol = by * 256;

  __shared__ u16 SB[3][12288];

  int tid = threadIdx.x, lane = tid & 63, w = tid >> 6;
  int wm = w >> 2, wn = w & 3;
  int l = lane & 15, q = lane >> 4;

  int srow = tid >> 2;
  int sc = tid & 3;
  int srcc = sc ^ ((srow >> 1) & 3);
  const u16* AgR = A + (size_t)(brow + srow) * KDIM + srcc * 8;
  const u16* BgR0 = BT + (size_t)(bcol + srow) * KDIM + srcc * 8;
  const u16* BgR1 = BgR0 + 128 * KDIM;
  int lo = w * 512;

#define STAGE256(buf, kt)                              \
  do {                                                 \
    int _ko = (kt) * 32;                               \
    gload16(AgR + _ko, (buf) + lo);                    \
    gload16(BgR0 + _ko, (buf) + 4096 + lo);            \
    gload16(BgR1 + _ko, (buf) + 8192 + lo);            \
  } while (0)

  f32x4 zero; zero[0] = 0.f; zero[1] = 0.f; zero[2] = 0.f; zero[3] = 0.f;
  f32x4 acc[4][4];
#pragma unroll
  for (int m = 0; m < 4; m++)
#pragma unroll
    for (int n = 0; n < 4; n++) acc[m][n] = zero;

  int rca = q ^ ((l >> 1) & 3);
  int arow = wm * 64 + l;
  int bro = wn * 64 + l;

  STAGE256(SB[0], 0);
  STAGE256(SB[1], 1);
  asm volatile("s_waitcnt vmcnt(3)" ::: "memory");
  __builtin_amdgcn_s_barrier();

  u16 *bc = SB[0], *bn = SB[1], *bq = SB[2];
#pragma unroll
  for (int kt = 0; kt < 16; ++kt) {
    if (kt < 14) STAGE256(bq, kt + 2);
    bf16x8 bfv[4];
#pragma unroll
    for (int n = 0; n < 4; n++)
      bfv[n] = *(const bf16x8*)&bc[4096 + (bro + n * 16) * 32 + rca * 8];
    __builtin_amdgcn_s_setprio(1);
#pragma unroll
    for (int m = 0; m < 4; m++) {
      bf16x8 af = *(const bf16x8*)&bc[(arow + m * 16) * 32 + rca * 8];
#pragma unroll
      for (int n = 0; n < 4; n++)
        acc[m][n] = __builtin_amdgcn_mfma_f32_16x16x32_bf16(af, bfv[n], acc[m][n], 0, 0, 0);
    }
    __builtin_amdgcn_s_setprio(0);
    asm volatile("s_waitcnt lgkmcnt(0)" ::: "memory");
    if (kt < 14)
      asm volatile("s_waitcnt vmcnt(3)" ::: "memory");
    else
      asm volatile("s_waitcnt vmcnt(0)" ::: "memory");
    __builtin_amdgcn_s_barrier();
    u16* t_ = bc; bc = bn; bn = bq; bq = t_;
  }
#undef STAGE256

  // epilogue: relu, x16, fp8 -> LDS u8 (stride 264) -> coalesced 16B stores
  int colL = wn * 64 + l;
  u8* S8 = (u8*)&SB[0][0];   // 128*264 = 33792 B < 73728
  float bvs[4];
#pragma unroll
  for (int n = 0; n < 4; n++) bvs[n] = bias[bcol + colL + n * 16];
#pragma unroll
  for (int m = 0; m < 4; m++) {
    int rl = wm * 64 + m * 16 + q * 4;
#pragma unroll
    for (int n = 0; n < 4; n++) {
#pragma unroll
      for (int rr = 0; rr < 4; rr++) {
        float v = fmaxf(acc[m][n][rr] + bvs[n], 0.f) * 16.f;
        S8[(rl + rr) * 264 + colL + n * 16] = f2fp8(v);
      }
    }
  }
  __syncthreads();
  int row = tid >> 2, cc = tid & 3;
#pragma unroll
  for (int j = 0; j < 4; j++)
    *(u8x16*)&Cq[(size_t)(brow + row) * 3072 + bcol + cc * 64 + j * 16] =
        *(const u8x16*)&S8[row * 264 + cc * 64 + j * 16];
}

// ===== fused W2 + gated combine, fp8: y[t][r] = sum_e g*(ehq_e[r]@W2q_e/1024 + b2) =====
// BM=64, BN=128, 256 thr = 4 waves (1M x 4N), wave tile 64x32. BK=64 fp8 -> 48 K-steps.
// LDS: 3 bufs x (A 64x64B + B 128x64B = 12KB) + bf16 gates. Chunk-XOR swizzle on 16B.
// launch_bounds MUST stay (256,2): (256,4) caps VGPR at 64 -> accumulator spill (R8).
__global__ __launch_bounds__(256, 2) void gemm_w2c(
    const u8* __restrict__ eh,       // [15360][3072] fp8 (x16)
    const u8* __restrict__ W2q,      // [6][512 col][512 k] fp8 (x64)
    const float* __restrict__ eb2,   // [6][512]
    const float* __restrict__ gates, // [(b*3+t)*30+c][6]
    u16* __restrict__ y) {           // [3][15360][512] bf16
  int nwg = gridDim.x, cpx = nwg >> 3;
  int bid = blockIdx.x;
  int swz = (bid & 7) * cpx + (bid >> 3);
  int bx = swz >> 2, by = swz & 3;
  int brow = bx * 64, bcol = by * 128;

  __shared__ u8 SB8[3][12288];       // per buf: A 0..4095 (64x64B), B 4096..12287 (128x64B)
  __shared__ u16 glds[64 * 18];

  int tid = threadIdx.x, lane = tid & 63, w = tid >> 6;
  int l = lane & 15, q = lane >> 4;

  for (int i = tid; i < 64 * 18; i += 256) {
    int r = i / 18, te = i % 18;
    int gr = brow + r, b = gr / CDIM, c = gr % CDIM;
    int t = te / 6, e = te % 6;
    glds[i] = f2bf(gates[((size_t)(b * TDIM + t) * CDIM + c) * EDIM + e]);
  }
  float b2all[2][6];
#pragma unroll
  for (int ni = 0; ni < 2; ni++) {
    int col = bcol + w * 32 + ni * 16 + l;
#pragma unroll
    for (int e = 0; e < 6; e++) b2all[ni][e] = eb2[e * 512 + col];
  }

  int srow = tid >> 2, sc = tid & 3;
  int scA = sc ^ (srow & 3);
  const u8* Ag = eh + (size_t)(brow + srow) * 3072 + scA * 16;
  const u8* Bg0 = W2q + (size_t)(bcol + srow) * 512 + scA * 16;
  const u8* Bg1 = Bg0 + (size_t)64 * 512;
  int lo = w * 1024;

#define STAGEW(buf, s2)                                                   \
  do {                                                                    \
    int _e2 = (s2) >> 3, _k2 = (s2) & 7;                                  \
    gload16(Ag + _e2 * 512 + _k2 * 64, (buf) + lo);                       \
    gload16(Bg0 + (size_t)_e2 * 262144 + _k2 * 64, (buf) + 4096 + lo);    \
    gload16(Bg1 + (size_t)_e2 * 262144 + _k2 * 64, (buf) + 8192 + lo);    \
  } while (0)

  f32x4 P[4][2], aY0[4][2], aY1[4][2], aY2[4][2];
#pragma unroll
  for (int mi = 0; mi < 4; mi++)
#pragma unroll
    for (int ni = 0; ni < 2; ni++) {
      P[mi][ni][0] = P[mi][ni][1] = P[mi][ni][2] = P[mi][ni][3] = 0.f;
      aY0[mi][ni] = P[mi][ni]; aY1[mi][ni] = P[mi][ni]; aY2[mi][ni] = P[mi][ni];
    }

  STAGEW(SB8[0], 0);
  STAGEW(SB8[1], 1);
  asm volatile("s_waitcnt vmcnt(3)" ::: "memory");
  __builtin_amdgcn_s_barrier();

  u8 *bc = SB8[0], *bn = SB8[1], *bq = SB8[2];
  for (int e = 0; e < 6; ++e) {
#pragma unroll
    for (int kt = 0; kt < 8; ++kt) {
      int s = e * 8 + kt;
      if (s < 46) STAGEW(bq, s + 2);
#pragma unroll
      for (int ks = 0; ks < 2; ++ks) {
        int cidx = ks * 2 + (q >> 1);
        int obyte = (q & 1) * 8;
        i64 bfv[2];
#pragma unroll
        for (int ni = 0; ni < 2; ni++) {
          int col = w * 32 + ni * 16 + l;
          bfv[ni] = *(const i64*)&bc[4096 + col * 64 + ((cidx ^ (col & 3)) * 16 + obyte)];
        }
        __builtin_amdgcn_s_setprio(1);
#pragma unroll
        for (int mi = 0; mi < 4; mi++) {
          int row = mi * 16 + l;
          i64 af = *(const i64*)&bc[row * 64 + ((cidx ^ (row & 3)) * 16 + obyte)];
#pragma unroll
          for (int ni = 0; ni < 2; ni++)
            P[mi][ni] = __builtin_amdgcn_mfma_f32_16x16x32_fp8_fp8(af, bfv[ni], P[mi][ni], 0, 0, 0);
        }
        __builtin_amdgcn_s_setprio(0);
      }
      asm volatile("s_waitcnt lgkmcnt(0)" ::: "memory");
      if (s < 46)
        asm volatile("s_waitcnt vmcnt(3)" ::: "memory");
      else
        asm volatile("s_waitcnt vmcnt(0)" ::: "memory");
      __builtin_amdgcn_s_barrier();
      u8* t_ = bc; bc = bn; bn = bq; bq = t_;
    }
    // expert boundary: descale (1/1024 = 1/(16*64)), add bias, fold with gates
#pragma unroll
    for (int mi = 0; mi < 4; mi++) {
#pragma unroll
      for (int rr = 0; rr < 4; rr++) {
        int row = mi * 16 + q * 4 + rr;
        float g0 = bf2f(glds[row * 18 + e]);
        float g1 = bf2f(glds[row * 18 + 6 + e]);
        float g2 = bf2f(glds[row * 18 + 12 + e]);
#pragma unroll
        for (int ni = 0; ni < 2; ni++) {
          float p = P[mi][ni][rr] * 9.765625e-4f + b2all[ni][e];
          aY0[mi][ni][rr] += g0 * p;
          aY1[mi][ni][rr] += g1 * p;
          aY2[mi][ni][rr] += g2 * p;
          P[mi][ni][rr] = 0.f;
        }
      }
    }
  }
#undef STAGEW

  // epilogue: per task, acc -> LDS (stride 136 u16) -> coalesced u16x8 stores
  u16* Sst = (u16*)&SB8[0][0];
#define EPI(AY, t)                                                          \
  do {                                                                      \
    _Pragma("unroll") for (int mi = 0; mi < 4; mi++)                        \
      _Pragma("unroll") for (int ni = 0; ni < 2; ni++)                      \
        _Pragma("unroll") for (int rr = 0; rr < 4; rr++)                    \
          Sst[(mi * 16 + q * 4 + rr) * 136 + w * 32 + ni * 16 + l] =        \
              f2bf(AY[mi][ni][rr]);                                         \
    __syncthreads();                                                        \
    {                                                                       \
      int row_ = tid >> 2, cc_ = tid & 3;                                   \
      _Pragma("unroll") for (int j = 0; j < 4; j++)                         \
        *(u16x8*)&y[((size_t)(t) * NROWS + brow + row_) * 512 + bcol +      \
                    cc_ * 32 + j * 8] =                                     \
            *(const u16x8*)&Sst[row_ * 136 + cc_ * 32 + j * 8];             \
    }                                                                       \
    __syncthreads();                                                        \
  } while (0)
  EPI(aY0, 0);
  EPI(aY1, 1);
  EPI(aY2, 2);
#undef EPI
}

// ---------------- tower GEMM (128^2 m97-structure) + fused dot(tw2) -> logits ----
__global__ __launch_bounds__(256, 2) void gemm_tower(
    const u16* __restrict__ yin, const u16* __restrict__ WTt,
    const float* __restrict__ tb1, const float* __restrict__ tw2,
    float* __restrict__ logits) {
  int t = blockIdx.z;
  const u16* A = yin + (size_t)t * NROWS * KDIM;
  const u16* BT = WTt + (size_t)t * 262144;
  const float* bias = tb1 + t * 512;

  __shared__ u16 Al[128 * 32];
  __shared__ u16 Bl[128 * 32];
  int tid = threadIdx.x, lane = tid & 63, w = tid >> 6;
  int wr = w >> 1, wc = w & 1;
  int brow = blockIdx.x * 128, bcol = blockIdx.y * 128;

  int srow = tid >> 2;
  int schunk = tid & 3;
  int srcc = schunk ^ ((srow >> 1) & 3);
  const u16* Ag0 = A + (size_t)(brow + srow) * KDIM + srcc * 8;
  const u16* Ag1 = A + (size_t)(brow + srow + 64) * KDIM + srcc * 8;
  const u16* Bg0 = BT + (size_t)(bcol + srow) * KDIM + srcc * 8;
  const u16* Bg1 = BT + (size_t)(bcol + srow + 64) * KDIM + srcc * 8;
  u16* Ald0 = Al + w * 512;
  u16* Ald1 = Al + 2048 + w * 512;
  u16* Bld0 = Bl + w * 512;
  u16* Bld1 = Bl + 2048 + w * 512;

  f32x4 zero; zero[0] = 0.f; zero[1] = 0.f; zero[2] = 0.f; zero[3] = 0.f;
  f32x4 acc[4][4];
#pragma unroll
  for (int m = 0; m < 4; m++)
#pragma unroll
    for (int n = 0; n < 4; n++) acc[m][n] = zero;

  int l = lane & 15, q = lane >> 4;
  int rc = q ^ ((l >> 1) & 3);
  int rbase = wr * 64 + l;
  int cbase = wc * 64 + l;

  for (int kt = 0; kt < 16; ++kt) {
    int ko = kt * 32;
    gload16(Ag0 + ko, Ald0);
    gload16(Ag1 + ko, Ald1);
    gload16(Bg0 + ko, Bld0);
    gload16(Bg1 + ko, Bld1);
    __syncthreads();
    bf16x8 af[4], bfr[4];
#pragma unroll
    for (int m = 0; m < 4; m++) af[m] = *(const bf16x8*)&Al[(rbase + m * 16) * 32 + rc * 8];
#pragma unroll
    for (int n = 0; n < 4; n++) bfr[n] = *(const bf16x8*)&Bl[(cbase + n * 16) * 32 + rc * 8];
#pragma unroll
    for (int m = 0; m < 4; m++)
#pragma unroll
      for (int n = 0; n < 4; n++)
        acc[m][n] = __builtin_amdgcn_mfma_f32_16x16x32_bf16(af[m], bfr[n], acc[m][n], 0, 0, 0);
    __syncthreads();
  }

  int col0 = bcol + wc * 64 + l;
  float bvs[4], tws[4];
#pragma unroll
  for (int n = 0; n < 4; n++) {
    int col = col0 + n * 16;
    bvs[n] = bias[col];
    tws[n] = tw2[t * 512 + col];
  }
  int row0 = brow + wr * 64 + q * 4;
#pragma unroll
  for (int m = 0; m < 4; m++) {
#pragma unroll
    for (int r = 0; r < 4; r++) {
      float s = 0.f;
#pragma unroll
      for (int n = 0; n < 4; n++) {
        float v = acc[m][n][r] + bvs[n];
        v = fmaxf(v, 0.f);
        s += v * tws[n];
      }
      s += __shfl_xor(s, 1, 64);
      s += __shfl_xor(s, 2, 64);
      s += __shfl_xor(s, 4, 64);
      s += __shfl_xor(s, 8, 64);
      if (l == 0) {
        int row = row0 + m * 16 + r;
        int b = row / CDIM, c = row % CDIM;
        atomicAdd(&logits[(size_t)(b * TDIM + t) * CDIM + c], s);
      }
    }
  }
}

// ---------------- bf16 MFMA GEMM (m97 structure, 128^2) for fc1/fc2 ----
template <int RELU>
__global__ __launch_bounds__(256, 2) void gemm_bt(
    const u16* __restrict__ A, int lda,
    const u16* __restrict__ BT,
    const float* __restrict__ bias,
    u16* __restrict__ C, int ldc) {
  __shared__ u16 S[8448];
  u16* Al = S;
  u16* Bl = S + 4096;
  int tid = threadIdx.x, lane = tid & 63, w = tid >> 6;
  int wr = w >> 1, wc = w & 1;
  int brow = blockIdx.x * 128, bcol = blockIdx.y * 128;

  int srow = tid >> 2;
  int schunk = tid & 3;
  int srcc = schunk ^ ((srow >> 1) & 3);
  const u16* Ag0 = A + (size_t)(brow + srow) * lda + srcc * 8;
  const u16* Ag1 = A + (size_t)(brow + srow + 64) * lda + srcc * 8;
  const u16* Bg0 = BT + (size_t)(bcol + srow) * KDIM + srcc * 8;
  const u16* Bg1 = BT + (size_t)(bcol + srow + 64) * KDIM + srcc * 8;
  u16* Ald0 = Al + w * 512;
  u16* Ald1 = Al + 2048 + w * 512;
  u16* Bld0 = Bl + w * 512;
  u16* Bld1 = Bl + 2048 + w * 512;

  f32x4 zero; zero[0] = 0.f; zero[1] = 0.f; zero[2] = 0.f; zero[3] = 0.f;
  f32x4 acc[4][4];
#pragma unroll
  for (int m = 0; m < 4; m++)
#pragma unroll
    for (int n = 0; n < 4; n++) acc[m][n] = zero;

  int l = lane & 15, q = lane >> 4;
  int rc = q ^ ((l >> 1) & 3);
  int rbase = wr * 64 + l;
  int cbase = wc * 64 + l;

  for (int kt = 0; kt < 16; ++kt) {
    int ko = kt * 32;
    gload16(Ag0 + ko, Ald0);
    gload16(Ag1 + ko, Ald1);
    gload16(Bg0 + ko, Bld0);
    gload16(Bg1 + ko, Bld1);
    __syncthreads();
    bf16x8 af[4], bfr[4];
#pragma unroll
    for (int m = 0; m < 4; m++) af[m] = *(const bf16x8*)&Al[(rbase + m * 16) * 32 + rc * 8];
#pragma unroll
    for (int n = 0; n < 4; n++) bfr[n] = *(const bf16x8*)&Bl[(cbase + n * 16) * 32 + rc * 8];
#pragma unroll
    for (int m = 0; m < 4; m++)
#pragma unroll
      for (int n = 0; n < 4; n++)
        acc[m][n] = __builtin_amdgcn_mfma_f32_16x16x32_bf16(af[m], bfr[n], acc[m][n], 0, 0, 0);
    __syncthreads();
  }

  int colL = wc * 64 + l;
  float bvs[4];
#pragma unroll
  for (int n = 0; n < 4; n++) bvs[n] = bias[bcol + colL + n * 16];
#pragma unroll
  for (int half = 0; half < 2; half++) {
    if (wr == half) {
#pragma unroll
      for (int m = 0; m < 4; m++) {
        int rl = m * 16 + q * 4;
#pragma unroll
        for (int n = 0; n < 4; n++) {
#pragma unroll
          for (int rr = 0; rr < 4; rr++) {
            float v = acc[m][n][rr] + bvs[n];
            if (RELU) v = fmaxf(v, 0.f);
            S[(rl + rr) * 132 + colL + n * 16] = f2bf(v);
          }
        }
      }
    }
    __syncthreads();
    int row = tid >> 2, cc = tid & 3;
#pragma unroll
    for (int j = 0; j < 4; j++)
      *(u16x8*)&C[(size_t)(brow + half * 64 + row) * ldc + bcol + cc * 32 + j * 8] =
          *(const u16x8*)&S[row * 132 + cc * 32 + j * 8];
    __syncthreads();
  }
}

// ---------------- gate: MFMA skinny GEMM [64 rows/block x 32] + top3 softmax ----
__global__ __launch_bounds__(256) void gate_kernel(const u16* __restrict__ h,
                                                   const u16* __restrict__ WgT,
                                                   float* __restrict__ gates) {
  __shared__ u16 Wl[16 * 32 * 32];
  __shared__ float Gl[4][16][33];
  int tid = threadIdx.x, lane = tid & 63, w = tid >> 6;
  int l = lane & 15, q = lane >> 4;

  for (int idx = tid; idx < 2048; idx += 256) {
    int kt = idx >> 7, col = (idx >> 2) & 31, c = idx & 3;
    int sc = c ^ ((col >> 1) & 3);
    *(u16x8*)&Wl[kt * 1024 + col * 32 + c * 8] =
        *(const u16x8*)&WgT[(size_t)col * 512 + kt * 32 + sc * 8];
  }
  __syncthreads();

  int r = blockIdx.x * 64 + w * 16 + l;
  int ch = q ^ ((l >> 1) & 3);

  f32x4 acc0, acc1;
  acc0[0] = acc0[1] = acc0[2] = acc0[3] = 0.f;
  acc1 = acc0;
#pragma unroll
  for (int kt = 0; kt < 16; ++kt) {
    bf16x8 av = *(const bf16x8*)&h[(size_t)r * 512 + kt * 32 + q * 8];
    bf16x8 b0 = *(const bf16x8*)&Wl[kt * 1024 + l * 32 + ch * 8];
    bf16x8 b1 = *(const bf16x8*)&Wl[kt * 1024 + (16 + l) * 32 + ch * 8];
    acc0 = __builtin_amdgcn_mfma_f32_16x16x32_bf16(av, b0, acc0, 0, 0, 0);
    acc1 = __builtin_amdgcn_mfma_f32_16x16x32_bf16(av, b1, acc1, 0, 0, 0);
  }

#pragma unroll
  for (int rr = 0; rr < 4; rr++) {
    Gl[w][q * 4 + rr][l] = acc0[rr];
    Gl[w][q * 4 + rr][16 + l] = acc1[rr];
  }
  __syncthreads();

  if (lane < 16) {
    int R = blockIdx.x * 64 + w * 16 + lane;
    int b = R / CDIM, c = R % CDIM;
    for (int t = 0; t < 3; t++) {
      float g[6];
#pragma unroll
      for (int e = 0; e < 6; e++) g[e] = Gl[w][lane][t * 6 + e];
      float out[6] = {0, 0, 0, 0, 0, 0};
      int idx[3]; float val[3];
      unsigned used = 0;
      for (int kk = 0; kk < 3; kk++) {
        int best = 0; float bv = -1e30f;
        for (int e = 0; e < 6; e++)
          if (!((used >> e) & 1) && g[e] > bv) { bv = g[e]; best = e; }
        used |= 1u << best; idx[kk] = best; val[kk] = bv;
      }
      float mx = val[0];
      float s = 0.f, ex[3];
      for (int kk = 0; kk < 3; kk++) { ex[kk] = expf(val[kk] - mx); s += ex[kk]; }
      for (int kk = 0; kk < 3; kk++) out[idx[kk]] = ex[kk] / s;
      float* gp = &gates[(size_t)((b * TDIM + t) * CDIM + c) * EDIM];
      for (int e = 0; e < 6; e++) gp[e] = out[e];
    }
  }
}

// ---------------- loss: one wave per b ----------------
__global__ __launch_bounds__(64) void loss_kernel(const float* __restrict__ scores,
                                                  const float* __restrict__ logits,
                                                  const float* __restrict__ gates,
                                                  const float* __restrict__ tb2,
                                                  float* __restrict__ out) {
  int b = blockIdx.x;
  int lane = threadIdx.x;
  float bce_sum = 0.f;
  float aux = 0.f;
  for (int t = 0; t < 3; t++) {
    float sc = (lane < CDIM) ? scores[(size_t)(b * TDIM + t) * CDIM + lane] : -1e30f;
    float mx = sc;
    for (int off = 32; off; off >>= 1) mx = fmaxf(mx, __shfl_xor(mx, off, 64));
    float lab = (lane < CDIM && sc == mx) ? 1.f : 0.f;
    float lg = (lane < CDIM) ? (logits[(size_t)(b * TDIM + t) * CDIM + lane] + tb2[t]) : 0.f;
    float bce = (lane < CDIM) ? (fmaxf(lg, 0.f) - lg * lab + log1pf(expf(-fabsf(lg)))) : 0.f;
    for (int off = 32; off; off >>= 1) bce += __shfl_xor(bce, off, 64);
    bce_sum += bce / (float)CDIM;

    float impv[6];
    float meansum = 0.f;
#pragma unroll
    for (int e = 0; e < 6; e++) {
      float gsum = (lane < CDIM) ? gates[(size_t)((b * TDIM + t) * CDIM + lane) * EDIM + e] : 0.f;
      for (int off = 32; off; off >>= 1) gsum += __shfl_xor(gsum, off, 64);
      impv[e] = gsum;
      meansum += gsum;
    }
    float mean = meansum / 6.f;
    float var = 0.f;
#pragma unroll
    for (int e = 0; e < 6; e++) { float d = impv[e] - mean; var += d * d; }
    var /= 6.f;
    aux += var / (mean * mean + 1e-10f);
  }
  float res = bce_sum / 3.f + 0.01f * aux;
  if (lane == 0) atomicAdd(out, res / (float)BDIM);
}

// ---------------- host ----------------
extern "C" void kernel_launch(void* const* d_in, const int* in_sizes, int n_in,
                              void* d_out, int out_size, void* d_ws, size_t ws_size,
                              hipStream_t stream) {
  const float* X = (const float*)d_in[0];
  const float* scores = (const float*)d_in[1];
  const float* fc1_w = (const float*)d_in[2];
  const float* fc1_b = (const float*)d_in[3];
  const float* fc2_w = (const float*)d_in[4];
  const float* fc2_b = (const float*)d_in[5];
  const float* w_gate = (const float*)d_in[6];
  const float* ew1 = (const float*)d_in[7];
  const float* eb1 = (const float*)d_in[8];
  const float* ew2 = (const float*)d_in[9];
  const float* eb2 = (const float*)d_in[10];
  const float* tw1 = (const float*)d_in[11];
  const float* tb1 = (const float*)d_in[12];
  const float* tw2 = (const float*)d_in[13];
  const float* tb2 = (const float*)d_in[14];
  float* out = (float*)d_out;

  // workspace layout (u16 elements unless noted)
  u16* WT = (u16*)d_ws;                          // 17*262144 (slots 8..13 hold w2q fp8)
  u8* w2q = (u8*)(WT + (size_t)8 * 262144);      // 6*262144 u8 (inside slots 8..10)
  u16* WgT = WT + (size_t)17 * 262144;           // 32*512
  u16* ehall = WgT + (size_t)32 * 512;           // region: 15360*3072 u16 worth
  u8* ehq = (u8*)ehall;                          // [15360][3072] fp8 (47 MB)
  u16* Xb = ehall + (size_t)NROWS * 1536;        // bf16 X, in unused upper half of region
  u16* A1 = Xb + (size_t)NROWS * 512;            // dead after fc2
  u16* h = ehall + (size_t)NROWS * 3072;         // 15360*512 bf16
  u16* y = h + (size_t)NROWS * 512;              // 3*15360*512 bf16
  float* gates = (float*)(y + (size_t)TDIM * NROWS * 512);
  float* logits = gates + (size_t)BDIM * TDIM * CDIM * EDIM;

  hipMemsetAsync(d_out, 0, sizeof(float) * out_size, stream);

  // merged prep: cvt X + transpose weights (W2 -> fp8 x64) + gate prep + zero logits
  prep_kernel<<<5005, 256, 0, stream>>>(X, Xb, fc1_w, fc2_w, ew1, ew2, tw1, WT, w2q,
                                        w_gate, WgT, logits);

  // shared bottom (128^2, N=512)
  gemm_bt<1><<<dim3(120, 4), 256, 0, stream>>>(Xb, 512, WT + (size_t)0 * 262144, fc1_b, A1, 512);
  gemm_bt<0><<<dim3(120, 4), 256, 0, stream>>>(A1, 512, WT + (size_t)1 * 262144, fc2_b, h, 512);

  // gating
  gate_kernel<<<240, 256, 0, stream>>>(h, WgT, gates);

  // experts W1: merged N=3072, relu -> fp8 eh (1440 blocks of 128x256)
  gemm256<<<dim3(1440, 1, 1), 512, 0, stream>>>(h, WT + (size_t)2 * 262144, eb1, ehq, 12);

  // experts W2 + gated combine, fp8 (960 blocks of 64x128, 48 K-steps)
  gemm_w2c<<<dim3(960, 1, 1), 256, 0, stream>>>(ehq, w2q, eb2, gates, y);

  // towers: 128^2 + fused tw2-dot epilogue -> logits (atomic), z = task
  gemm_tower<<<dim3(120, 4, 3), 256, 0, stream>>>(y, WT + (size_t)14 * 262144, tb1, tw2, logits);

  // loss
  loss_kernel<<<BDIM, 64, 0, stream>>>(scores, logits, gates, tb2, out);
}

// Round 11
// 245.266 us; speedup vs baseline: 1.3147x; 1.3147x over previous
//
#include <hip/hip_runtime.h>
#include <hip/hip_bf16.h>
#include <cstdint>
#include <cstddef>

typedef unsigned short u16;
typedef unsigned char u8;
typedef long i64;
typedef __bf16 bf16x8 __attribute__((ext_vector_type(8)));
typedef float f32x4 __attribute__((ext_vector_type(4)));
typedef u16 u16x8 __attribute__((ext_vector_type(8)));
typedef u8 u8x16 __attribute__((ext_vector_type(16)));
typedef i64 i64x2 __attribute__((ext_vector_type(2)));

#define NROWS 15360   // B*C = 512*30
#define KDIM 512
#define BDIM 512
#define CDIM 30
#define TDIM 3
#define EDIM 6

typedef __attribute__((address_space(1))) const unsigned int gu32;
typedef __attribute__((address_space(3))) unsigned int lu32;

__device__ __forceinline__ void gload16(const void* g, void* l) {
  __builtin_amdgcn_global_load_lds((gu32*)g, (lu32*)l, 16, 0, 0);
}

__device__ __forceinline__ float bf2f(u16 u) {
  union { unsigned i; float f; } v; v.i = ((unsigned)u) << 16; return v.f;
}
__device__ __forceinline__ u16 f2bf(float f) {
  union { float f; unsigned i; } v; v.f = f;
  unsigned r = v.i + 0x7fffu + ((v.i >> 16) & 1u);
  return (u16)(r >> 16);
}
// fp8 e4m3fn encode, software fallback
__device__ __forceinline__ u8 f2fp8_sw(float v) {
  union { float f; unsigned u; } x; x.f = v;
  unsigned s = (x.u >> 24) & 0x80;
  x.u &= 0x7fffffffu;
  if (x.f < 0.0009765625f) return (u8)s;
  if (x.f > 448.f) return (u8)(s | 0x7e);
  int e; float m = frexpf(x.f, &e);
  if (e < -5) {
    int qq = (int)(x.f * 512.f + 0.5f);
    return (u8)(s | qq);
  }
  int qq = (int)(m * 16.f + 0.5f);
  if (qq == 16) { qq = 8; e++; }
  int E = e + 6;
  if (E >= 16 || (E == 15 && qq - 8 == 7)) return (u8)(s | 0x7e);
  return (u8)(s | (E << 3) | (qq - 8));
}
// packed HW encode: 2 floats -> 2 fp8 bytes (low, high)
__device__ __forceinline__ unsigned cvt2fp8(float a, float b) {
#if __has_builtin(__builtin_amdgcn_cvt_pk_fp8_f32)
  return (unsigned)__builtin_amdgcn_cvt_pk_fp8_f32(a, b, 0, false) & 0xffffu;
#else
  return (unsigned)f2fp8_sw(a) | ((unsigned)f2fp8_sw(b) << 8);
#endif
}
// within-64B-group byte permutation: interleave the two 32B k-halves in 8B granules
// so lane(q)'s 16B granule = {ks0 bytes q*8..+8} ++ {ks1 bytes q*8..+8}
__device__ __forceinline__ int permpos(int j) {
  return ((j & 24) << 1) + ((j & 32) >> 2) + (j & 7);
}

// ---------------- merged prep ----------------
// bid 0..3839: cvt X fp32->bf16
// bid 3840..4927: weight tile; mids 8..13 -> fp8 W2q (x64, byte-permuted), others bf16
// bid 4928..4959: gate weight col (WgT [32][512], cols 18..31 zero)
// bid 4960..5004: zero logits
__global__ __launch_bounds__(256) void prep_kernel(
    const float* __restrict__ X, u16* __restrict__ Xb,
    const float* __restrict__ fc1, const float* __restrict__ fc2,
    const float* __restrict__ ew1, const float* __restrict__ ew2,
    const float* __restrict__ tw1, u16* __restrict__ wt, u8* __restrict__ w2q,
    const float* __restrict__ wg, u16* __restrict__ WgT,
    float* __restrict__ logits) {
  int bid = blockIdx.x;
  if (bid < 3840) {
    int i = (bid * 256 + threadIdx.x) * 8;
    float4 a = *(const float4*)(X + i);
    float4 b = *(const float4*)(X + i + 4);
    u16x8 v;
    v[0] = f2bf(a.x); v[1] = f2bf(a.y); v[2] = f2bf(a.z); v[3] = f2bf(a.w);
    v[4] = f2bf(b.x); v[5] = f2bf(b.y); v[6] = f2bf(b.z); v[7] = f2bf(b.w);
    *(u16x8*)(Xb + i) = v;
  } else if (bid < 4928) {
    int id = bid - 3840;
    int mid = id >> 6, tile = id & 63;
    const float* src;
    if (mid == 0) src = fc1;
    else if (mid == 1) src = fc2;
    else if (mid < 8) src = ew1 + (size_t)(mid - 2) * 262144;
    else if (mid < 14) src = ew2 + (size_t)(mid - 8) * 262144;
    else src = tw1 + (size_t)(mid - 14) * 262144;
    int tr = (tile >> 3) * 64, tc = (tile & 7) * 64;
    __shared__ float t[64][65];
    int c = threadIdx.x & 63, r0 = threadIdx.x >> 6;
#pragma unroll
    for (int i = 0; i < 16; i++) {
      int r = r0 + i * 4;
      t[r][c] = src[(size_t)(tr + r) * 512 + tc + c];
    }
    __syncthreads();
    if (mid >= 8 && mid < 14) {
      // W2 -> fp8 (x64), k index = tr + c; byte-permuted within each 64B k-group
      u8* dq = w2q + (size_t)(mid - 8) * 262144;
      int pc = tr + permpos(c);   // tr is a multiple of 64
#pragma unroll
      for (int i = 0; i < 16; i++) {
        int r = r0 + i * 4;
        dq[(size_t)(tc + r) * 512 + pc] = (u8)(cvt2fp8(t[c][r] * 64.f, 0.f) & 0xff);
      }
    } else {
      u16* dst = wt + (size_t)mid * 262144;
#pragma unroll
      for (int i = 0; i < 16; i++) {
        int r = r0 + i * 4;
        dst[(size_t)(tc + r) * 512 + tr + c] = f2bf(t[c][r]);
      }
    }
  } else if (bid < 4960) {
    int col = bid - 4928;
    for (int k = threadIdx.x; k < 512; k += 256) {
      u16 v = 0;
      if (col < 18) {
        int t = col / 6, e = col % 6;
        v = f2bf(wg[(size_t)(t * 512 + k) * 6 + e]);
      }
      WgT[(size_t)col * 512 + k] = v;
    }
  } else {
    int i = (bid - 4960) * 1024 + threadIdx.x * 4;
    float4 z; z.x = 0.f; z.y = 0.f; z.z = 0.f; z.w = 0.f;
    *(float4*)(logits + i) = z;
  }
}

// ===== W1: 128x256 triple-buffer bf16 GEMM, epilogue relu -> fp8(x16, permuted) =====
__global__ __launch_bounds__(512, 4) void gemm256(
    const u16* __restrict__ A,
    const u16* __restrict__ BT,
    const float* __restrict__ bias,
    u8* __restrict__ Cq,           // [15360][3072] fp8 x16, 64B-group byte-permuted
    int nby) {
  int nwg = gridDim.x;
  int cpx = nwg >> 3;
  int bid = blockIdx.x;
  int swz = (bid & 7) * cpx + (bid >> 3);
  int bx = swz / nby, by = swz % nby;
  int brow = bx * 128, bcol = by * 256;

  __shared__ u16 SB[3][12288];

  int tid = threadIdx.x, lane = tid & 63, w = tid >> 6;
  int wm = w >> 2, wn = w & 3;
  int l = lane & 15, q = lane >> 4;

  int srow = tid >> 2;
  int sc = tid & 3;
  int srcc = sc ^ ((srow >> 1) & 3);
  const u16* AgR = A + (size_t)(brow + srow) * KDIM + srcc * 8;
  const u16* BgR0 = BT + (size_t)(bcol + srow) * KDIM + srcc * 8;
  const u16* BgR1 = BgR0 + 128 * KDIM;
  int lo = w * 512;

#define STAGE256(buf, kt)                              \
  do {                                                 \
    int _ko = (kt) * 32;                               \
    gload16(AgR + _ko, (buf) + lo);                    \
    gload16(BgR0 + _ko, (buf) + 4096 + lo);            \
    gload16(BgR1 + _ko, (buf) + 8192 + lo);            \
  } while (0)

  f32x4 zero; zero[0] = 0.f; zero[1] = 0.f; zero[2] = 0.f; zero[3] = 0.f;
  f32x4 acc[4][4];
#pragma unroll
  for (int m = 0; m < 4; m++)
#pragma unroll
    for (int n = 0; n < 4; n++) acc[m][n] = zero;

  int rca = q ^ ((l >> 1) & 3);
  int arow = wm * 64 + l;
  int bro = wn * 64 + l;

  STAGE256(SB[0], 0);
  STAGE256(SB[1], 1);
  asm volatile("s_waitcnt vmcnt(3)" ::: "memory");
  __builtin_amdgcn_s_barrier();

  u16 *bc = SB[0], *bn = SB[1], *bq = SB[2];
#pragma unroll
  for (int kt = 0; kt < 16; ++kt) {
    if (kt < 14) STAGE256(bq, kt + 2);
    bf16x8 bfv[4];
#pragma unroll
    for (int n = 0; n < 4; n++)
      bfv[n] = *(const bf16x8*)&bc[4096 + (bro + n * 16) * 32 + rca * 8];
    __builtin_amdgcn_s_setprio(1);
#pragma unroll
    for (int m = 0; m < 4; m++) {
      bf16x8 af = *(const bf16x8*)&bc[(arow + m * 16) * 32 + rca * 8];
#pragma unroll
      for (int n = 0; n < 4; n++)
        acc[m][n] = __builtin_amdgcn_mfma_f32_16x16x32_bf16(af, bfv[n], acc[m][n], 0, 0, 0);
    }
    __builtin_amdgcn_s_setprio(0);
    asm volatile("s_waitcnt lgkmcnt(0)" ::: "memory");
    if (kt < 14)
      asm volatile("s_waitcnt vmcnt(3)" ::: "memory");
    else
      asm volatile("s_waitcnt vmcnt(0)" ::: "memory");
    __builtin_amdgcn_s_barrier();
    u16* t_ = bc; bc = bn; bn = bq; bq = t_;
  }
#undef STAGE256

  // epilogue: relu, x16, fp8 (HW cvt) -> LDS at permuted col -> coalesced 16B stores
  int colL = wn * 64 + l;
  u8* S8 = (u8*)&SB[0][0];   // 128*264 = 33792 B < 73728
  float bvs[4];
#pragma unroll
  for (int n = 0; n < 4; n++) bvs[n] = bias[bcol + colL + n * 16];
#pragma unroll
  for (int m = 0; m < 4; m++) {
    int rl = wm * 64 + m * 16 + q * 4;
#pragma unroll
    for (int n = 0; n < 4; n++) {
      int j = n * 16 + l;                       // in-group col (group = wn*64)
      int pc = wn * 64 + permpos(j);
      float v0 = fmaxf(acc[m][n][0] + bvs[n], 0.f) * 16.f;
      float v1 = fmaxf(acc[m][n][1] + bvs[n], 0.f) * 16.f;
      float v2 = fmaxf(acc[m][n][2] + bvs[n], 0.f) * 16.f;
      float v3 = fmaxf(acc[m][n][3] + bvs[n], 0.f) * 16.f;
      unsigned p01 = cvt2fp8(v0, v1);
      unsigned p23 = cvt2fp8(v2, v3);
      S8[(rl + 0) * 264 + pc] = (u8)(p01 & 0xff);
      S8[(rl + 1) * 264 + pc] = (u8)(p01 >> 8);
      S8[(rl + 2) * 264 + pc] = (u8)(p23 & 0xff);
      S8[(rl + 3) * 264 + pc] = (u8)(p23 >> 8);
    }
  }
  __syncthreads();
  int row = tid >> 2, cc = tid & 3;
#pragma unroll
  for (int j = 0; j < 4; j++)
    *(u8x16*)&Cq[(size_t)(brow + row) * 3072 + bcol + cc * 64 + j * 16] =
        *(const u8x16*)&S8[row * 264 + cc * 64 + j * 16];
}

// ===== fused W2 + gated combine, fp8 with permuted layout: b128 frag reads =====
// BM=64, BN=128, 256 thr = 4 waves (1M x 4N), wave tile 64x32. BK=64 -> 48 K-steps.
// LDS access identical in structure to the proven 0-conflict bf16 pattern:
// one ds_read_b128 per fragment, granule-XOR swizzle, split into 2 i64 halves in-reg.
// launch_bounds MUST stay (256,2): (256,4) caps VGPR at 64 -> accumulator spill (R8).
__global__ __launch_bounds__(256, 2) void gemm_w2c(
    const u8* __restrict__ eh,       // [15360][3072] fp8 (x16), permuted
    const u8* __restrict__ W2q,      // [6][512 col][512 k] fp8 (x64), permuted
    const float* __restrict__ eb2,   // [6][512]
    const float* __restrict__ gates, // [(b*3+t)*30+c][6]
    u16* __restrict__ y) {           // [3][15360][512] bf16
  int nwg = gridDim.x, cpx = nwg >> 3;
  int bid = blockIdx.x;
  int swz = (bid & 7) * cpx + (bid >> 3);
  int bx = swz >> 2, by = swz & 3;
  int brow = bx * 64, bcol = by * 128;

  __shared__ __align__(16) u8 SB8[3][12288]; // buf: A 0..4095 (64x64B), B 4096..12287 (128x64B)
  __shared__ u16 glds[64 * 18];

  int tid = threadIdx.x, lane = tid & 63, w = tid >> 6;
  int l = lane & 15, q = lane >> 4;

  for (int i = tid; i < 64 * 18; i += 256) {
    int r = i / 18, te = i % 18;
    int gr = brow + r, b = gr / CDIM, c = gr % CDIM;
    int t = te / 6, e = te % 6;
    glds[i] = f2bf(gates[((size_t)(b * TDIM + t) * CDIM + c) * EDIM + e]);
  }
  float b2all[2][6];
#pragma unroll
  for (int ni = 0; ni < 2; ni++) {
    int col = bcol + w * 32 + ni * 16 + l;
#pragma unroll
    for (int e = 0; e < 6; e++) b2all[ni][e] = eb2[e * 512 + col];
  }

  int srow = tid >> 2, sc = tid & 3;
  int scA = sc ^ (srow & 3);
  const u8* Ag = eh + (size_t)(brow + srow) * 3072 + scA * 16;
  const u8* Bg0 = W2q + (size_t)(bcol + srow) * 512 + scA * 16;
  const u8* Bg1 = Bg0 + (size_t)64 * 512;
  int lo = w * 1024;

#define STAGEW(buf, s2)                                                   \
  do {                                                                    \
    int _e2 = (s2) >> 3, _k2 = (s2) & 7;                                  \
    gload16(Ag + _e2 * 512 + _k2 * 64, (buf) + lo);                       \
    gload16(Bg0 + (size_t)_e2 * 262144 + _k2 * 64, (buf) + 4096 + lo);    \
    gload16(Bg1 + (size_t)_e2 * 262144 + _k2 * 64, (buf) + 8192 + lo);    \
  } while (0)

  f32x4 P[4][2], aY0[4][2], aY1[4][2], aY2[4][2];
#pragma unroll
  for (int mi = 0; mi < 4; mi++)
#pragma unroll
    for (int ni = 0; ni < 2; ni++) {
      P[mi][ni][0] = P[mi][ni][1] = P[mi][ni][2] = P[mi][ni][3] = 0.f;
      aY0[mi][ni] = P[mi][ni]; aY1[mi][ni] = P[mi][ni]; aY2[mi][ni] = P[mi][ni];
    }

  STAGEW(SB8[0], 0);
  STAGEW(SB8[1], 1);
  asm volatile("s_waitcnt vmcnt(3)" ::: "memory");
  __builtin_amdgcn_s_barrier();

  u8 *bc = SB8[0], *bn = SB8[1], *bq = SB8[2];
  for (int e = 0; e < 6; ++e) {
#pragma unroll
    for (int kt = 0; kt < 8; ++kt) {
      int s = e * 8 + kt;
      if (s < 46) STAGEW(bq, s + 2);
      // fragment loads: one b128 per fragment (permuted layout -> both k-halves)
      i64x2 bfv[2], afv[4];
#pragma unroll
      for (int ni = 0; ni < 2; ni++) {
        int col = w * 32 + ni * 16 + l;
        bfv[ni] = *(const i64x2*)&bc[4096 + col * 64 + ((q ^ (col & 3)) * 16)];
      }
#pragma unroll
      for (int mi = 0; mi < 4; mi++) {
        int row = mi * 16 + l;
        afv[mi] = *(const i64x2*)&bc[row * 64 + ((q ^ (row & 3)) * 16)];
      }
      __builtin_amdgcn_s_setprio(1);
#pragma unroll
      for (int ks = 0; ks < 2; ++ks)
#pragma unroll
        for (int mi = 0; mi < 4; mi++)
#pragma unroll
          for (int ni = 0; ni < 2; ni++)
            P[mi][ni] = __builtin_amdgcn_mfma_f32_16x16x32_fp8_fp8(
                afv[mi][ks], bfv[ni][ks], P[mi][ni], 0, 0, 0);
      __builtin_amdgcn_s_setprio(0);
      asm volatile("s_waitcnt lgkmcnt(0)" ::: "memory");
      if (s < 46)
        asm volatile("s_waitcnt vmcnt(3)" ::: "memory");
      else
        asm volatile("s_waitcnt vmcnt(0)" ::: "memory");
      __builtin_amdgcn_s_barrier();
      u8* t_ = bc; bc = bn; bn = bq; bq = t_;
    }
    // expert boundary: descale (1/(16*64)), add bias, fold with gates
#pragma unroll
    for (int mi = 0; mi < 4; mi++) {
#pragma unroll
      for (int rr = 0; rr < 4; rr++) {
        int row = mi * 16 + q * 4 + rr;
        float g0 = bf2f(glds[row * 18 + e]);
        float g1 = bf2f(glds[row * 18 + 6 + e]);
        float g2 = bf2f(glds[row * 18 + 12 + e]);
#pragma unroll
        for (int ni = 0; ni < 2; ni++) {
          float p = P[mi][ni][rr] * 9.765625e-4f + b2all[ni][e];
          aY0[mi][ni][rr] += g0 * p;
          aY1[mi][ni][rr] += g1 * p;
          aY2[mi][ni][rr] += g2 * p;
          P[mi][ni][rr] = 0.f;
        }
      }
    }
  }
#undef STAGEW

  // epilogue: per task, acc -> LDS (stride 136 u16) -> coalesced u16x8 stores
  u16* Sst = (u16*)&SB8[0][0];
#define EPI(AY, t)                                                          \
  do {                                                                      \
    _Pragma("unroll") for (int mi = 0; mi < 4; mi++)                        \
      _Pragma("unroll") for (int ni = 0; ni < 2; ni++)                      \
        _Pragma("unroll") for (int rr = 0; rr < 4; rr++)                    \
          Sst[(mi * 16 + q * 4 + rr) * 136 + w * 32 + ni * 16 + l] =        \
              f2bf(AY[mi][ni][rr]);                                         \
    __syncthreads();                                                        \
    {                                                                       \
      int row_ = tid >> 2, cc_ = tid & 3;                                   \
      _Pragma("unroll") for (int j = 0; j < 4; j++)                         \
        *(u16x8*)&y[((size_t)(t) * NROWS + brow + row_) * 512 + bcol +      \
                    cc_ * 32 + j * 8] =                                     \
            *(const u16x8*)&Sst[row_ * 136 + cc_ * 32 + j * 8];             \
    }                                                                       \
    __syncthreads();                                                        \
  } while (0)
  EPI(aY0, 0);
  EPI(aY1, 1);
  EPI(aY2, 2);
#undef EPI
}

// ---------------- tower GEMM (128^2 m97-structure) + fused dot(tw2) -> logits ----
__global__ __launch_bounds__(256, 2) void gemm_tower(
    const u16* __restrict__ yin, const u16* __restrict__ WTt,
    const float* __restrict__ tb1, const float* __restrict__ tw2,
    float* __restrict__ logits) {
  int t = blockIdx.z;
  const u16* A = yin + (size_t)t * NROWS * KDIM;
  const u16* BT = WTt + (size_t)t * 262144;
  const float* bias = tb1 + t * 512;

  __shared__ u16 Al[128 * 32];
  __shared__ u16 Bl[128 * 32];
  int tid = threadIdx.x, lane = tid & 63, w = tid >> 6;
  int wr = w >> 1, wc = w & 1;
  int brow = blockIdx.x * 128, bcol = blockIdx.y * 128;

  int srow = tid >> 2;
  int schunk = tid & 3;
  int srcc = schunk ^ ((srow >> 1) & 3);
  const u16* Ag0 = A + (size_t)(brow + srow) * KDIM + srcc * 8;
  const u16* Ag1 = A + (size_t)(brow + srow + 64) * KDIM + srcc * 8;
  const u16* Bg0 = BT + (size_t)(bcol + srow) * KDIM + srcc * 8;
  const u16* Bg1 = BT + (size_t)(bcol + srow + 64) * KDIM + srcc * 8;
  u16* Ald0 = Al + w * 512;
  u16* Ald1 = Al + 2048 + w * 512;
  u16* Bld0 = Bl + w * 512;
  u16* Bld1 = Bl + 2048 + w * 512;

  f32x4 zero; zero[0] = 0.f; zero[1] = 0.f; zero[2] = 0.f; zero[3] = 0.f;
  f32x4 acc[4][4];
#pragma unroll
  for (int m = 0; m < 4; m++)
#pragma unroll
    for (int n = 0; n < 4; n++) acc[m][n] = zero;

  int l = lane & 15, q = lane >> 4;
  int rc = q ^ ((l >> 1) & 3);
  int rbase = wr * 64 + l;
  int cbase = wc * 64 + l;

  for (int kt = 0; kt < 16; ++kt) {
    int ko = kt * 32;
    gload16(Ag0 + ko, Ald0);
    gload16(Ag1 + ko, Ald1);
    gload16(Bg0 + ko, Bld0);
    gload16(Bg1 + ko, Bld1);
    __syncthreads();
    bf16x8 af[4], bfr[4];
#pragma unroll
    for (int m = 0; m < 4; m++) af[m] = *(const bf16x8*)&Al[(rbase + m * 16) * 32 + rc * 8];
#pragma unroll
    for (int n = 0; n < 4; n++) bfr[n] = *(const bf16x8*)&Bl[(cbase + n * 16) * 32 + rc * 8];
#pragma unroll
    for (int m = 0; m < 4; m++)
#pragma unroll
      for (int n = 0; n < 4; n++)
        acc[m][n] = __builtin_amdgcn_mfma_f32_16x16x32_bf16(af[m], bfr[n], acc[m][n], 0, 0, 0);
    __syncthreads();
  }

  int col0 = bcol + wc * 64 + l;
  float bvs[4], tws[4];
#pragma unroll
  for (int n = 0; n < 4; n++) {
    int col = col0 + n * 16;
    bvs[n] = bias[col];
    tws[n] = tw2[t * 512 + col];
  }
  int row0 = brow + wr * 64 + q * 4;
#pragma unroll
  for (int m = 0; m < 4; m++) {
#pragma unroll
    for (int r = 0; r < 4; r++) {
      float s = 0.f;
#pragma unroll
      for (int n = 0; n < 4; n++) {
        float v = acc[m][n][r] + bvs[n];
        v = fmaxf(v, 0.f);
        s += v * tws[n];
      }
      s += __shfl_xor(s, 1, 64);
      s += __shfl_xor(s, 2, 64);
      s += __shfl_xor(s, 4, 64);
      s += __shfl_xor(s, 8, 64);
      if (l == 0) {
        int row = row0 + m * 16 + r;
        int b = row / CDIM, c = row % CDIM;
        atomicAdd(&logits[(size_t)(b * TDIM + t) * CDIM + c], s);
      }
    }
  }
}

// ---------------- bf16 MFMA GEMM (m97 structure, 128^2) for fc1/fc2 ----
template <int RELU>
__global__ __launch_bounds__(256, 2) void gemm_bt(
    const u16* __restrict__ A, int lda,
    const u16* __restrict__ BT,
    const float* __restrict__ bias,
    u16* __restrict__ C, int ldc) {
  __shared__ u16 S[8448];
  u16* Al = S;
  u16* Bl = S + 4096;
  int tid = threadIdx.x, lane = tid & 63, w = tid >> 6;
  int wr = w >> 1, wc = w & 1;
  int brow = blockIdx.x * 128, bcol = blockIdx.y * 128;

  int srow = tid >> 2;
  int schunk = tid & 3;
  int srcc = schunk ^ ((srow >> 1) & 3);
  const u16* Ag0 = A + (size_t)(brow + srow) * lda + srcc * 8;
  const u16* Ag1 = A + (size_t)(brow + srow + 64) * lda + srcc * 8;
  const u16* Bg0 = BT + (size_t)(bcol + srow) * KDIM + srcc * 8;
  const u16* Bg1 = BT + (size_t)(bcol + srow + 64) * KDIM + srcc * 8;
  u16* Ald0 = Al + w * 512;
  u16* Ald1 = Al + 2048 + w * 512;
  u16* Bld0 = Bl + w * 512;
  u16* Bld1 = Bl + 2048 + w * 512;

  f32x4 zero; zero[0] = 0.f; zero[1] = 0.f; zero[2] = 0.f; zero[3] = 0.f;
  f32x4 acc[4][4];
#pragma unroll
  for (int m = 0; m < 4; m++)
#pragma unroll
    for (int n = 0; n < 4; n++) acc[m][n] = zero;

  int l = lane & 15, q = lane >> 4;
  int rc = q ^ ((l >> 1) & 3);
  int rbase = wr * 64 + l;
  int cbase = wc * 64 + l;

  for (int kt = 0; kt < 16; ++kt) {
    int ko = kt * 32;
    gload16(Ag0 + ko, Ald0);
    gload16(Ag1 + ko, Ald1);
    gload16(Bg0 + ko, Bld0);
    gload16(Bg1 + ko, Bld1);
    __syncthreads();
    bf16x8 af[4], bfr[4];
#pragma unroll
    for (int m = 0; m < 4; m++) af[m] = *(const bf16x8*)&Al[(rbase + m * 16) * 32 + rc * 8];
#pragma unroll
    for (int n = 0; n < 4; n++) bfr[n] = *(const bf16x8*)&Bl[(cbase + n * 16) * 32 + rc * 8];
#pragma unroll
    for (int m = 0; m < 4; m++)
#pragma unroll
      for (int n = 0; n < 4; n++)
        acc[m][n] = __builtin_amdgcn_mfma_f32_16x16x32_bf16(af[m], bfr[n], acc[m][n], 0, 0, 0);
    __syncthreads();
  }

  int colL = wc * 64 + l;
  float bvs[4];
#pragma unroll
  for (int n = 0; n < 4; n++) bvs[n] = bias[bcol + colL + n * 16];
#pragma unroll
  for (int half = 0; half < 2; half++) {
    if (wr == half) {
#pragma unroll
      for (int m = 0; m < 4; m++) {
        int rl = m * 16 + q * 4;
#pragma unroll
        for (int n = 0; n < 4; n++) {
#pragma unroll
          for (int rr = 0; rr < 4; rr++) {
            float v = acc[m][n][rr] + bvs[n];
            if (RELU) v = fmaxf(v, 0.f);
            S[(rl + rr) * 132 + colL + n * 16] = f2bf(v);
          }
        }
      }
    }
    __syncthreads();
    int row = tid >> 2, cc = tid & 3;
#pragma unroll
    for (int j = 0; j < 4; j++)
      *(u16x8*)&C[(size_t)(brow + half * 64 + row) * ldc + bcol + cc * 32 + j * 8] =
          *(const u16x8*)&S[row * 132 + cc * 32 + j * 8];
    __syncthreads();
  }
}

// ---------------- gate: MFMA skinny GEMM [64 rows/block x 32] + top3 softmax ----
__global__ __launch_bounds__(256) void gate_kernel(const u16* __restrict__ h,
                                                   const u16* __restrict__ WgT,
                                                   float* __restrict__ gates) {
  __shared__ u16 Wl[16 * 32 * 32];
  __shared__ float Gl[4][16][33];
  int tid = threadIdx.x, lane = tid & 63, w = tid >> 6;
  int l = lane & 15, q = lane >> 4;

  for (int idx = tid; idx < 2048; idx += 256) {
    int kt = idx >> 7, col = (idx >> 2) & 31, c = idx & 3;
    int sc = c ^ ((col >> 1) & 3);
    *(u16x8*)&Wl[kt * 1024 + col * 32 + c * 8] =
        *(const u16x8*)&WgT[(size_t)col * 512 + kt * 32 + sc * 8];
  }
  __syncthreads();

  int r = blockIdx.x * 64 + w * 16 + l;
  int ch = q ^ ((l >> 1) & 3);

  f32x4 acc0, acc1;
  acc0[0] = acc0[1] = acc0[2] = acc0[3] = 0.f;
  acc1 = acc0;
#pragma unroll
  for (int kt = 0; kt < 16; ++kt) {
    bf16x8 av = *(const bf16x8*)&h[(size_t)r * 512 + kt * 32 + q * 8];
    bf16x8 b0 = *(const bf16x8*)&Wl[kt * 1024 + l * 32 + ch * 8];
    bf16x8 b1 = *(const bf16x8*)&Wl[kt * 1024 + (16 + l) * 32 + ch * 8];
    acc0 = __builtin_amdgcn_mfma_f32_16x16x32_bf16(av, b0, acc0, 0, 0, 0);
    acc1 = __builtin_amdgcn_mfma_f32_16x16x32_bf16(av, b1, acc1, 0, 0, 0);
  }

#pragma unroll
  for (int rr = 0; rr < 4; rr++) {
    Gl[w][q * 4 + rr][l] = acc0[rr];
    Gl[w][q * 4 + rr][16 + l] = acc1[rr];
  }
  __syncthreads();

  if (lane < 16) {
    int R = blockIdx.x * 64 + w * 16 + lane;
    int b = R / CDIM, c = R % CDIM;
    for (int t = 0; t < 3; t++) {
      float g[6];
#pragma unroll
      for (int e = 0; e < 6; e++) g[e] = Gl[w][lane][t * 6 + e];
      float out[6] = {0, 0, 0, 0, 0, 0};
      int idx[3]; float val[3];
      unsigned used = 0;
      for (int kk = 0; kk < 3; kk++) {
        int best = 0; float bv = -1e30f;
        for (int e = 0; e < 6; e++)
          if (!((used >> e) & 1) && g[e] > bv) { bv = g[e]; best = e; }
        used |= 1u << best; idx[kk] = best; val[kk] = bv;
      }
      float mx = val[0];
      float s = 0.f, ex[3];
      for (int kk = 0; kk < 3; kk++) { ex[kk] = expf(val[kk] - mx); s += ex[kk]; }
      for (int kk = 0; kk < 3; kk++) out[idx[kk]] = ex[kk] / s;
      float* gp = &gates[(size_t)((b * TDIM + t) * CDIM + c) * EDIM];
      for (int e = 0; e < 6; e++) gp[e] = out[e];
    }
  }
}

// ---------------- loss: one wave per b ----------------
__global__ __launch_bounds__(64) void loss_kernel(const float* __restrict__ scores,
                                                  const float* __restrict__ logits,
                                                  const float* __restrict__ gates,
                                                  const float* __restrict__ tb2,
                                                  float* __restrict__ out) {
  int b = blockIdx.x;
  int lane = threadIdx.x;
  float bce_sum = 0.f;
  float aux = 0.f;
  for (int t = 0; t < 3; t++) {
    float sc = (lane < CDIM) ? scores[(size_t)(b * TDIM + t) * CDIM + lane] : -1e30f;
    float mx = sc;
    for (int off = 32; off; off >>= 1) mx = fmaxf(mx, __shfl_xor(mx, off, 64));
    float lab = (lane < CDIM && sc == mx) ? 1.f : 0.f;
    float lg = (lane < CDIM) ? (logits[(size_t)(b * TDIM + t) * CDIM + lane] + tb2[t]) : 0.f;
    float bce = (lane < CDIM) ? (fmaxf(lg, 0.f) - lg * lab + log1pf(expf(-fabsf(lg)))) : 0.f;
    for (int off = 32; off; off >>= 1) bce += __shfl_xor(bce, off, 64);
    bce_sum += bce / (float)CDIM;

    float impv[6];
    float meansum = 0.f;
#pragma unroll
    for (int e = 0; e < 6; e++) {
      float gsum = (lane < CDIM) ? gates[(size_t)((b * TDIM + t) * CDIM + lane) * EDIM + e] : 0.f;
      for (int off = 32; off; off >>= 1) gsum += __shfl_xor(gsum, off, 64);
      impv[e] = gsum;
      meansum += gsum;
    }
    float mean = meansum / 6.f;
    float var = 0.f;
#pragma unroll
    for (int e = 0; e < 6; e++) { float d = impv[e] - mean; var += d * d; }
    var /= 6.f;
    aux += var / (mean * mean + 1e-10f);
  }
  float res = bce_sum / 3.f + 0.01f * aux;
  if (lane == 0) atomicAdd(out, res / (float)BDIM);
}

// ---------------- host ----------------
extern "C" void kernel_launch(void* const* d_in, const int* in_sizes, int n_in,
                              void* d_out, int out_size, void* d_ws, size_t ws_size,
                              hipStream_t stream) {
  const float* X = (const float*)d_in[0];
  const float* scores = (const float*)d_in[1];
  const float* fc1_w = (const float*)d_in[2];
  const float* fc1_b = (const float*)d_in[3];
  const float* fc2_w = (const float*)d_in[4];
  const float* fc2_b = (const float*)d_in[5];
  const float* w_gate = (const float*)d_in[6];
  const float* ew1 = (const float*)d_in[7];
  const float* eb1 = (const float*)d_in[8];
  const float* ew2 = (const float*)d_in[9];
  const float* eb2 = (const float*)d_in[10];
  const float* tw1 = (const float*)d_in[11];
  const float* tb1 = (const float*)d_in[12];
  const float* tw2 = (const float*)d_in[13];
  const float* tb2 = (const float*)d_in[14];
  float* out = (float*)d_out;

  // workspace layout (u16 elements unless noted)
  u16* WT = (u16*)d_ws;                          // 17*262144
  u8* w2q = (u8*)(WT + (size_t)8 * 262144);      // 6*262144 u8 (inside slots 8..10)
  u16* WgT = WT + (size_t)17 * 262144;           // 32*512
  u16* ehall = WgT + (size_t)32 * 512;           // region: 15360*3072 u16 worth
  u8* ehq = (u8*)ehall;                          // [15360][3072] fp8 (47 MB)
  u16* Xb = ehall + (size_t)NROWS * 1536;        // bf16 X, in upper half of region
  u16* A1 = Xb + (size_t)NROWS * 512;            // dead after fc2
  u16* h = ehall + (size_t)NROWS * 3072;         // 15360*512 bf16
  u16* y = h + (size_t)NROWS * 512;              // 3*15360*512 bf16
  float* gates = (float*)(y + (size_t)TDIM * NROWS * 512);
  float* logits = gates + (size_t)BDIM * TDIM * CDIM * EDIM;

  hipMemsetAsync(d_out, 0, sizeof(float) * out_size, stream);

  // merged prep: cvt X + transpose weights (W2 -> fp8 x64 permuted) + gate prep + zero logits
  prep_kernel<<<5005, 256, 0, stream>>>(X, Xb, fc1_w, fc2_w, ew1, ew2, tw1, WT, w2q,
                                        w_gate, WgT, logits);

  // shared bottom (128^2, N=512)
  gemm_bt<1><<<dim3(120, 4), 256, 0, stream>>>(Xb, 512, WT + (size_t)0 * 262144, fc1_b, A1, 512);
  gemm_bt<0><<<dim3(120, 4), 256, 0, stream>>>(A1, 512, WT + (size_t)1 * 262144, fc2_b, h, 512);

  // gating
  gate_kernel<<<240, 256, 0, stream>>>(h, WgT, gates);

  // experts W1: merged N=3072, relu -> fp8 eh (1440 blocks of 128x256)
  gemm256<<<dim3(1440, 1, 1), 512, 0, stream>>>(h, WT + (size_t)2 * 262144, eb1, ehq, 12);

  // experts W2 + gated combine, fp8 (960 blocks of 64x128, 48 K-steps)
  gemm_w2c<<<dim3(960, 1, 1), 256, 0, stream>>>(ehq, w2q, eb2, gates, y);

  // towers: 128^2 + fused tw2-dot epilogue -> logits (atomic), z = task
  gemm_tower<<<dim3(120, 4, 3), 256, 0, stream>>>(y, WT + (size_t)14 * 262144, tb1, tw2, logits);

  // loss
  loss_kernel<<<BDIM, 64, 0, stream>>>(scores, logits, gates, tb2, out);
}

// Round 12
// 236.048 us; speedup vs baseline: 1.3660x; 1.0391x over previous
//
#include <hip/hip_runtime.h>
#include <hip/hip_bf16.h>
#include <cstdint>
#include <cstddef>

typedef unsigned short u16;
typedef unsigned char u8;
typedef long i64;
typedef __bf16 bf16x8 __attribute__((ext_vector_type(8)));
typedef float f32x4 __attribute__((ext_vector_type(4)));
typedef u16 u16x8 __attribute__((ext_vector_type(8)));
typedef u8 u8x16 __attribute__((ext_vector_type(16)));
typedef i64 i64x2 __attribute__((ext_vector_type(2)));

#define NROWS 15360   // B*C = 512*30
#define KDIM 512
#define BDIM 512
#define CDIM 30
#define TDIM 3
#define EDIM 6

typedef __attribute__((address_space(1))) const unsigned int gu32;
typedef __attribute__((address_space(3))) unsigned int lu32;

__device__ __forceinline__ void gload16(const void* g, void* l) {
  __builtin_amdgcn_global_load_lds((gu32*)g, (lu32*)l, 16, 0, 0);
}

__device__ __forceinline__ float bf2f(u16 u) {
  union { unsigned i; float f; } v; v.i = ((unsigned)u) << 16; return v.f;
}
__device__ __forceinline__ u16 f2bf(float f) {
  union { float f; unsigned i; } v; v.f = f;
  unsigned r = v.i + 0x7fffu + ((v.i >> 16) & 1u);
  return (u16)(r >> 16);
}
// fp8 e4m3fn encode, software fallback
__device__ __forceinline__ u8 f2fp8_sw(float v) {
  union { float f; unsigned u; } x; x.f = v;
  unsigned s = (x.u >> 24) & 0x80;
  x.u &= 0x7fffffffu;
  if (x.f < 0.0009765625f) return (u8)s;
  if (x.f > 448.f) return (u8)(s | 0x7e);
  int e; float m = frexpf(x.f, &e);
  if (e < -5) {
    int qq = (int)(x.f * 512.f + 0.5f);
    return (u8)(s | qq);
  }
  int qq = (int)(m * 16.f + 0.5f);
  if (qq == 16) { qq = 8; e++; }
  int E = e + 6;
  if (E >= 16 || (E == 15 && qq - 8 == 7)) return (u8)(s | 0x7e);
  return (u8)(s | (E << 3) | (qq - 8));
}
__device__ __forceinline__ unsigned cvt2fp8(float a, float b) {
#if __has_builtin(__builtin_amdgcn_cvt_pk_fp8_f32)
  return (unsigned)__builtin_amdgcn_cvt_pk_fp8_f32(a, b, 0, false) & 0xffffu;
#else
  return (unsigned)f2fp8_sw(a) | ((unsigned)f2fp8_sw(b) << 8);
#endif
}
// within-64B-group byte permutation: chunk q = {ks0 granule q (8B)} ++ {ks1 granule q (8B)}
__device__ __forceinline__ int permpos(int j) {
  return ((j & 24) << 1) + ((j & 32) >> 2) + (j & 7);
}

// ---------------- merged prep ----------------
// bid 0..3839: cvt X fp32->bf16
// bid 3840..4927: weight tile; mids 8..13 -> w2q fp8 x64; 14..16 -> tw1q fp8 x64; else bf16
// bid 4928..4959: gate weight col (WgT [32][512], cols 18..31 zero)
// bid 4960..5004: zero logits
__global__ __launch_bounds__(256) void prep_kernel(
    const float* __restrict__ X, u16* __restrict__ Xb,
    const float* __restrict__ fc1, const float* __restrict__ fc2,
    const float* __restrict__ ew1, const float* __restrict__ ew2,
    const float* __restrict__ tw1, u16* __restrict__ wt,
    u8* __restrict__ w2q, u8* __restrict__ tw1q,
    const float* __restrict__ wg, u16* __restrict__ WgT,
    float* __restrict__ logits) {
  int bid = blockIdx.x;
  if (bid < 3840) {
    int i = (bid * 256 + threadIdx.x) * 8;
    float4 a = *(const float4*)(X + i);
    float4 b = *(const float4*)(X + i + 4);
    u16x8 v;
    v[0] = f2bf(a.x); v[1] = f2bf(a.y); v[2] = f2bf(a.z); v[3] = f2bf(a.w);
    v[4] = f2bf(b.x); v[5] = f2bf(b.y); v[6] = f2bf(b.z); v[7] = f2bf(b.w);
    *(u16x8*)(Xb + i) = v;
  } else if (bid < 4928) {
    int id = bid - 3840;
    int mid = id >> 6, tile = id & 63;
    const float* src;
    if (mid == 0) src = fc1;
    else if (mid == 1) src = fc2;
    else if (mid < 8) src = ew1 + (size_t)(mid - 2) * 262144;
    else if (mid < 14) src = ew2 + (size_t)(mid - 8) * 262144;
    else src = tw1 + (size_t)(mid - 14) * 262144;
    int tr = (tile >> 3) * 64, tc = (tile & 7) * 64;
    __shared__ float t[64][65];
    int c = threadIdx.x & 63, r0 = threadIdx.x >> 6;
#pragma unroll
    for (int i = 0; i < 16; i++) {
      int r = r0 + i * 4;
      t[r][c] = src[(size_t)(tr + r) * 512 + tc + c];
    }
    __syncthreads();
    if (mid >= 8) {
      // fp8 (x64), k index = tr + c; byte-permuted within each 64B k-group
      u8* dq = (mid < 14) ? w2q + (size_t)(mid - 8) * 262144
                          : tw1q + (size_t)(mid - 14) * 262144;
      int pc = tr + permpos(c);   // tr is a multiple of 64
#pragma unroll
      for (int i = 0; i < 16; i++) {
        int r = r0 + i * 4;
        dq[(size_t)(tc + r) * 512 + pc] = (u8)(cvt2fp8(t[c][r] * 64.f, 0.f) & 0xff);
      }
    } else {
      u16* dst = wt + (size_t)mid * 262144;
#pragma unroll
      for (int i = 0; i < 16; i++) {
        int r = r0 + i * 4;
        dst[(size_t)(tc + r) * 512 + tr + c] = f2bf(t[c][r]);
      }
    }
  } else if (bid < 4960) {
    int col = bid - 4928;
    for (int k = threadIdx.x; k < 512; k += 256) {
      u16 v = 0;
      if (col < 18) {
        int t = col / 6, e = col % 6;
        v = f2bf(wg[(size_t)(t * 512 + k) * 6 + e]);
      }
      WgT[(size_t)col * 512 + k] = v;
    }
  } else {
    int i = (bid - 4960) * 1024 + threadIdx.x * 4;
    float4 z; z.x = 0.f; z.y = 0.f; z.z = 0.f; z.w = 0.f;
    *(float4*)(logits + i) = z;
  }
}

// ===== W1: 128x256 triple-buffer bf16 GEMM, epilogue relu -> fp8(x16, permuted) =====
__global__ __launch_bounds__(512, 4) void gemm256(
    const u16* __restrict__ A,
    const u16* __restrict__ BT,
    const float* __restrict__ bias,
    u8* __restrict__ Cq,           // [15360][3072] fp8 x16, 64B-group byte-permuted
    int nby) {
  int nwg = gridDim.x;
  int cpx = nwg >> 3;
  int bid = blockIdx.x;
  int swz = (bid & 7) * cpx + (bid >> 3);
  int bx = swz / nby, by = swz % nby;
  int brow = bx * 128, bcol = by * 256;

  __shared__ u16 SB[3][12288];

  int tid = threadIdx.x, lane = tid & 63, w = tid >> 6;
  int wm = w >> 2, wn = w & 3;
  int l = lane & 15, q = lane >> 4;

  int srow = tid >> 2;
  int sc = tid & 3;
  int srcc = sc ^ ((srow >> 1) & 3);
  const u16* AgR = A + (size_t)(brow + srow) * KDIM + srcc * 8;
  const u16* BgR0 = BT + (size_t)(bcol + srow) * KDIM + srcc * 8;
  const u16* BgR1 = BgR0 + 128 * KDIM;
  int lo = w * 512;

#define STAGE256(buf, kt)                              \
  do {                                                 \
    int _ko = (kt) * 32;                               \
    gload16(AgR + _ko, (buf) + lo);                    \
    gload16(BgR0 + _ko, (buf) + 4096 + lo);            \
    gload16(BgR1 + _ko, (buf) + 8192 + lo);            \
  } while (0)

  f32x4 zero; zero[0] = 0.f; zero[1] = 0.f; zero[2] = 0.f; zero[3] = 0.f;
  f32x4 acc[4][4];
#pragma unroll
  for (int m = 0; m < 4; m++)
#pragma unroll
    for (int n = 0; n < 4; n++) acc[m][n] = zero;

  int rca = q ^ ((l >> 1) & 3);
  int arow = wm * 64 + l;
  int bro = wn * 64 + l;

  STAGE256(SB[0], 0);
  STAGE256(SB[1], 1);
  asm volatile("s_waitcnt vmcnt(3)" ::: "memory");
  __builtin_amdgcn_s_barrier();

  u16 *bc = SB[0], *bn = SB[1], *bq = SB[2];
#pragma unroll
  for (int kt = 0; kt < 16; ++kt) {
    if (kt < 14) STAGE256(bq, kt + 2);
    bf16x8 bfv[4];
#pragma unroll
    for (int n = 0; n < 4; n++)
      bfv[n] = *(const bf16x8*)&bc[4096 + (bro + n * 16) * 32 + rca * 8];
    __builtin_amdgcn_s_setprio(1);
#pragma unroll
    for (int m = 0; m < 4; m++) {
      bf16x8 af = *(const bf16x8*)&bc[(arow + m * 16) * 32 + rca * 8];
#pragma unroll
      for (int n = 0; n < 4; n++)
        acc[m][n] = __builtin_amdgcn_mfma_f32_16x16x32_bf16(af, bfv[n], acc[m][n], 0, 0, 0);
    }
    __builtin_amdgcn_s_setprio(0);
    asm volatile("s_waitcnt lgkmcnt(0)" ::: "memory");
    if (kt < 14)
      asm volatile("s_waitcnt vmcnt(3)" ::: "memory");
    else
      asm volatile("s_waitcnt vmcnt(0)" ::: "memory");
    __builtin_amdgcn_s_barrier();
    u16* t_ = bc; bc = bn; bn = bq; bq = t_;
  }
#undef STAGE256

  // epilogue: relu, x16, fp8 (HW cvt) -> LDS at permuted col -> coalesced 16B stores
  int colL = wn * 64 + l;
  u8* S8 = (u8*)&SB[0][0];   // 128*264 = 33792 B < 73728
  float bvs[4];
#pragma unroll
  for (int n = 0; n < 4; n++) bvs[n] = bias[bcol + colL + n * 16];
#pragma unroll
  for (int m = 0; m < 4; m++) {
    int rl = wm * 64 + m * 16 + q * 4;
#pragma unroll
    for (int n = 0; n < 4; n++) {
      int j = n * 16 + l;                       // in-group col (group = wn*64)
      int pc = wn * 64 + permpos(j);
      float v0 = fmaxf(acc[m][n][0] + bvs[n], 0.f) * 16.f;
      float v1 = fmaxf(acc[m][n][1] + bvs[n], 0.f) * 16.f;
      float v2 = fmaxf(acc[m][n][2] + bvs[n], 0.f) * 16.f;
      float v3 = fmaxf(acc[m][n][3] + bvs[n], 0.f) * 16.f;
      unsigned p01 = cvt2fp8(v0, v1);
      unsigned p23 = cvt2fp8(v2, v3);
      S8[(rl + 0) * 264 + pc] = (u8)(p01 & 0xff);
      S8[(rl + 1) * 264 + pc] = (u8)(p01 >> 8);
      S8[(rl + 2) * 264 + pc] = (u8)(p23 & 0xff);
      S8[(rl + 3) * 264 + pc] = (u8)(p23 >> 8);
    }
  }
  __syncthreads();
  int row = tid >> 2, cc = tid & 3;
#pragma unroll
  for (int j = 0; j < 4; j++)
    *(u8x16*)&Cq[(size_t)(brow + row) * 3072 + bcol + cc * 64 + j * 16] =
        *(const u8x16*)&S8[row * 264 + cc * 64 + j * 16];
}

// ===== fused W2 + gated combine, fp8 permuted, 2-way-free swizzle =====
// BM=64, BN=128, 256 thr = 4 waves (1M x 4N), wave tile 64x32. BK=64 -> 48 K-steps.
// Swizzle x = (row>>1)&3 both sides (proven 2-way-free geometry of the bf16 kernel).
// launch_bounds MUST stay (256,2): (256,4) caps VGPR at 64 -> accumulator spill (R8).
__global__ __launch_bounds__(256, 2) void gemm_w2c(
    const u8* __restrict__ eh,       // [15360][3072] fp8 (x16), permuted
    const u8* __restrict__ W2q,      // [6][512 col][512 k] fp8 (x64), permuted
    const float* __restrict__ eb2,   // [6][512]
    const float* __restrict__ gates, // [(b*3+t)*30+c][6]
    u8* __restrict__ yq) {           // [3][15360][512] fp8 (x32), permuted
  int nwg = gridDim.x, cpx = nwg >> 3;
  int bid = blockIdx.x;
  int swz = (bid & 7) * cpx + (bid >> 3);
  int bx = swz >> 2, by = swz & 3;
  int brow = bx * 64, bcol = by * 128;

  __shared__ __align__(16) u8 SB8[3][12288]; // buf: A 0..4095 (64x64B), B 4096..12287 (128x64B)
  __shared__ u16 glds[64 * 18];

  int tid = threadIdx.x, lane = tid & 63, w = tid >> 6;
  int l = lane & 15, q = lane >> 4;

  for (int i = tid; i < 64 * 18; i += 256) {
    int r = i / 18, te = i % 18;
    int gr = brow + r, b = gr / CDIM, c = gr % CDIM;
    int t = te / 6, e = te % 6;
    glds[i] = f2bf(gates[((size_t)(b * TDIM + t) * CDIM + c) * EDIM + e]);
  }
  float b2all[2][6];
#pragma unroll
  for (int ni = 0; ni < 2; ni++) {
    int col = bcol + w * 32 + ni * 16 + l;
#pragma unroll
    for (int e = 0; e < 6; e++) b2all[ni][e] = eb2[e * 512 + col];
  }

  int srow = tid >> 2, sc = tid & 3;
  int scX = sc ^ ((srow >> 1) & 3);
  const u8* Ag = eh + (size_t)(brow + srow) * 3072 + scX * 16;
  const u8* Bg0 = W2q + (size_t)(bcol + srow) * 512 + scX * 16;
  const u8* Bg1 = Bg0 + (size_t)64 * 512;
  int lo = w * 1024;

#define STAGEW(buf, s2)                                                   \
  do {                                                                    \
    int _e2 = (s2) >> 3, _k2 = (s2) & 7;                                  \
    gload16(Ag + _e2 * 512 + _k2 * 64, (buf) + lo);                       \
    gload16(Bg0 + (size_t)_e2 * 262144 + _k2 * 64, (buf) + 4096 + lo);    \
    gload16(Bg1 + (size_t)_e2 * 262144 + _k2 * 64, (buf) + 8192 + lo);    \
  } while (0)

  f32x4 P[4][2], aY0[4][2], aY1[4][2], aY2[4][2];
#pragma unroll
  for (int mi = 0; mi < 4; mi++)
#pragma unroll
    for (int ni = 0; ni < 2; ni++) {
      P[mi][ni][0] = P[mi][ni][1] = P[mi][ni][2] = P[mi][ni][3] = 0.f;
      aY0[mi][ni] = P[mi][ni]; aY1[mi][ni] = P[mi][ni]; aY2[mi][ni] = P[mi][ni];
    }

  int xg = q ^ ((l >> 1) & 3);   // read granule (matches scX; 2-way-free)

  STAGEW(SB8[0], 0);
  STAGEW(SB8[1], 1);
  asm volatile("s_waitcnt vmcnt(3)" ::: "memory");
  __builtin_amdgcn_s_barrier();

  u8 *bc = SB8[0], *bn = SB8[1], *bq = SB8[2];
  for (int e = 0; e < 6; ++e) {
#pragma unroll
    for (int kt = 0; kt < 8; ++kt) {
      int s = e * 8 + kt;
      if (s < 46) STAGEW(bq, s + 2);
      i64x2 bfv[2], afv[4];
#pragma unroll
      for (int ni = 0; ni < 2; ni++) {
        int col = w * 32 + ni * 16 + l;
        bfv[ni] = *(const i64x2*)&bc[4096 + col * 64 + xg * 16];
      }
#pragma unroll
      for (int mi = 0; mi < 4; mi++) {
        int row = mi * 16 + l;
        afv[mi] = *(const i64x2*)&bc[row * 64 + xg * 16];
      }
      __builtin_amdgcn_s_setprio(1);
#pragma unroll
      for (int ks = 0; ks < 2; ++ks)
#pragma unroll
        for (int mi = 0; mi < 4; mi++)
#pragma unroll
          for (int ni = 0; ni < 2; ni++)
            P[mi][ni] = __builtin_amdgcn_mfma_f32_16x16x32_fp8_fp8(
                afv[mi][ks], bfv[ni][ks], P[mi][ni], 0, 0, 0);
      __builtin_amdgcn_s_setprio(0);
      asm volatile("s_waitcnt lgkmcnt(0)" ::: "memory");
      if (s < 46)
        asm volatile("s_waitcnt vmcnt(3)" ::: "memory");
      else
        asm volatile("s_waitcnt vmcnt(0)" ::: "memory");
      __builtin_amdgcn_s_barrier();
      u8* t_ = bc; bc = bn; bn = bq; bq = t_;
    }
    // expert boundary: descale (1/(16*64)), add bias, fold with gates
#pragma unroll
    for (int mi = 0; mi < 4; mi++) {
#pragma unroll
      for (int rr = 0; rr < 4; rr++) {
        int row = mi * 16 + q * 4 + rr;
        float g0 = bf2f(glds[row * 18 + e]);
        float g1 = bf2f(glds[row * 18 + 6 + e]);
        float g2 = bf2f(glds[row * 18 + 12 + e]);
#pragma unroll
        for (int ni = 0; ni < 2; ni++) {
          float p = P[mi][ni][rr] * 9.765625e-4f + b2all[ni][e];
          aY0[mi][ni][rr] += g0 * p;
          aY1[mi][ni][rr] += g1 * p;
          aY2[mi][ni][rr] += g2 * p;
          P[mi][ni][rr] = 0.f;
        }
      }
    }
  }
#undef STAGEW

  // epilogue: per task, y -> fp8(x32) at permuted col -> coalesced 16B stores
  u8* S8 = (u8*)&SB8[0][0];   // 64*144 = 9216 B
#define EPI(AY, t)                                                          \
  do {                                                                      \
    _Pragma("unroll") for (int mi = 0; mi < 4; mi++) {                      \
      int rl = mi * 16 + q * 4;                                             \
      _Pragma("unroll") for (int ni = 0; ni < 2; ni++) {                    \
        int colL = w * 32 + ni * 16 + l;                                    \
        int pc = (colL & 64) + permpos(colL & 63);                          \
        unsigned p01 = cvt2fp8(AY[mi][ni][0] * 32.f, AY[mi][ni][1] * 32.f); \
        unsigned p23 = cvt2fp8(AY[mi][ni][2] * 32.f, AY[mi][ni][3] * 32.f); \
        S8[(rl + 0) * 144 + pc] = (u8)(p01 & 0xff);                         \
        S8[(rl + 1) * 144 + pc] = (u8)(p01 >> 8);                           \
        S8[(rl + 2) * 144 + pc] = (u8)(p23 & 0xff);                         \
        S8[(rl + 3) * 144 + pc] = (u8)(p23 >> 8);                           \
      }                                                                     \
    }                                                                       \
    __syncthreads();                                                        \
    {                                                                       \
      int row_ = tid >> 2, cc_ = tid & 3;                                   \
      _Pragma("unroll") for (int j = 0; j < 2; j++)                         \
        *(u8x16*)&yq[((size_t)(t) * NROWS + brow + row_) * 512 + bcol +     \
                     j * 64 + cc_ * 16] =                                   \
            *(const u8x16*)&S8[row_ * 144 + j * 64 + cc_ * 16];             \
    }                                                                       \
    __syncthreads();                                                        \
  } while (0)
  EPI(aY0, 0);
  EPI(aY1, 1);
  EPI(aY2, 2);
#undef EPI
}

// ===== tower fp8: th = relu(yq@tw1q/2048 + tb1); logits += th . tw2 =====
// Same template as gemm_w2c: BM=64, BN=128, BK=64, 8 K-steps, permuted fp8 layout.
__global__ __launch_bounds__(256, 2) void gemm_tower(
    const u8* __restrict__ yq,       // [3][15360][512] fp8 (x32), permuted
    const u8* __restrict__ tw1q,     // [3][512 col][512 k] fp8 (x64), permuted
    const float* __restrict__ tb1, const float* __restrict__ tw2,
    float* __restrict__ logits) {
  int t = blockIdx.z;
  const u8* A = yq + (size_t)t * NROWS * 512;
  const u8* BT = tw1q + (size_t)t * 262144;

  int nwg = gridDim.x, cpx = nwg >> 3;
  int bid = blockIdx.x;
  int swz = (bid & 7) * cpx + (bid >> 3);
  int bx = swz >> 2, by = swz & 3;
  int brow = bx * 64, bcol = by * 128;

  __shared__ __align__(16) u8 SB8[3][12288];

  int tid = threadIdx.x, lane = tid & 63, w = tid >> 6;
  int l = lane & 15, q = lane >> 4;

  int srow = tid >> 2, sc = tid & 3;
  int scX = sc ^ ((srow >> 1) & 3);
  const u8* Ag = A + (size_t)(brow + srow) * 512 + scX * 16;
  const u8* Bg0 = BT + (size_t)(bcol + srow) * 512 + scX * 16;
  const u8* Bg1 = Bg0 + (size_t)64 * 512;
  int lo = w * 1024;

#define STAGET(buf, kt)                                \
  do {                                                 \
    gload16(Ag + (kt) * 64, (buf) + lo);               \
    gload16(Bg0 + (kt) * 64, (buf) + 4096 + lo);       \
    gload16(Bg1 + (kt) * 64, (buf) + 8192 + lo);       \
  } while (0)

  f32x4 P[4][2];
#pragma unroll
  for (int mi = 0; mi < 4; mi++)
#pragma unroll
    for (int ni = 0; ni < 2; ni++) {
      P[mi][ni][0] = 0.f; P[mi][ni][1] = 0.f; P[mi][ni][2] = 0.f; P[mi][ni][3] = 0.f;
    }

  int xg = q ^ ((l >> 1) & 3);

  STAGET(SB8[0], 0);
  STAGET(SB8[1], 1);
  asm volatile("s_waitcnt vmcnt(3)" ::: "memory");
  __builtin_amdgcn_s_barrier();

  u8 *bc = SB8[0], *bn = SB8[1], *bq = SB8[2];
#pragma unroll
  for (int kt = 0; kt < 8; ++kt) {
    if (kt < 6) STAGET(bq, kt + 2);
    i64x2 bfv[2], afv[4];
#pragma unroll
    for (int ni = 0; ni < 2; ni++) {
      int col = w * 32 + ni * 16 + l;
      bfv[ni] = *(const i64x2*)&bc[4096 + col * 64 + xg * 16];
    }
#pragma unroll
    for (int mi = 0; mi < 4; mi++) {
      int row = mi * 16 + l;
      afv[mi] = *(const i64x2*)&bc[row * 64 + xg * 16];
    }
    __builtin_amdgcn_s_setprio(1);
#pragma unroll
    for (int ks = 0; ks < 2; ++ks)
#pragma unroll
      for (int mi = 0; mi < 4; mi++)
#pragma unroll
        for (int ni = 0; ni < 2; ni++)
          P[mi][ni] = __builtin_amdgcn_mfma_f32_16x16x32_fp8_fp8(
              afv[mi][ks], bfv[ni][ks], P[mi][ni], 0, 0, 0);
    __builtin_amdgcn_s_setprio(0);
    asm volatile("s_waitcnt lgkmcnt(0)" ::: "memory");
    if (kt < 6)
      asm volatile("s_waitcnt vmcnt(3)" ::: "memory");
    else
      asm volatile("s_waitcnt vmcnt(0)" ::: "memory");
    __builtin_amdgcn_s_barrier();
    u8* t_ = bc; bc = bn; bn = bq; bq = t_;
  }
#undef STAGET

  // epilogue: descale 1/(32*64), +tb1, relu, dot tw2, reduce over l, atomic
  float bvs[2], tws[2];
#pragma unroll
  for (int ni = 0; ni < 2; ni++) {
    int col = bcol + w * 32 + ni * 16 + l;
    bvs[ni] = tb1[t * 512 + col];
    tws[ni] = tw2[t * 512 + col];
  }
#pragma unroll
  for (int mi = 0; mi < 4; mi++) {
#pragma unroll
    for (int rr = 0; rr < 4; rr++) {
      float s = 0.f;
#pragma unroll
      for (int ni = 0; ni < 2; ni++) {
        float v = P[mi][ni][rr] * 4.8828125e-4f + bvs[ni];
        v = fmaxf(v, 0.f);
        s += v * tws[ni];
      }
      s += __shfl_xor(s, 1, 64);
      s += __shfl_xor(s, 2, 64);
      s += __shfl_xor(s, 4, 64);
      s += __shfl_xor(s, 8, 64);
      if (l == 0) {
        int row = brow + mi * 16 + q * 4 + rr;
        int b = row / CDIM, c = row % CDIM;
        atomicAdd(&logits[(size_t)(b * TDIM + t) * CDIM + c], s);
      }
    }
  }
}

// ---------------- bf16 MFMA GEMM (m97 structure, 128^2) for fc1/fc2 ----
template <int RELU>
__global__ __launch_bounds__(256, 2) void gemm_bt(
    const u16* __restrict__ A, int lda,
    const u16* __restrict__ BT,
    const float* __restrict__ bias,
    u16* __restrict__ C, int ldc) {
  __shared__ u16 S[8448];
  u16* Al = S;
  u16* Bl = S + 4096;
  int tid = threadIdx.x, lane = tid & 63, w = tid >> 6;
  int wr = w >> 1, wc = w & 1;
  int brow = blockIdx.x * 128, bcol = blockIdx.y * 128;

  int srow = tid >> 2;
  int schunk = tid & 3;
  int srcc = schunk ^ ((srow >> 1) & 3);
  const u16* Ag0 = A + (size_t)(brow + srow) * lda + srcc * 8;
  const u16* Ag1 = A + (size_t)(brow + srow + 64) * lda + srcc * 8;
  const u16* Bg0 = BT + (size_t)(bcol + srow) * KDIM + srcc * 8;
  const u16* Bg1 = BT + (size_t)(bcol + srow + 64) * KDIM + srcc * 8;
  u16* Ald0 = Al + w * 512;
  u16* Ald1 = Al + 2048 + w * 512;
  u16* Bld0 = Bl + w * 512;
  u16* Bld1 = Bl + 2048 + w * 512;

  f32x4 zero; zero[0] = 0.f; zero[1] = 0.f; zero[2] = 0.f; zero[3] = 0.f;
  f32x4 acc[4][4];
#pragma unroll
  for (int m = 0; m < 4; m++)
#pragma unroll
    for (int n = 0; n < 4; n++) acc[m][n] = zero;

  int l = lane & 15, q = lane >> 4;
  int rc = q ^ ((l >> 1) & 3);
  int rbase = wr * 64 + l;
  int cbase = wc * 64 + l;

  for (int kt = 0; kt < 16; ++kt) {
    int ko = kt * 32;
    gload16(Ag0 + ko, Ald0);
    gload16(Ag1 + ko, Ald1);
    gload16(Bg0 + ko, Bld0);
    gload16(Bg1 + ko, Bld1);
    __syncthreads();
    bf16x8 af[4], bfr[4];
#pragma unroll
    for (int m = 0; m < 4; m++) af[m] = *(const bf16x8*)&Al[(rbase + m * 16) * 32 + rc * 8];
#pragma unroll
    for (int n = 0; n < 4; n++) bfr[n] = *(const bf16x8*)&Bl[(cbase + n * 16) * 32 + rc * 8];
#pragma unroll
    for (int m = 0; m < 4; m++)
#pragma unroll
      for (int n = 0; n < 4; n++)
        acc[m][n] = __builtin_amdgcn_mfma_f32_16x16x32_bf16(af[m], bfr[n], acc[m][n], 0, 0, 0);
    __syncthreads();
  }

  int colL = wc * 64 + l;
  float bvs[4];
#pragma unroll
  for (int n = 0; n < 4; n++) bvs[n] = bias[bcol + colL + n * 16];
#pragma unroll
  for (int half = 0; half < 2; half++) {
    if (wr == half) {
#pragma unroll
      for (int m = 0; m < 4; m++) {
        int rl = m * 16 + q * 4;
#pragma unroll
        for (int n = 0; n < 4; n++) {
#pragma unroll
          for (int rr = 0; rr < 4; rr++) {
            float v = acc[m][n][rr] + bvs[n];
            if (RELU) v = fmaxf(v, 0.f);
            S[(rl + rr) * 132 + colL + n * 16] = f2bf(v);
          }
        }
      }
    }
    __syncthreads();
    int row = tid >> 2, cc = tid & 3;
#pragma unroll
    for (int j = 0; j < 4; j++)
      *(u16x8*)&C[(size_t)(brow + half * 64 + row) * ldc + bcol + cc * 32 + j * 8] =
          *(const u16x8*)&S[row * 132 + cc * 32 + j * 8];
    __syncthreads();
  }
}

// ---------------- gate: MFMA skinny GEMM [64 rows/block x 32] + top3 softmax ----
__global__ __launch_bounds__(256) void gate_kernel(const u16* __restrict__ h,
                                                   const u16* __restrict__ WgT,
                                                   float* __restrict__ gates) {
  __shared__ u16 Wl[16 * 32 * 32];
  __shared__ float Gl[4][16][33];
  int tid = threadIdx.x, lane = tid & 63, w = tid >> 6;
  int l = lane & 15, q = lane >> 4;

  for (int idx = tid; idx < 2048; idx += 256) {
    int kt = idx >> 7, col = (idx >> 2) & 31, c = idx & 3;
    int sc = c ^ ((col >> 1) & 3);
    *(u16x8*)&Wl[kt * 1024 + col * 32 + c * 8] =
        *(const u16x8*)&WgT[(size_t)col * 512 + kt * 32 + sc * 8];
  }
  __syncthreads();

  int r = blockIdx.x * 64 + w * 16 + l;
  int ch = q ^ ((l >> 1) & 3);

  f32x4 acc0, acc1;
  acc0[0] = acc0[1] = acc0[2] = acc0[3] = 0.f;
  acc1 = acc0;
#pragma unroll
  for (int kt = 0; kt < 16; ++kt) {
    bf16x8 av = *(const bf16x8*)&h[(size_t)r * 512 + kt * 32 + q * 8];
    bf16x8 b0 = *(const bf16x8*)&Wl[kt * 1024 + l * 32 + ch * 8];
    bf16x8 b1 = *(const bf16x8*)&Wl[kt * 1024 + (16 + l) * 32 + ch * 8];
    acc0 = __builtin_amdgcn_mfma_f32_16x16x32_bf16(av, b0, acc0, 0, 0, 0);
    acc1 = __builtin_amdgcn_mfma_f32_16x16x32_bf16(av, b1, acc1, 0, 0, 0);
  }

#pragma unroll
  for (int rr = 0; rr < 4; rr++) {
    Gl[w][q * 4 + rr][l] = acc0[rr];
    Gl[w][q * 4 + rr][16 + l] = acc1[rr];
  }
  __syncthreads();

  if (lane < 16) {
    int R = blockIdx.x * 64 + w * 16 + lane;
    int b = R / CDIM, c = R % CDIM;
    for (int t = 0; t < 3; t++) {
      float g[6];
#pragma unroll
      for (int e = 0; e < 6; e++) g[e] = Gl[w][lane][t * 6 + e];
      float out[6] = {0, 0, 0, 0, 0, 0};
      int idx[3]; float val[3];
      unsigned used = 0;
      for (int kk = 0; kk < 3; kk++) {
        int best = 0; float bv = -1e30f;
        for (int e = 0; e < 6; e++)
          if (!((used >> e) & 1) && g[e] > bv) { bv = g[e]; best = e; }
        used |= 1u << best; idx[kk] = best; val[kk] = bv;
      }
      float mx = val[0];
      float s = 0.f, ex[3];
      for (int kk = 0; kk < 3; kk++) { ex[kk] = expf(val[kk] - mx); s += ex[kk]; }
      for (int kk = 0; kk < 3; kk++) out[idx[kk]] = ex[kk] / s;
      float* gp = &gates[(size_t)((b * TDIM + t) * CDIM + c) * EDIM];
      for (int e = 0; e < 6; e++) gp[e] = out[e];
    }
  }
}

// ---------------- loss: one wave per b ----------------
__global__ __launch_bounds__(64) void loss_kernel(const float* __restrict__ scores,
                                                  const float* __restrict__ logits,
                                                  const float* __restrict__ gates,
                                                  const float* __restrict__ tb2,
                                                  float* __restrict__ out) {
  int b = blockIdx.x;
  int lane = threadIdx.x;
  float bce_sum = 0.f;
  float aux = 0.f;
  for (int t = 0; t < 3; t++) {
    float sc = (lane < CDIM) ? scores[(size_t)(b * TDIM + t) * CDIM + lane] : -1e30f;
    float mx = sc;
    for (int off = 32; off; off >>= 1) mx = fmaxf(mx, __shfl_xor(mx, off, 64));
    float lab = (lane < CDIM && sc == mx) ? 1.f : 0.f;
    float lg = (lane < CDIM) ? (logits[(size_t)(b * TDIM + t) * CDIM + lane] + tb2[t]) : 0.f;
    float bce = (lane < CDIM) ? (fmaxf(lg, 0.f) - lg * lab + log1pf(expf(-fabsf(lg)))) : 0.f;
    for (int off = 32; off; off >>= 1) bce += __shfl_xor(bce, off, 64);
    bce_sum += bce / (float)CDIM;

    float impv[6];
    float meansum = 0.f;
#pragma unroll
    for (int e = 0; e < 6; e++) {
      float gsum = (lane < CDIM) ? gates[(size_t)((b * TDIM + t) * CDIM + lane) * EDIM + e] : 0.f;
      for (int off = 32; off; off >>= 1) gsum += __shfl_xor(gsum, off, 64);
      impv[e] = gsum;
      meansum += gsum;
    }
    float mean = meansum / 6.f;
    float var = 0.f;
#pragma unroll
    for (int e = 0; e < 6; e++) { float d = impv[e] - mean; var += d * d; }
    var /= 6.f;
    aux += var / (mean * mean + 1e-10f);
  }
  float res = bce_sum / 3.f + 0.01f * aux;
  if (lane == 0) atomicAdd(out, res / (float)BDIM);
}

// ---------------- host ----------------
extern "C" void kernel_launch(void* const* d_in, const int* in_sizes, int n_in,
                              void* d_out, int out_size, void* d_ws, size_t ws_size,
                              hipStream_t stream) {
  const float* X = (const float*)d_in[0];
  const float* scores = (const float*)d_in[1];
  const float* fc1_w = (const float*)d_in[2];
  const float* fc1_b = (const float*)d_in[3];
  const float* fc2_w = (const float*)d_in[4];
  const float* fc2_b = (const float*)d_in[5];
  const float* w_gate = (const float*)d_in[6];
  const float* ew1 = (const float*)d_in[7];
  const float* eb1 = (const float*)d_in[8];
  const float* ew2 = (const float*)d_in[9];
  const float* eb2 = (const float*)d_in[10];
  const float* tw1 = (const float*)d_in[11];
  const float* tb1 = (const float*)d_in[12];
  const float* tw2 = (const float*)d_in[13];
  const float* tb2 = (const float*)d_in[14];
  float* out = (float*)d_out;

  // workspace layout
  u16* WT = (u16*)d_ws;                          // slots 0..7 bf16; 8..13 repurposed
  u8* w2q = (u8*)(WT + (size_t)8 * 262144);      // 6*262144 u8
  u8* tw1q = w2q + (size_t)6 * 262144;           // 3*262144 u8
  u16* WgT = WT + (size_t)17 * 262144;           // 32*512
  u16* ehall = WgT + (size_t)32 * 512;
  u8* ehq = (u8*)ehall;                          // [15360][3072] fp8 (47 MB)
  u16* Xb = ehall + (size_t)NROWS * 1536;        // bf16 X, in upper half of ehq region
  u16* A1 = Xb + (size_t)NROWS * 512;            // dead after fc2
  u16* h = ehall + (size_t)NROWS * 3072;         // 15360*512 bf16
  u8* yq = (u8*)(h + (size_t)NROWS * 512);       // [3][15360][512] fp8 (23.6 MB)
  float* gates = (float*)(yq + (size_t)TDIM * NROWS * 512);
  float* logits = gates + (size_t)BDIM * TDIM * CDIM * EDIM;

  hipMemsetAsync(d_out, 0, sizeof(float) * out_size, stream);

  // merged prep: cvt X + weights (W2/tw1 -> fp8 x64 permuted) + gate prep + zero logits
  prep_kernel<<<5005, 256, 0, stream>>>(X, Xb, fc1_w, fc2_w, ew1, ew2, tw1, WT, w2q, tw1q,
                                        w_gate, WgT, logits);

  // shared bottom (128^2, N=512)
  gemm_bt<1><<<dim3(120, 4), 256, 0, stream>>>(Xb, 512, WT + (size_t)0 * 262144, fc1_b, A1, 512);
  gemm_bt<0><<<dim3(120, 4), 256, 0, stream>>>(A1, 512, WT + (size_t)1 * 262144, fc2_b, h, 512);

  // gating
  gate_kernel<<<240, 256, 0, stream>>>(h, WgT, gates);

  // experts W1: merged N=3072, relu -> fp8 eh (1440 blocks of 128x256)
  gemm256<<<dim3(1440, 1, 1), 512, 0, stream>>>(h, WT + (size_t)2 * 262144, eb1, ehq, 12);

  // experts W2 + gated combine, fp8 (960 blocks of 64x128, 48 K-steps) -> yq fp8
  gemm_w2c<<<dim3(960, 1, 1), 256, 0, stream>>>(ehq, w2q, eb2, gates, yq);

  // towers fp8 (960 x 3 blocks of 64x128, 8 K-steps) -> logits (atomic)
  gemm_tower<<<dim3(960, 1, 3), 256, 0, stream>>>(yq, tw1q, tb1, tw2, logits);

  // loss
  loss_kernel<<<BDIM, 64, 0, stream>>>(scores, logits, gates, tb2, out);
}

// Round 13
// 233.596 us; speedup vs baseline: 1.3803x; 1.0105x over previous
//
#include <hip/hip_runtime.h>
#include <hip/hip_bf16.h>
#include <cstdint>
#include <cstddef>

typedef unsigned short u16;
typedef unsigned char u8;
typedef long i64;
typedef __bf16 bf16x8 __attribute__((ext_vector_type(8)));
typedef float f32x4 __attribute__((ext_vector_type(4)));
typedef u16 u16x8 __attribute__((ext_vector_type(8)));
typedef u8 u8x16 __attribute__((ext_vector_type(16)));
typedef i64 i64x2 __attribute__((ext_vector_type(2)));

#define NROWS 15360   // B*C = 512*30
#define KDIM 512
#define BDIM 512
#define CDIM 30
#define TDIM 3
#define EDIM 6

typedef __attribute__((address_space(1))) const unsigned int gu32;
typedef __attribute__((address_space(3))) unsigned int lu32;

__device__ __forceinline__ void gload16(const void* g, void* l) {
  __builtin_amdgcn_global_load_lds((gu32*)g, (lu32*)l, 16, 0, 0);
}

__device__ __forceinline__ float bf2f(u16 u) {
  union { unsigned i; float f; } v; v.i = ((unsigned)u) << 16; return v.f;
}
__device__ __forceinline__ u16 f2bf(float f) {
  union { float f; unsigned i; } v; v.f = f;
  unsigned r = v.i + 0x7fffu + ((v.i >> 16) & 1u);
  return (u16)(r >> 16);
}
// fp8 e4m3fn encode, software fallback
__device__ __forceinline__ u8 f2fp8_sw(float v) {
  union { float f; unsigned u; } x; x.f = v;
  unsigned s = (x.u >> 24) & 0x80;
  x.u &= 0x7fffffffu;
  if (x.f < 0.0009765625f) return (u8)s;
  if (x.f > 448.f) return (u8)(s | 0x7e);
  int e; float m = frexpf(x.f, &e);
  if (e < -5) {
    int qq = (int)(x.f * 512.f + 0.5f);
    return (u8)(s | qq);
  }
  int qq = (int)(m * 16.f + 0.5f);
  if (qq == 16) { qq = 8; e++; }
  int E = e + 6;
  if (E >= 16 || (E == 15 && qq - 8 == 7)) return (u8)(s | 0x7e);
  return (u8)(s | (E << 3) | (qq - 8));
}
__device__ __forceinline__ unsigned cvt2fp8(float a, float b) {
#if __has_builtin(__builtin_amdgcn_cvt_pk_fp8_f32)
  return (unsigned)__builtin_amdgcn_cvt_pk_fp8_f32(a, b, 0, false) & 0xffffu;
#else
  return (unsigned)f2fp8_sw(a) | ((unsigned)f2fp8_sw(b) << 8);
#endif
}
// within-64B-group byte permutation: chunk q = {ks0 granule q (8B)} ++ {ks1 granule q (8B)}
__device__ __forceinline__ int permpos(int j) {
  return ((j & 24) << 1) + ((j & 32) >> 2) + (j & 7);
}

// ---------------- merged prep ----------------
// bid 0..3839: cvt X fp32->bf16
// bid 3840..4927: weight tile; mids 0..1 bf16; 2..7 -> w1q; 8..13 -> w2q; 14..16 -> tw1q (fp8 x64)
// bid 4928..4959: gate weight col (WgT [32][512], cols 18..31 zero)
// bid 4960..5004: zero logits
__global__ __launch_bounds__(256) void prep_kernel(
    const float* __restrict__ X, u16* __restrict__ Xb,
    const float* __restrict__ fc1, const float* __restrict__ fc2,
    const float* __restrict__ ew1, const float* __restrict__ ew2,
    const float* __restrict__ tw1, u16* __restrict__ wt,
    u8* __restrict__ w1q, u8* __restrict__ w2q, u8* __restrict__ tw1q,
    const float* __restrict__ wg, u16* __restrict__ WgT,
    float* __restrict__ logits) {
  int bid = blockIdx.x;
  if (bid < 3840) {
    int i = (bid * 256 + threadIdx.x) * 8;
    float4 a = *(const float4*)(X + i);
    float4 b = *(const float4*)(X + i + 4);
    u16x8 v;
    v[0] = f2bf(a.x); v[1] = f2bf(a.y); v[2] = f2bf(a.z); v[3] = f2bf(a.w);
    v[4] = f2bf(b.x); v[5] = f2bf(b.y); v[6] = f2bf(b.z); v[7] = f2bf(b.w);
    *(u16x8*)(Xb + i) = v;
  } else if (bid < 4928) {
    int id = bid - 3840;
    int mid = id >> 6, tile = id & 63;
    const float* src;
    if (mid == 0) src = fc1;
    else if (mid == 1) src = fc2;
    else if (mid < 8) src = ew1 + (size_t)(mid - 2) * 262144;
    else if (mid < 14) src = ew2 + (size_t)(mid - 8) * 262144;
    else src = tw1 + (size_t)(mid - 14) * 262144;
    int tr = (tile >> 3) * 64, tc = (tile & 7) * 64;
    __shared__ float t[64][65];
    int c = threadIdx.x & 63, r0 = threadIdx.x >> 6;
#pragma unroll
    for (int i = 0; i < 16; i++) {
      int r = r0 + i * 4;
      t[r][c] = src[(size_t)(tr + r) * 512 + tc + c];
    }
    __syncthreads();
    if (mid >= 2) {
      // fp8 (x64), k index = tr + c; byte-permuted within each 64B k-group
      u8* dq;
      if (mid < 8) dq = w1q + (size_t)(mid - 2) * 262144;
      else if (mid < 14) dq = w2q + (size_t)(mid - 8) * 262144;
      else dq = tw1q + (size_t)(mid - 14) * 262144;
      int pc = tr + permpos(c);   // tr is a multiple of 64
#pragma unroll
      for (int i = 0; i < 16; i++) {
        int r = r0 + i * 4;
        dq[(size_t)(tc + r) * 512 + pc] = (u8)(cvt2fp8(t[c][r] * 64.f, 0.f) & 0xff);
      }
    } else {
      u16* dst = wt + (size_t)mid * 262144;
#pragma unroll
      for (int i = 0; i < 16; i++) {
        int r = r0 + i * 4;
        dst[(size_t)(tc + r) * 512 + tr + c] = f2bf(t[c][r]);
      }
    }
  } else if (bid < 4960) {
    int col = bid - 4928;
    for (int k = threadIdx.x; k < 512; k += 256) {
      u16 v = 0;
      if (col < 18) {
        int t = col / 6, e = col % 6;
        v = f2bf(wg[(size_t)(t * 512 + k) * 6 + e]);
      }
      WgT[(size_t)col * 512 + k] = v;
    }
  } else {
    int i = (bid - 4960) * 1024 + threadIdx.x * 4;
    float4 z; z.x = 0.f; z.y = 0.f; z.z = 0.f; z.w = 0.f;
    *(float4*)(logits + i) = z;
  }
}

// ---------------- cvt h (bf16) -> hq (fp8 x16, permuted); coalesced ----------------
__global__ __launch_bounds__(256) void cvt_h_kernel(const u16* __restrict__ h,
                                                    u8* __restrict__ hq) {
  int idx = blockIdx.x * 256 + threadIdx.x;   // one 64-elem k-group per thread
  int row = idx >> 3, g = idx & 7;
  const u16* src = h + (size_t)row * 512 + g * 64;
  u8 outb[64];
#pragma unroll
  for (int c = 0; c < 8; c++) {
    u16x8 v = *(const u16x8*)(src + c * 8);
    int base = (c & 3) * 16 + (c & 4) * 2;    // permpos(c*8)
#pragma unroll
    for (int t = 0; t < 8; t += 2) {
      unsigned p = cvt2fp8(bf2f(v[t]) * 16.f, bf2f(v[t + 1]) * 16.f);
      outb[base + t] = (u8)(p & 0xff);
      outb[base + t + 1] = (u8)(p >> 8);
    }
  }
  u8* dst = hq + (size_t)row * 512 + g * 64;
#pragma unroll
  for (int j = 0; j < 4; j++)
    *(u8x16*)(dst + j * 16) = *(const u8x16*)&outb[j * 16];
}

// ===== W1 fp8: 128x256 tile, BK=64, 8 K-steps, triple-buffer counted vmcnt =====
// 512 thr = 8 waves (2M x 4N), wave tile 64x64 (4x4 frags), 32 fp8 MFMAs/step.
// LDS: 3 bufs x (A 128x64B + B 256x64B = 24KB) = 72KB -> 2 blocks/CU.
// Epilogue: descale 1/1024 + eb1 + relu -> ehq fp8 x16 permuted.
__global__ __launch_bounds__(512, 4) void gemm256q(
    const u8* __restrict__ Aq,      // hq [15360][512] fp8 x16 permuted
    const u8* __restrict__ Bq,      // w1q [3072][512] fp8 x64 permuted
    const float* __restrict__ bias, // eb1 [3072]
    u8* __restrict__ Cq,            // ehq [15360][3072] fp8 x16 permuted
    int nby) {
  int nwg = gridDim.x;
  int cpx = nwg >> 3;
  int bid = blockIdx.x;
  int swz = (bid & 7) * cpx + (bid >> 3);
  int bx = swz / nby, by = swz % nby;
  int brow = bx * 128, bcol = by * 256;

  __shared__ __align__(16) u8 SB8[3][24576];  // A 0..8191, B 8192..24575

  int tid = threadIdx.x, lane = tid & 63, w = tid >> 6;
  int wm = w >> 2, wn = w & 3;
  int l = lane & 15, q = lane >> 4;

  int srow = tid >> 2, sc = tid & 3;
  int scX = sc ^ ((srow >> 1) & 3);
  const u8* Ag = Aq + (size_t)(brow + srow) * 512 + scX * 16;
  const u8* Bg0 = Bq + (size_t)(bcol + srow) * 512 + scX * 16;
  const u8* Bg1 = Bg0 + (size_t)128 * 512;
  int lo = w * 1024;

#define STAGEQ(buf, kt)                                \
  do {                                                 \
    gload16(Ag + (kt) * 64, (buf) + lo);               \
    gload16(Bg0 + (kt) * 64, (buf) + 8192 + lo);       \
    gload16(Bg1 + (kt) * 64, (buf) + 16384 + lo);      \
  } while (0)

  f32x4 acc[4][4];
#pragma unroll
  for (int m = 0; m < 4; m++)
#pragma unroll
    for (int n = 0; n < 4; n++) {
      acc[m][n][0] = 0.f; acc[m][n][1] = 0.f; acc[m][n][2] = 0.f; acc[m][n][3] = 0.f;
    }

  int xg = q ^ ((l >> 1) & 3);

  STAGEQ(SB8[0], 0);
  STAGEQ(SB8[1], 1);
  asm volatile("s_waitcnt vmcnt(3)" ::: "memory");
  __builtin_amdgcn_s_barrier();

  u8 *bc = SB8[0], *bn = SB8[1], *bq = SB8[2];
#pragma unroll
  for (int kt = 0; kt < 8; ++kt) {
    if (kt < 6) STAGEQ(bq, kt + 2);
    i64x2 afv[4], bfv[4];
#pragma unroll
    for (int mi = 0; mi < 4; mi++) {
      int row = wm * 64 + mi * 16 + l;
      afv[mi] = *(const i64x2*)&bc[row * 64 + xg * 16];
    }
#pragma unroll
    for (int ni = 0; ni < 4; ni++) {
      int col = wn * 64 + ni * 16 + l;
      bfv[ni] = *(const i64x2*)&bc[8192 + col * 64 + xg * 16];
    }
    __builtin_amdgcn_s_setprio(1);
#pragma unroll
    for (int ks = 0; ks < 2; ++ks)
#pragma unroll
      for (int mi = 0; mi < 4; mi++)
#pragma unroll
        for (int ni = 0; ni < 4; ni++)
          acc[mi][ni] = __builtin_amdgcn_mfma_f32_16x16x32_fp8_fp8(
              afv[mi][ks], bfv[ni][ks], acc[mi][ni], 0, 0, 0);
    __builtin_amdgcn_s_setprio(0);
    asm volatile("s_waitcnt lgkmcnt(0)" ::: "memory");
    if (kt < 6)
      asm volatile("s_waitcnt vmcnt(3)" ::: "memory");
    else
      asm volatile("s_waitcnt vmcnt(0)" ::: "memory");
    __builtin_amdgcn_s_barrier();
    u8* t_ = bc; bc = bn; bn = bq; bq = t_;
  }
#undef STAGEQ

  // epilogue: descale 1/1024, +eb1, relu, x16, fp8 -> LDS (stride 264) -> 16B stores
  u8* S8 = (u8*)&SB8[0][0];   // 128*264 = 33792 B < 73728
  float bvs[4];
#pragma unroll
  for (int n = 0; n < 4; n++) bvs[n] = bias[bcol + wn * 64 + n * 16 + l];
#pragma unroll
  for (int m = 0; m < 4; m++) {
    int rl = wm * 64 + m * 16 + q * 4;
#pragma unroll
    for (int n = 0; n < 4; n++) {
      int pc = wn * 64 + permpos(n * 16 + l);
      float v0 = fmaxf(acc[m][n][0] * 9.765625e-4f + bvs[n], 0.f) * 16.f;
      float v1 = fmaxf(acc[m][n][1] * 9.765625e-4f + bvs[n], 0.f) * 16.f;
      float v2 = fmaxf(acc[m][n][2] * 9.765625e-4f + bvs[n], 0.f) * 16.f;
      float v3 = fmaxf(acc[m][n][3] * 9.765625e-4f + bvs[n], 0.f) * 16.f;
      unsigned p01 = cvt2fp8(v0, v1);
      unsigned p23 = cvt2fp8(v2, v3);
      S8[(rl + 0) * 264 + pc] = (u8)(p01 & 0xff);
      S8[(rl + 1) * 264 + pc] = (u8)(p01 >> 8);
      S8[(rl + 2) * 264 + pc] = (u8)(p23 & 0xff);
      S8[(rl + 3) * 264 + pc] = (u8)(p23 >> 8);
    }
  }
  __syncthreads();
  int row = tid >> 2, cc = tid & 3;
#pragma unroll
  for (int j = 0; j < 4; j++)
    *(u8x16*)&Cq[(size_t)(brow + row) * 3072 + bcol + cc * 64 + j * 16] =
        *(const u8x16*)&S8[row * 264 + cc * 64 + j * 16];
}

// ===== fused W2 + gated combine, fp8 permuted, 2-way-free swizzle =====
// BM=64, BN=128, 256 thr = 4 waves (1M x 4N), wave tile 64x32. BK=64 -> 48 K-steps.
// launch_bounds MUST stay (256,2): (256,4) caps VGPR at 64 -> accumulator spill (R8).
__global__ __launch_bounds__(256, 2) void gemm_w2c(
    const u8* __restrict__ eh,       // [15360][3072] fp8 (x16), permuted
    const u8* __restrict__ W2q,      // [6][512 col][512 k] fp8 (x64), permuted
    const float* __restrict__ eb2,   // [6][512]
    const float* __restrict__ gates, // [(b*3+t)*30+c][6]
    u8* __restrict__ yq) {           // [3][15360][512] fp8 (x32), permuted
  int nwg = gridDim.x, cpx = nwg >> 3;
  int bid = blockIdx.x;
  int swz = (bid & 7) * cpx + (bid >> 3);
  int bx = swz >> 2, by = swz & 3;
  int brow = bx * 64, bcol = by * 128;

  __shared__ __align__(16) u8 SB8[3][12288]; // buf: A 0..4095 (64x64B), B 4096..12287 (128x64B)
  __shared__ u16 glds[64 * 18];

  int tid = threadIdx.x, lane = tid & 63, w = tid >> 6;
  int l = lane & 15, q = lane >> 4;

  for (int i = tid; i < 64 * 18; i += 256) {
    int r = i / 18, te = i % 18;
    int gr = brow + r, b = gr / CDIM, c = gr % CDIM;
    int t = te / 6, e = te % 6;
    glds[i] = f2bf(gates[((size_t)(b * TDIM + t) * CDIM + c) * EDIM + e]);
  }
  float b2all[2][6];
#pragma unroll
  for (int ni = 0; ni < 2; ni++) {
    int col = bcol + w * 32 + ni * 16 + l;
#pragma unroll
    for (int e = 0; e < 6; e++) b2all[ni][e] = eb2[e * 512 + col];
  }

  int srow = tid >> 2, sc = tid & 3;
  int scX = sc ^ ((srow >> 1) & 3);
  const u8* Ag = eh + (size_t)(brow + srow) * 3072 + scX * 16;
  const u8* Bg0 = W2q + (size_t)(bcol + srow) * 512 + scX * 16;
  const u8* Bg1 = Bg0 + (size_t)64 * 512;
  int lo = w * 1024;

#define STAGEW(buf, s2)                                                   \
  do {                                                                    \
    int _e2 = (s2) >> 3, _k2 = (s2) & 7;                                  \
    gload16(Ag + _e2 * 512 + _k2 * 64, (buf) + lo);                       \
    gload16(Bg0 + (size_t)_e2 * 262144 + _k2 * 64, (buf) + 4096 + lo);    \
    gload16(Bg1 + (size_t)_e2 * 262144 + _k2 * 64, (buf) + 8192 + lo);    \
  } while (0)

  f32x4 P[4][2], aY0[4][2], aY1[4][2], aY2[4][2];
#pragma unroll
  for (int mi = 0; mi < 4; mi++)
#pragma unroll
    for (int ni = 0; ni < 2; ni++) {
      P[mi][ni][0] = P[mi][ni][1] = P[mi][ni][2] = P[mi][ni][3] = 0.f;
      aY0[mi][ni] = P[mi][ni]; aY1[mi][ni] = P[mi][ni]; aY2[mi][ni] = P[mi][ni];
    }

  int xg = q ^ ((l >> 1) & 3);

  STAGEW(SB8[0], 0);
  STAGEW(SB8[1], 1);
  asm volatile("s_waitcnt vmcnt(3)" ::: "memory");
  __builtin_amdgcn_s_barrier();

  u8 *bc = SB8[0], *bn = SB8[1], *bq = SB8[2];
  for (int e = 0; e < 6; ++e) {
#pragma unroll
    for (int kt = 0; kt < 8; ++kt) {
      int s = e * 8 + kt;
      if (s < 46) STAGEW(bq, s + 2);
      i64x2 bfv[2], afv[4];
#pragma unroll
      for (int ni = 0; ni < 2; ni++) {
        int col = w * 32 + ni * 16 + l;
        bfv[ni] = *(const i64x2*)&bc[4096 + col * 64 + xg * 16];
      }
#pragma unroll
      for (int mi = 0; mi < 4; mi++) {
        int row = mi * 16 + l;
        afv[mi] = *(const i64x2*)&bc[row * 64 + xg * 16];
      }
      __builtin_amdgcn_s_setprio(1);
#pragma unroll
      for (int ks = 0; ks < 2; ++ks)
#pragma unroll
        for (int mi = 0; mi < 4; mi++)
#pragma unroll
          for (int ni = 0; ni < 2; ni++)
            P[mi][ni] = __builtin_amdgcn_mfma_f32_16x16x32_fp8_fp8(
                afv[mi][ks], bfv[ni][ks], P[mi][ni], 0, 0, 0);
      __builtin_amdgcn_s_setprio(0);
      asm volatile("s_waitcnt lgkmcnt(0)" ::: "memory");
      if (s < 46)
        asm volatile("s_waitcnt vmcnt(3)" ::: "memory");
      else
        asm volatile("s_waitcnt vmcnt(0)" ::: "memory");
      __builtin_amdgcn_s_barrier();
      u8* t_ = bc; bc = bn; bn = bq; bq = t_;
    }
#pragma unroll
    for (int mi = 0; mi < 4; mi++) {
#pragma unroll
      for (int rr = 0; rr < 4; rr++) {
        int row = mi * 16 + q * 4 + rr;
        float g0 = bf2f(glds[row * 18 + e]);
        float g1 = bf2f(glds[row * 18 + 6 + e]);
        float g2 = bf2f(glds[row * 18 + 12 + e]);
#pragma unroll
        for (int ni = 0; ni < 2; ni++) {
          float p = P[mi][ni][rr] * 9.765625e-4f + b2all[ni][e];
          aY0[mi][ni][rr] += g0 * p;
          aY1[mi][ni][rr] += g1 * p;
          aY2[mi][ni][rr] += g2 * p;
          P[mi][ni][rr] = 0.f;
        }
      }
    }
  }
#undef STAGEW

  // epilogue: per task, y -> fp8(x32) at permuted col -> coalesced 16B stores
  u8* S8 = (u8*)&SB8[0][0];
#define EPI(AY, t)                                                          \
  do {                                                                      \
    _Pragma("unroll") for (int mi = 0; mi < 4; mi++) {                      \
      int rl = mi * 16 + q * 4;                                             \
      _Pragma("unroll") for (int ni = 0; ni < 2; ni++) {                    \
        int colL = w * 32 + ni * 16 + l;                                    \
        int pc = (colL & 64) + permpos(colL & 63);                          \
        unsigned p01 = cvt2fp8(AY[mi][ni][0] * 32.f, AY[mi][ni][1] * 32.f); \
        unsigned p23 = cvt2fp8(AY[mi][ni][2] * 32.f, AY[mi][ni][3] * 32.f); \
        S8[(rl + 0) * 144 + pc] = (u8)(p01 & 0xff);                         \
        S8[(rl + 1) * 144 + pc] = (u8)(p01 >> 8);                           \
        S8[(rl + 2) * 144 + pc] = (u8)(p23 & 0xff);                         \
        S8[(rl + 3) * 144 + pc] = (u8)(p23 >> 8);                           \
      }                                                                     \
    }                                                                       \
    __syncthreads();                                                        \
    {                                                                       \
      int row_ = tid >> 2, cc_ = tid & 3;                                   \
      _Pragma("unroll") for (int j = 0; j < 2; j++)                         \
        *(u8x16*)&yq[((size_t)(t) * NROWS + brow + row_) * 512 + bcol +     \
                     j * 64 + cc_ * 16] =                                   \
            *(const u8x16*)&S8[row_ * 144 + j * 64 + cc_ * 16];             \
    }                                                                       \
    __syncthreads();                                                        \
  } while (0)
  EPI(aY0, 0);
  EPI(aY1, 1);
  EPI(aY2, 2);
#undef EPI
}

// ===== tower fp8: th = relu(yq@tw1q/2048 + tb1); logits += th . tw2 =====
__global__ __launch_bounds__(256, 2) void gemm_tower(
    const u8* __restrict__ yq,       // [3][15360][512] fp8 (x32), permuted
    const u8* __restrict__ tw1q,     // [3][512 col][512 k] fp8 (x64), permuted
    const float* __restrict__ tb1, const float* __restrict__ tw2,
    float* __restrict__ logits) {
  int t = blockIdx.z;
  const u8* A = yq + (size_t)t * NROWS * 512;
  const u8* BT = tw1q + (size_t)t * 262144;

  int nwg = gridDim.x, cpx = nwg >> 3;
  int bid = blockIdx.x;
  int swz = (bid & 7) * cpx + (bid >> 3);
  int bx = swz >> 2, by = swz & 3;
  int brow = bx * 64, bcol = by * 128;

  __shared__ __align__(16) u8 SB8[3][12288];

  int tid = threadIdx.x, lane = tid & 63, w = tid >> 6;
  int l = lane & 15, q = lane >> 4;

  int srow = tid >> 2, sc = tid & 3;
  int scX = sc ^ ((srow >> 1) & 3);
  const u8* Ag = A + (size_t)(brow + srow) * 512 + scX * 16;
  const u8* Bg0 = BT + (size_t)(bcol + srow) * 512 + scX * 16;
  const u8* Bg1 = Bg0 + (size_t)64 * 512;
  int lo = w * 1024;

#define STAGET(buf, kt)                                \
  do {                                                 \
    gload16(Ag + (kt) * 64, (buf) + lo);               \
    gload16(Bg0 + (kt) * 64, (buf) + 4096 + lo);       \
    gload16(Bg1 + (kt) * 64, (buf) + 8192 + lo);       \
  } while (0)

  f32x4 P[4][2];
#pragma unroll
  for (int mi = 0; mi < 4; mi++)
#pragma unroll
    for (int ni = 0; ni < 2; ni++) {
      P[mi][ni][0] = 0.f; P[mi][ni][1] = 0.f; P[mi][ni][2] = 0.f; P[mi][ni][3] = 0.f;
    }

  int xg = q ^ ((l >> 1) & 3);

  STAGET(SB8[0], 0);
  STAGET(SB8[1], 1);
  asm volatile("s_waitcnt vmcnt(3)" ::: "memory");
  __builtin_amdgcn_s_barrier();

  u8 *bc = SB8[0], *bn = SB8[1], *bq = SB8[2];
#pragma unroll
  for (int kt = 0; kt < 8; ++kt) {
    if (kt < 6) STAGET(bq, kt + 2);
    i64x2 bfv[2], afv[4];
#pragma unroll
    for (int ni = 0; ni < 2; ni++) {
      int col = w * 32 + ni * 16 + l;
      bfv[ni] = *(const i64x2*)&bc[4096 + col * 64 + xg * 16];
    }
#pragma unroll
    for (int mi = 0; mi < 4; mi++) {
      int row = mi * 16 + l;
      afv[mi] = *(const i64x2*)&bc[row * 64 + xg * 16];
    }
    __builtin_amdgcn_s_setprio(1);
#pragma unroll
    for (int ks = 0; ks < 2; ++ks)
#pragma unroll
      for (int mi = 0; mi < 4; mi++)
#pragma unroll
        for (int ni = 0; ni < 2; ni++)
          P[mi][ni] = __builtin_amdgcn_mfma_f32_16x16x32_fp8_fp8(
              afv[mi][ks], bfv[ni][ks], P[mi][ni], 0, 0, 0);
    __builtin_amdgcn_s_setprio(0);
    asm volatile("s_waitcnt lgkmcnt(0)" ::: "memory");
    if (kt < 6)
      asm volatile("s_waitcnt vmcnt(3)" ::: "memory");
    else
      asm volatile("s_waitcnt vmcnt(0)" ::: "memory");
    __builtin_amdgcn_s_barrier();
    u8* t_ = bc; bc = bn; bn = bq; bq = t_;
  }
#undef STAGET

  float bvs[2], tws[2];
#pragma unroll
  for (int ni = 0; ni < 2; ni++) {
    int col = bcol + w * 32 + ni * 16 + l;
    bvs[ni] = tb1[t * 512 + col];
    tws[ni] = tw2[t * 512 + col];
  }
#pragma unroll
  for (int mi = 0; mi < 4; mi++) {
#pragma unroll
    for (int rr = 0; rr < 4; rr++) {
      float s = 0.f;
#pragma unroll
      for (int ni = 0; ni < 2; ni++) {
        float v = P[mi][ni][rr] * 4.8828125e-4f + bvs[ni];
        v = fmaxf(v, 0.f);
        s += v * tws[ni];
      }
      s += __shfl_xor(s, 1, 64);
      s += __shfl_xor(s, 2, 64);
      s += __shfl_xor(s, 4, 64);
      s += __shfl_xor(s, 8, 64);
      if (l == 0) {
        int row = brow + mi * 16 + q * 4 + rr;
        int b = row / CDIM, c = row % CDIM;
        atomicAdd(&logits[(size_t)(b * TDIM + t) * CDIM + c], s);
      }
    }
  }
}

// ---------------- bf16 MFMA GEMM (m97 structure, 128^2) for fc1/fc2 ----
template <int RELU>
__global__ __launch_bounds__(256, 2) void gemm_bt(
    const u16* __restrict__ A, int lda,
    const u16* __restrict__ BT,
    const float* __restrict__ bias,
    u16* __restrict__ C, int ldc) {
  __shared__ u16 S[8448];
  u16* Al = S;
  u16* Bl = S + 4096;
  int tid = threadIdx.x, lane = tid & 63, w = tid >> 6;
  int wr = w >> 1, wc = w & 1;
  int brow = blockIdx.x * 128, bcol = blockIdx.y * 128;

  int srow = tid >> 2;
  int schunk = tid & 3;
  int srcc = schunk ^ ((srow >> 1) & 3);
  const u16* Ag0 = A + (size_t)(brow + srow) * lda + srcc * 8;
  const u16* Ag1 = A + (size_t)(brow + srow + 64) * lda + srcc * 8;
  const u16* Bg0 = BT + (size_t)(bcol + srow) * KDIM + srcc * 8;
  const u16* Bg1 = BT + (size_t)(bcol + srow + 64) * KDIM + srcc * 8;
  u16* Ald0 = Al + w * 512;
  u16* Ald1 = Al + 2048 + w * 512;
  u16* Bld0 = Bl + w * 512;
  u16* Bld1 = Bl + 2048 + w * 512;

  f32x4 zero; zero[0] = 0.f; zero[1] = 0.f; zero[2] = 0.f; zero[3] = 0.f;
  f32x4 acc[4][4];
#pragma unroll
  for (int m = 0; m < 4; m++)
#pragma unroll
    for (int n = 0; n < 4; n++) acc[m][n] = zero;

  int l = lane & 15, q = lane >> 4;
  int rc = q ^ ((l >> 1) & 3);
  int rbase = wr * 64 + l;
  int cbase = wc * 64 + l;

  for (int kt = 0; kt < 16; ++kt) {
    int ko = kt * 32;
    gload16(Ag0 + ko, Ald0);
    gload16(Ag1 + ko, Ald1);
    gload16(Bg0 + ko, Bld0);
    gload16(Bg1 + ko, Bld1);
    __syncthreads();
    bf16x8 af[4], bfr[4];
#pragma unroll
    for (int m = 0; m < 4; m++) af[m] = *(const bf16x8*)&Al[(rbase + m * 16) * 32 + rc * 8];
#pragma unroll
    for (int n = 0; n < 4; n++) bfr[n] = *(const bf16x8*)&Bl[(cbase + n * 16) * 32 + rc * 8];
#pragma unroll
    for (int m = 0; m < 4; m++)
#pragma unroll
      for (int n = 0; n < 4; n++)
        acc[m][n] = __builtin_amdgcn_mfma_f32_16x16x32_bf16(af[m], bfr[n], acc[m][n], 0, 0, 0);
    __syncthreads();
  }

  int colL = wc * 64 + l;
  float bvs[4];
#pragma unroll
  for (int n = 0; n < 4; n++) bvs[n] = bias[bcol + colL + n * 16];
#pragma unroll
  for (int half = 0; half < 2; half++) {
    if (wr == half) {
#pragma unroll
      for (int m = 0; m < 4; m++) {
        int rl = m * 16 + q * 4;
#pragma unroll
        for (int n = 0; n < 4; n++) {
#pragma unroll
          for (int rr = 0; rr < 4; rr++) {
            float v = acc[m][n][rr] + bvs[n];
            if (RELU) v = fmaxf(v, 0.f);
            S[(rl + rr) * 132 + colL + n * 16] = f2bf(v);
          }
        }
      }
    }
    __syncthreads();
    int row = tid >> 2, cc = tid & 3;
#pragma unroll
    for (int j = 0; j < 4; j++)
      *(u16x8*)&C[(size_t)(brow + half * 64 + row) * ldc + bcol + cc * 32 + j * 8] =
          *(const u16x8*)&S[row * 132 + cc * 32 + j * 8];
    __syncthreads();
  }
}

// ---------------- gate: MFMA skinny GEMM [64 rows/block x 32] + top3 softmax ----
__global__ __launch_bounds__(256) void gate_kernel(const u16* __restrict__ h,
                                                   const u16* __restrict__ WgT,
                                                   float* __restrict__ gates) {
  __shared__ u16 Wl[16 * 32 * 32];
  __shared__ float Gl[4][16][33];
  int tid = threadIdx.x, lane = tid & 63, w = tid >> 6;
  int l = lane & 15, q = lane >> 4;

  for (int idx = tid; idx < 2048; idx += 256) {
    int kt = idx >> 7, col = (idx >> 2) & 31, c = idx & 3;
    int sc = c ^ ((col >> 1) & 3);
    *(u16x8*)&Wl[kt * 1024 + col * 32 + c * 8] =
        *(const u16x8*)&WgT[(size_t)col * 512 + kt * 32 + sc * 8];
  }
  __syncthreads();

  int r = blockIdx.x * 64 + w * 16 + l;
  int ch = q ^ ((l >> 1) & 3);

  f32x4 acc0, acc1;
  acc0[0] = acc0[1] = acc0[2] = acc0[3] = 0.f;
  acc1 = acc0;
#pragma unroll
  for (int kt = 0; kt < 16; ++kt) {
    bf16x8 av = *(const bf16x8*)&h[(size_t)r * 512 + kt * 32 + q * 8];
    bf16x8 b0 = *(const bf16x8*)&Wl[kt * 1024 + l * 32 + ch * 8];
    bf16x8 b1 = *(const bf16x8*)&Wl[kt * 1024 + (16 + l) * 32 + ch * 8];
    acc0 = __builtin_amdgcn_mfma_f32_16x16x32_bf16(av, b0, acc0, 0, 0, 0);
    acc1 = __builtin_amdgcn_mfma_f32_16x16x32_bf16(av, b1, acc1, 0, 0, 0);
  }

#pragma unroll
  for (int rr = 0; rr < 4; rr++) {
    Gl[w][q * 4 + rr][l] = acc0[rr];
    Gl[w][q * 4 + rr][16 + l] = acc1[rr];
  }
  __syncthreads();

  if (lane < 16) {
    int R = blockIdx.x * 64 + w * 16 + lane;
    int b = R / CDIM, c = R % CDIM;
    for (int t = 0; t < 3; t++) {
      float g[6];
#pragma unroll
      for (int e = 0; e < 6; e++) g[e] = Gl[w][lane][t * 6 + e];
      float out[6] = {0, 0, 0, 0, 0, 0};
      int idx[3]; float val[3];
      unsigned used = 0;
      for (int kk = 0; kk < 3; kk++) {
        int best = 0; float bv = -1e30f;
        for (int e = 0; e < 6; e++)
          if (!((used >> e) & 1) && g[e] > bv) { bv = g[e]; best = e; }
        used |= 1u << best; idx[kk] = best; val[kk] = bv;
      }
      float mx = val[0];
      float s = 0.f, ex[3];
      for (int kk = 0; kk < 3; kk++) { ex[kk] = expf(val[kk] - mx); s += ex[kk]; }
      for (int kk = 0; kk < 3; kk++) out[idx[kk]] = ex[kk] / s;
      float* gp = &gates[(size_t)((b * TDIM + t) * CDIM + c) * EDIM];
      for (int e = 0; e < 6; e++) gp[e] = out[e];
    }
  }
}

// ---------------- loss: one wave per b ----------------
__global__ __launch_bounds__(64) void loss_kernel(const float* __restrict__ scores,
                                                  const float* __restrict__ logits,
                                                  const float* __restrict__ gates,
                                                  const float* __restrict__ tb2,
                                                  float* __restrict__ out) {
  int b = blockIdx.x;
  int lane = threadIdx.x;
  float bce_sum = 0.f;
  float aux = 0.f;
  for (int t = 0; t < 3; t++) {
    float sc = (lane < CDIM) ? scores[(size_t)(b * TDIM + t) * CDIM + lane] : -1e30f;
    float mx = sc;
    for (int off = 32; off; off >>= 1) mx = fmaxf(mx, __shfl_xor(mx, off, 64));
    float lab = (lane < CDIM && sc == mx) ? 1.f : 0.f;
    float lg = (lane < CDIM) ? (logits[(size_t)(b * TDIM + t) * CDIM + lane] + tb2[t]) : 0.f;
    float bce = (lane < CDIM) ? (fmaxf(lg, 0.f) - lg * lab + log1pf(expf(-fabsf(lg)))) : 0.f;
    for (int off = 32; off; off >>= 1) bce += __shfl_xor(bce, off, 64);
    bce_sum += bce / (float)CDIM;

    float impv[6];
    float meansum = 0.f;
#pragma unroll
    for (int e = 0; e < 6; e++) {
      float gsum = (lane < CDIM) ? gates[(size_t)((b * TDIM + t) * CDIM + lane) * EDIM + e] : 0.f;
      for (int off = 32; off; off >>= 1) gsum += __shfl_xor(gsum, off, 64);
      impv[e] = gsum;
      meansum += gsum;
    }
    float mean = meansum / 6.f;
    float var = 0.f;
#pragma unroll
    for (int e = 0; e < 6; e++) { float d = impv[e] - mean; var += d * d; }
    var /= 6.f;
    aux += var / (mean * mean + 1e-10f);
  }
  float res = bce_sum / 3.f + 0.01f * aux;
  if (lane == 0) atomicAdd(out, res / (float)BDIM);
}

// ---------------- host ----------------
extern "C" void kernel_launch(void* const* d_in, const int* in_sizes, int n_in,
                              void* d_out, int out_size, void* d_ws, size_t ws_size,
                              hipStream_t stream) {
  const float* X = (const float*)d_in[0];
  const float* scores = (const float*)d_in[1];
  const float* fc1_w = (const float*)d_in[2];
  const float* fc1_b = (const float*)d_in[3];
  const float* fc2_w = (const float*)d_in[4];
  const float* fc2_b = (const float*)d_in[5];
  const float* w_gate = (const float*)d_in[6];
  const float* ew1 = (const float*)d_in[7];
  const float* eb1 = (const float*)d_in[8];
  const float* ew2 = (const float*)d_in[9];
  const float* eb2 = (const float*)d_in[10];
  const float* tw1 = (const float*)d_in[11];
  const float* tb1 = (const float*)d_in[12];
  const float* tw2 = (const float*)d_in[13];
  const float* tb2 = (const float*)d_in[14];
  float* out = (float*)d_out;

  // workspace layout (disjoint)
  u16* WT = (u16*)d_ws;                          // 2 slots bf16 (fc1, fc2)
  u8* w1q = (u8*)(WT + (size_t)2 * 262144);      // 6*262144
  u8* w2q = w1q + (size_t)6 * 262144;            // 6*262144
  u8* tw1q = w2q + (size_t)6 * 262144;           // 3*262144
  u16* WgT = (u16*)(tw1q + (size_t)3 * 262144);  // 32*512
  u8* hq = (u8*)(WgT + (size_t)32 * 512);        // [15360][512] fp8
  u8* ehq = hq + (size_t)NROWS * 512;            // [15360][3072] fp8
  u16* Xb = (u16*)(ehq + (size_t)NROWS * 3072);  // bf16
  u16* A1 = Xb + (size_t)NROWS * 512;
  u16* h = A1 + (size_t)NROWS * 512;
  u8* yq = (u8*)(h + (size_t)NROWS * 512);       // [3][15360][512] fp8
  float* gates = (float*)(yq + (size_t)TDIM * NROWS * 512);
  float* logits = gates + (size_t)BDIM * TDIM * CDIM * EDIM;

  hipMemsetAsync(d_out, 0, sizeof(float) * out_size, stream);

  // merged prep
  prep_kernel<<<5005, 256, 0, stream>>>(X, Xb, fc1_w, fc2_w, ew1, ew2, tw1, WT,
                                        w1q, w2q, tw1q, w_gate, WgT, logits);

  // shared bottom (128^2, N=512)
  gemm_bt<1><<<dim3(120, 4), 256, 0, stream>>>(Xb, 512, WT + (size_t)0 * 262144, fc1_b, A1, 512);
  gemm_bt<0><<<dim3(120, 4), 256, 0, stream>>>(A1, 512, WT + (size_t)1 * 262144, fc2_b, h, 512);

  // h -> fp8 for W1 (gate still reads bf16 h)
  cvt_h_kernel<<<480, 256, 0, stream>>>(h, hq);

  // gating
  gate_kernel<<<240, 256, 0, stream>>>(h, WgT, gates);

  // experts W1 fp8: merged N=3072 (1440 blocks of 128x256, 8 K-steps) -> ehq
  gemm256q<<<dim3(1440, 1, 1), 512, 0, stream>>>(hq, w1q, eb1, ehq, 12);

  // experts W2 + gated combine, fp8 (960 blocks of 64x128, 48 K-steps) -> yq
  gemm_w2c<<<dim3(960, 1, 1), 256, 0, stream>>>(ehq, w2q, eb2, gates, yq);

  // towers fp8 (960 x 3 blocks of 64x128, 8 K-steps) -> logits (atomic)
  gemm_tower<<<dim3(960, 1, 3), 256, 0, stream>>>(yq, tw1q, tb1, tw2, logits);

  // loss
  loss_kernel<<<BDIM, 64, 0, stream>>>(scores, logits, gates, tb2, out);
}

// Round 14
// 206.225 us; speedup vs baseline: 1.5635x; 1.1327x over previous
//
#include <hip/hip_runtime.h>
#include <hip/hip_bf16.h>
#include <cstdint>
#include <cstddef>

typedef unsigned short u16;
typedef unsigned char u8;
typedef long i64;
typedef __bf16 bf16x8 __attribute__((ext_vector_type(8)));
typedef float f32x4 __attribute__((ext_vector_type(4)));
typedef u16 u16x8 __attribute__((ext_vector_type(8)));
typedef u8 u8x16 __attribute__((ext_vector_type(16)));
typedef i64 i64x2 __attribute__((ext_vector_type(2)));

#define NROWS 15360   // B*C = 512*30
#define KDIM 512
#define BDIM 512
#define CDIM 30
#define TDIM 3
#define EDIM 6

typedef __attribute__((address_space(1))) const unsigned int gu32;
typedef __attribute__((address_space(3))) unsigned int lu32;

__device__ __forceinline__ void gload16(const void* g, void* l) {
  __builtin_amdgcn_global_load_lds((gu32*)g, (lu32*)l, 16, 0, 0);
}

__device__ __forceinline__ float bf2f(u16 u) {
  union { unsigned i; float f; } v; v.i = ((unsigned)u) << 16; return v.f;
}
__device__ __forceinline__ u16 f2bf(float f) {
  union { float f; unsigned i; } v; v.f = f;
  unsigned r = v.i + 0x7fffu + ((v.i >> 16) & 1u);
  return (u16)(r >> 16);
}
// fp8 e4m3fn encode, software fallback
__device__ __forceinline__ u8 f2fp8_sw(float v) {
  union { float f; unsigned u; } x; x.f = v;
  unsigned s = (x.u >> 24) & 0x80;
  x.u &= 0x7fffffffu;
  if (x.f < 0.0009765625f) return (u8)s;
  if (x.f > 448.f) return (u8)(s | 0x7e);
  int e; float m = frexpf(x.f, &e);
  if (e < -5) {
    int qq = (int)(x.f * 512.f + 0.5f);
    return (u8)(s | qq);
  }
  int qq = (int)(m * 16.f + 0.5f);
  if (qq == 16) { qq = 8; e++; }
  int E = e + 6;
  if (E >= 16 || (E == 15 && qq - 8 == 7)) return (u8)(s | 0x7e);
  return (u8)(s | (E << 3) | (qq - 8));
}
__device__ __forceinline__ unsigned cvt2fp8(float a, float b) {
#if __has_builtin(__builtin_amdgcn_cvt_pk_fp8_f32)
  return (unsigned)__builtin_amdgcn_cvt_pk_fp8_f32(a, b, 0, false) & 0xffffu;
#else
  return (unsigned)f2fp8_sw(a) | ((unsigned)f2fp8_sw(b) << 8);
#endif
}
// within-64B-group byte permutation: chunk q = {ks0 granule q (8B)} ++ {ks1 granule q (8B)}
__device__ __forceinline__ int permpos(int j) {
  return ((j & 24) << 1) + ((j & 32) >> 2) + (j & 7);
}

// ---------------- merged prep ----------------
// bid 0..3839: cvt X fp32 -> fp8 x16 permuted (one 8-elem granule per thread)
// bid 3840..4927: weight tiles -> fp8 x64 permuted (fc1,fc2,w1,w2,tw1)
// bid 4928..4959: gate weight col (WgT [32][512] bf16, cols 18..31 zero)
// bid 4960..5004: zero logits
__global__ __launch_bounds__(256) void prep_kernel(
    const float* __restrict__ X, u8* __restrict__ Xq,
    const float* __restrict__ fc1, const float* __restrict__ fc2,
    const float* __restrict__ ew1, const float* __restrict__ ew2,
    const float* __restrict__ tw1,
    u8* __restrict__ fc1q, u8* __restrict__ fc2q,
    u8* __restrict__ w1q, u8* __restrict__ w2q, u8* __restrict__ tw1q,
    const float* __restrict__ wg, u16* __restrict__ WgT,
    float* __restrict__ logits) {
  int bid = blockIdx.x;
  if (bid < 3840) {
    int i = bid * 256 + threadIdx.x;          // granule id (8 elems)
    float4 a = *(const float4*)(X + (size_t)i * 8);
    float4 b = *(const float4*)(X + (size_t)i * 8 + 4);
    unsigned p0 = cvt2fp8(a.x * 16.f, a.y * 16.f);
    unsigned p1 = cvt2fp8(a.z * 16.f, a.w * 16.f);
    unsigned p2 = cvt2fp8(b.x * 16.f, b.y * 16.f);
    unsigned p3 = cvt2fp8(b.z * 16.f, b.w * 16.f);
    int row = i >> 6, g = i & 63;
    int pos = (g >> 3) * 64 + (g & 3) * 16 + (g & 4) * 2;  // permpos of granule start
    u8* dst = Xq + (size_t)row * 512 + pos;
    *(unsigned*)dst = p0 | (p1 << 16);
    *(unsigned*)(dst + 4) = p2 | (p3 << 16);
  } else if (bid < 4928) {
    int id = bid - 3840;
    int mid = id >> 6, tile = id & 63;
    const float* src;
    if (mid == 0) src = fc1;
    else if (mid == 1) src = fc2;
    else if (mid < 8) src = ew1 + (size_t)(mid - 2) * 262144;
    else if (mid < 14) src = ew2 + (size_t)(mid - 8) * 262144;
    else src = tw1 + (size_t)(mid - 14) * 262144;
    int tr = (tile >> 3) * 64, tc = (tile & 7) * 64;
    __shared__ float t[64][65];
    int c = threadIdx.x & 63, r0 = threadIdx.x >> 6;
#pragma unroll
    for (int i = 0; i < 16; i++) {
      int r = r0 + i * 4;
      t[r][c] = src[(size_t)(tr + r) * 512 + tc + c];
    }
    __syncthreads();
    u8* dq;
    if (mid == 0) dq = fc1q;
    else if (mid == 1) dq = fc2q;
    else if (mid < 8) dq = w1q + (size_t)(mid - 2) * 262144;
    else if (mid < 14) dq = w2q + (size_t)(mid - 8) * 262144;
    else dq = tw1q + (size_t)(mid - 14) * 262144;
    int pc = tr + permpos(c);   // tr is a multiple of 64
#pragma unroll
    for (int i = 0; i < 16; i++) {
      int r = r0 + i * 4;
      dq[(size_t)(tc + r) * 512 + pc] = (u8)(cvt2fp8(t[c][r] * 64.f, 0.f) & 0xff);
    }
  } else if (bid < 4960) {
    int col = bid - 4928;
    for (int k = threadIdx.x; k < 512; k += 256) {
      u16 v = 0;
      if (col < 18) {
        int t = col / 6, e = col % 6;
        v = f2bf(wg[(size_t)(t * 512 + k) * 6 + e]);
      }
      WgT[(size_t)col * 512 + k] = v;
    }
  } else {
    int i = (bid - 4960) * 1024 + threadIdx.x * 4;
    float4 z; z.x = 0.f; z.y = 0.f; z.z = 0.f; z.w = 0.f;
    *(float4*)(logits + i) = z;
  }
}

// ===== generic fp8 GEMM, BM=64 BN=128 BK=64, 8 K-steps (tower-proven template) =====
// DUAL=0: Cq = fp8(relu(P/1024 + bias) * 16)  (fc1 -> A1q)
// DUAL=1: Ch = bf16(P/1024 + bias), Cq = fp8(Ch * 16)  (fc2 -> h, hq; no relu)
template <int DUAL>
__global__ __launch_bounds__(256, 2) void gemm_s8(
    const u8* __restrict__ Aq,      // [M][512] fp8 x16 permuted
    const u8* __restrict__ Bq,      // [512 col][512 k] fp8 x64 permuted
    const float* __restrict__ bias,
    u8* __restrict__ Cq,            // [M][512] fp8 x16 permuted
    u16* __restrict__ Ch) {         // [M][512] bf16 (DUAL only)
  int nwg = gridDim.x, cpx = nwg >> 3;
  int bid = blockIdx.x;
  int swz = (bid & 7) * cpx + (bid >> 3);
  int bx = swz >> 2, by = swz & 3;
  int brow = bx * 64, bcol = by * 128;

  __shared__ __align__(16) u8 SB8[3][12288];

  int tid = threadIdx.x, lane = tid & 63, w = tid >> 6;
  int l = lane & 15, q = lane >> 4;

  int srow = tid >> 2, sc = tid & 3;
  int scX = sc ^ ((srow >> 1) & 3);
  const u8* Ag = Aq + (size_t)(brow + srow) * 512 + scX * 16;
  const u8* Bg0 = Bq + (size_t)(bcol + srow) * 512 + scX * 16;
  const u8* Bg1 = Bg0 + (size_t)64 * 512;
  int lo = w * 1024;

#define STAGES(buf, kt)                                \
  do {                                                 \
    gload16(Ag + (kt) * 64, (buf) + lo);               \
    gload16(Bg0 + (kt) * 64, (buf) + 4096 + lo);       \
    gload16(Bg1 + (kt) * 64, (buf) + 8192 + lo);       \
  } while (0)

  f32x4 P[4][2];
#pragma unroll
  for (int mi = 0; mi < 4; mi++)
#pragma unroll
    for (int ni = 0; ni < 2; ni++) {
      P[mi][ni][0] = 0.f; P[mi][ni][1] = 0.f; P[mi][ni][2] = 0.f; P[mi][ni][3] = 0.f;
    }

  int xg = q ^ ((l >> 1) & 3);

  STAGES(SB8[0], 0);
  STAGES(SB8[1], 1);
  asm volatile("s_waitcnt vmcnt(3)" ::: "memory");
  __builtin_amdgcn_s_barrier();

  u8 *bc = SB8[0], *bn = SB8[1], *bq = SB8[2];
#pragma unroll
  for (int kt = 0; kt < 8; ++kt) {
    if (kt < 6) STAGES(bq, kt + 2);
    i64x2 bfv[2], afv[4];
#pragma unroll
    for (int ni = 0; ni < 2; ni++) {
      int col = w * 32 + ni * 16 + l;
      bfv[ni] = *(const i64x2*)&bc[4096 + col * 64 + xg * 16];
    }
#pragma unroll
    for (int mi = 0; mi < 4; mi++) {
      int row = mi * 16 + l;
      afv[mi] = *(const i64x2*)&bc[row * 64 + xg * 16];
    }
    __builtin_amdgcn_s_setprio(1);
#pragma unroll
    for (int ks = 0; ks < 2; ++ks)
#pragma unroll
      for (int mi = 0; mi < 4; mi++)
#pragma unroll
        for (int ni = 0; ni < 2; ni++)
          P[mi][ni] = __builtin_amdgcn_mfma_f32_16x16x32_fp8_fp8(
              afv[mi][ks], bfv[ni][ks], P[mi][ni], 0, 0, 0);
    __builtin_amdgcn_s_setprio(0);
    asm volatile("s_waitcnt lgkmcnt(0)" ::: "memory");
    if (kt < 6)
      asm volatile("s_waitcnt vmcnt(3)" ::: "memory");
    else
      asm volatile("s_waitcnt vmcnt(0)" ::: "memory");
    __builtin_amdgcn_s_barrier();
    u8* t_ = bc; bc = bn; bn = bq; bq = t_;
  }
#undef STAGES

  float bvs[2];
#pragma unroll
  for (int ni = 0; ni < 2; ni++) bvs[ni] = bias[bcol + w * 32 + ni * 16 + l];

  // fp8 output (both modes): value v = P/1024 + bias (+relu for DUAL=0), x16
  u8* S8 = (u8*)&SB8[0][0];   // 64*144 = 9216 B
#pragma unroll
  for (int mi = 0; mi < 4; mi++) {
    int rl = mi * 16 + q * 4;
#pragma unroll
    for (int ni = 0; ni < 2; ni++) {
      int colL = w * 32 + ni * 16 + l;
      int pc = (colL & 64) + permpos(colL & 63);
      float v[4];
#pragma unroll
      for (int rr = 0; rr < 4; rr++) {
        float x = P[mi][ni][rr] * 9.765625e-4f + bvs[ni];
        if (!DUAL) x = fmaxf(x, 0.f);
        v[rr] = x;
      }
      unsigned p01 = cvt2fp8(v[0] * 16.f, v[1] * 16.f);
      unsigned p23 = cvt2fp8(v[2] * 16.f, v[3] * 16.f);
      S8[(rl + 0) * 144 + pc] = (u8)(p01 & 0xff);
      S8[(rl + 1) * 144 + pc] = (u8)(p01 >> 8);
      S8[(rl + 2) * 144 + pc] = (u8)(p23 & 0xff);
      S8[(rl + 3) * 144 + pc] = (u8)(p23 >> 8);
    }
  }
  __syncthreads();
  {
    int row_ = tid >> 2, cc_ = tid & 3;
#pragma unroll
    for (int j = 0; j < 2; j++)
      *(u8x16*)&Cq[(size_t)(brow + row_) * 512 + bcol + j * 64 + cc_ * 16] =
          *(const u8x16*)&S8[row_ * 144 + j * 64 + cc_ * 16];
  }
  if (DUAL) {
    __syncthreads();
    u16* Sst = (u16*)&SB8[0][0];   // 64*136*2 = 17408 B < 36864
#pragma unroll
    for (int mi = 0; mi < 4; mi++) {
      int rl = mi * 16 + q * 4;
#pragma unroll
      for (int ni = 0; ni < 2; ni++) {
        int colL = w * 32 + ni * 16 + l;
#pragma unroll
        for (int rr = 0; rr < 4; rr++) {
          float x = P[mi][ni][rr] * 9.765625e-4f + bvs[ni];
          Sst[(rl + rr) * 136 + colL] = f2bf(x);
        }
      }
    }
    __syncthreads();
    int row_ = tid >> 2, cc_ = tid & 3;
#pragma unroll
    for (int j = 0; j < 4; j++)
      *(u16x8*)&Ch[(size_t)(brow + row_) * 512 + bcol + cc_ * 32 + j * 8] =
          *(const u16x8*)&Sst[row_ * 136 + cc_ * 32 + j * 8];
  }
}

// ===== W1 fp8: 128x256 tile, BK=64, 8 K-steps, triple-buffer counted vmcnt =====
__global__ __launch_bounds__(512, 4) void gemm256q(
    const u8* __restrict__ Aq,      // hq [15360][512] fp8 x16 permuted
    const u8* __restrict__ Bq,      // w1q [3072][512] fp8 x64 permuted
    const float* __restrict__ bias, // eb1 [3072]
    u8* __restrict__ Cq,            // ehq [15360][3072] fp8 x16 permuted
    int nby) {
  int nwg = gridDim.x;
  int cpx = nwg >> 3;
  int bid = blockIdx.x;
  int swz = (bid & 7) * cpx + (bid >> 3);
  int bx = swz / nby, by = swz % nby;
  int brow = bx * 128, bcol = by * 256;

  __shared__ __align__(16) u8 SB8[3][24576];  // A 0..8191, B 8192..24575

  int tid = threadIdx.x, lane = tid & 63, w = tid >> 6;
  int wm = w >> 2, wn = w & 3;
  int l = lane & 15, q = lane >> 4;

  int srow = tid >> 2, sc = tid & 3;
  int scX = sc ^ ((srow >> 1) & 3);
  const u8* Ag = Aq + (size_t)(brow + srow) * 512 + scX * 16;
  const u8* Bg0 = Bq + (size_t)(bcol + srow) * 512 + scX * 16;
  const u8* Bg1 = Bg0 + (size_t)128 * 512;
  int lo = w * 1024;

#define STAGEQ(buf, kt)                                \
  do {                                                 \
    gload16(Ag + (kt) * 64, (buf) + lo);               \
    gload16(Bg0 + (kt) * 64, (buf) + 8192 + lo);       \
    gload16(Bg1 + (kt) * 64, (buf) + 16384 + lo);      \
  } while (0)

  f32x4 acc[4][4];
#pragma unroll
  for (int m = 0; m < 4; m++)
#pragma unroll
    for (int n = 0; n < 4; n++) {
      acc[m][n][0] = 0.f; acc[m][n][1] = 0.f; acc[m][n][2] = 0.f; acc[m][n][3] = 0.f;
    }

  int xg = q ^ ((l >> 1) & 3);

  STAGEQ(SB8[0], 0);
  STAGEQ(SB8[1], 1);
  asm volatile("s_waitcnt vmcnt(3)" ::: "memory");
  __builtin_amdgcn_s_barrier();

  u8 *bc = SB8[0], *bn = SB8[1], *bq = SB8[2];
#pragma unroll
  for (int kt = 0; kt < 8; ++kt) {
    if (kt < 6) STAGEQ(bq, kt + 2);
    i64x2 afv[4], bfv[4];
#pragma unroll
    for (int mi = 0; mi < 4; mi++) {
      int row = wm * 64 + mi * 16 + l;
      afv[mi] = *(const i64x2*)&bc[row * 64 + xg * 16];
    }
#pragma unroll
    for (int ni = 0; ni < 4; ni++) {
      int col = wn * 64 + ni * 16 + l;
      bfv[ni] = *(const i64x2*)&bc[8192 + col * 64 + xg * 16];
    }
    __builtin_amdgcn_s_setprio(1);
#pragma unroll
    for (int ks = 0; ks < 2; ++ks)
#pragma unroll
      for (int mi = 0; mi < 4; mi++)
#pragma unroll
        for (int ni = 0; ni < 4; ni++)
          acc[mi][ni] = __builtin_amdgcn_mfma_f32_16x16x32_fp8_fp8(
              afv[mi][ks], bfv[ni][ks], acc[mi][ni], 0, 0, 0);
    __builtin_amdgcn_s_setprio(0);
    asm volatile("s_waitcnt lgkmcnt(0)" ::: "memory");
    if (kt < 6)
      asm volatile("s_waitcnt vmcnt(3)" ::: "memory");
    else
      asm volatile("s_waitcnt vmcnt(0)" ::: "memory");
    __builtin_amdgcn_s_barrier();
    u8* t_ = bc; bc = bn; bn = bq; bq = t_;
  }
#undef STAGEQ

  u8* S8 = (u8*)&SB8[0][0];   // 128*264 = 33792 B < 73728
  float bvs[4];
#pragma unroll
  for (int n = 0; n < 4; n++) bvs[n] = bias[bcol + wn * 64 + n * 16 + l];
#pragma unroll
  for (int m = 0; m < 4; m++) {
    int rl = wm * 64 + m * 16 + q * 4;
#pragma unroll
    for (int n = 0; n < 4; n++) {
      int pc = wn * 64 + permpos(n * 16 + l);
      float v0 = fmaxf(acc[m][n][0] * 9.765625e-4f + bvs[n], 0.f) * 16.f;
      float v1 = fmaxf(acc[m][n][1] * 9.765625e-4f + bvs[n], 0.f) * 16.f;
      float v2 = fmaxf(acc[m][n][2] * 9.765625e-4f + bvs[n], 0.f) * 16.f;
      float v3 = fmaxf(acc[m][n][3] * 9.765625e-4f + bvs[n], 0.f) * 16.f;
      unsigned p01 = cvt2fp8(v0, v1);
      unsigned p23 = cvt2fp8(v2, v3);
      S8[(rl + 0) * 264 + pc] = (u8)(p01 & 0xff);
      S8[(rl + 1) * 264 + pc] = (u8)(p01 >> 8);
      S8[(rl + 2) * 264 + pc] = (u8)(p23 & 0xff);
      S8[(rl + 3) * 264 + pc] = (u8)(p23 >> 8);
    }
  }
  __syncthreads();
  int row = tid >> 2, cc = tid & 3;
#pragma unroll
  for (int j = 0; j < 4; j++)
    *(u8x16*)&Cq[(size_t)(brow + row) * 3072 + bcol + cc * 64 + j * 16] =
        *(const u8x16*)&S8[row * 264 + cc * 64 + j * 16];
}

// ===== fused W2 + gated combine, fp8 permuted, 2-way-free swizzle =====
// launch_bounds MUST stay (256,2): (256,4) caps VGPR at 64 -> accumulator spill (R8).
__global__ __launch_bounds__(256, 2) void gemm_w2c(
    const u8* __restrict__ eh,       // [15360][3072] fp8 (x16), permuted
    const u8* __restrict__ W2q,      // [6][512 col][512 k] fp8 (x64), permuted
    const float* __restrict__ eb2,   // [6][512]
    const float* __restrict__ gates, // [(b*3+t)*30+c][6]
    u8* __restrict__ yq) {           // [3][15360][512] fp8 (x32), permuted
  int nwg = gridDim.x, cpx = nwg >> 3;
  int bid = blockIdx.x;
  int swz = (bid & 7) * cpx + (bid >> 3);
  int bx = swz >> 2, by = swz & 3;
  int brow = bx * 64, bcol = by * 128;

  __shared__ __align__(16) u8 SB8[3][12288];
  __shared__ u16 glds[64 * 18];

  int tid = threadIdx.x, lane = tid & 63, w = tid >> 6;
  int l = lane & 15, q = lane >> 4;

  for (int i = tid; i < 64 * 18; i += 256) {
    int r = i / 18, te = i % 18;
    int gr = brow + r, b = gr / CDIM, c = gr % CDIM;
    int t = te / 6, e = te % 6;
    glds[i] = f2bf(gates[((size_t)(b * TDIM + t) * CDIM + c) * EDIM + e]);
  }
  float b2all[2][6];
#pragma unroll
  for (int ni = 0; ni < 2; ni++) {
    int col = bcol + w * 32 + ni * 16 + l;
#pragma unroll
    for (int e = 0; e < 6; e++) b2all[ni][e] = eb2[e * 512 + col];
  }

  int srow = tid >> 2, sc = tid & 3;
  int scX = sc ^ ((srow >> 1) & 3);
  const u8* Ag = eh + (size_t)(brow + srow) * 3072 + scX * 16;
  const u8* Bg0 = W2q + (size_t)(bcol + srow) * 512 + scX * 16;
  const u8* Bg1 = Bg0 + (size_t)64 * 512;
  int lo = w * 1024;

#define STAGEW(buf, s2)                                                   \
  do {                                                                    \
    int _e2 = (s2) >> 3, _k2 = (s2) & 7;                                  \
    gload16(Ag + _e2 * 512 + _k2 * 64, (buf) + lo);                       \
    gload16(Bg0 + (size_t)_e2 * 262144 + _k2 * 64, (buf) + 4096 + lo);    \
    gload16(Bg1 + (size_t)_e2 * 262144 + _k2 * 64, (buf) + 8192 + lo);    \
  } while (0)

  f32x4 P[4][2], aY0[4][2], aY1[4][2], aY2[4][2];
#pragma unroll
  for (int mi = 0; mi < 4; mi++)
#pragma unroll
    for (int ni = 0; ni < 2; ni++) {
      P[mi][ni][0] = P[mi][ni][1] = P[mi][ni][2] = P[mi][ni][3] = 0.f;
      aY0[mi][ni] = P[mi][ni]; aY1[mi][ni] = P[mi][ni]; aY2[mi][ni] = P[mi][ni];
    }

  int xg = q ^ ((l >> 1) & 3);

  STAGEW(SB8[0], 0);
  STAGEW(SB8[1], 1);
  asm volatile("s_waitcnt vmcnt(3)" ::: "memory");
  __builtin_amdgcn_s_barrier();

  u8 *bc = SB8[0], *bn = SB8[1], *bq = SB8[2];
  for (int e = 0; e < 6; ++e) {
#pragma unroll
    for (int kt = 0; kt < 8; ++kt) {
      int s = e * 8 + kt;
      if (s < 46) STAGEW(bq, s + 2);
      i64x2 bfv[2], afv[4];
#pragma unroll
      for (int ni = 0; ni < 2; ni++) {
        int col = w * 32 + ni * 16 + l;
        bfv[ni] = *(const i64x2*)&bc[4096 + col * 64 + xg * 16];
      }
#pragma unroll
      for (int mi = 0; mi < 4; mi++) {
        int row = mi * 16 + l;
        afv[mi] = *(const i64x2*)&bc[row * 64 + xg * 16];
      }
      __builtin_amdgcn_s_setprio(1);
#pragma unroll
      for (int ks = 0; ks < 2; ++ks)
#pragma unroll
        for (int mi = 0; mi < 4; mi++)
#pragma unroll
          for (int ni = 0; ni < 2; ni++)
            P[mi][ni] = __builtin_amdgcn_mfma_f32_16x16x32_fp8_fp8(
                afv[mi][ks], bfv[ni][ks], P[mi][ni], 0, 0, 0);
      __builtin_amdgcn_s_setprio(0);
      asm volatile("s_waitcnt lgkmcnt(0)" ::: "memory");
      if (s < 46)
        asm volatile("s_waitcnt vmcnt(3)" ::: "memory");
      else
        asm volatile("s_waitcnt vmcnt(0)" ::: "memory");
      __builtin_amdgcn_s_barrier();
      u8* t_ = bc; bc = bn; bn = bq; bq = t_;
    }
#pragma unroll
    for (int mi = 0; mi < 4; mi++) {
#pragma unroll
      for (int rr = 0; rr < 4; rr++) {
        int row = mi * 16 + q * 4 + rr;
        float g0 = bf2f(glds[row * 18 + e]);
        float g1 = bf2f(glds[row * 18 + 6 + e]);
        float g2 = bf2f(glds[row * 18 + 12 + e]);
#pragma unroll
        for (int ni = 0; ni < 2; ni++) {
          float p = P[mi][ni][rr] * 9.765625e-4f + b2all[ni][e];
          aY0[mi][ni][rr] += g0 * p;
          aY1[mi][ni][rr] += g1 * p;
          aY2[mi][ni][rr] += g2 * p;
          P[mi][ni][rr] = 0.f;
        }
      }
    }
  }
#undef STAGEW

  u8* S8 = (u8*)&SB8[0][0];
#define EPI(AY, t)                                                          \
  do {                                                                      \
    _Pragma("unroll") for (int mi = 0; mi < 4; mi++) {                      \
      int rl = mi * 16 + q * 4;                                             \
      _Pragma("unroll") for (int ni = 0; ni < 2; ni++) {                    \
        int colL = w * 32 + ni * 16 + l;                                    \
        int pc = (colL & 64) + permpos(colL & 63);                          \
        unsigned p01 = cvt2fp8(AY[mi][ni][0] * 32.f, AY[mi][ni][1] * 32.f); \
        unsigned p23 = cvt2fp8(AY[mi][ni][2] * 32.f, AY[mi][ni][3] * 32.f); \
        S8[(rl + 0) * 144 + pc] = (u8)(p01 & 0xff);                         \
        S8[(rl + 1) * 144 + pc] = (u8)(p01 >> 8);                           \
        S8[(rl + 2) * 144 + pc] = (u8)(p23 & 0xff);                         \
        S8[(rl + 3) * 144 + pc] = (u8)(p23 >> 8);                           \
      }                                                                     \
    }                                                                       \
    __syncthreads();                                                        \
    {                                                                       \
      int row_ = tid >> 2, cc_ = tid & 3;                                   \
      _Pragma("unroll") for (int j = 0; j < 2; j++)                         \
        *(u8x16*)&yq[((size_t)(t) * NROWS + brow + row_) * 512 + bcol +     \
                     j * 64 + cc_ * 16] =                                   \
            *(const u8x16*)&S8[row_ * 144 + j * 64 + cc_ * 16];             \
    }                                                                       \
    __syncthreads();                                                        \
  } while (0)
  EPI(aY0, 0);
  EPI(aY1, 1);
  EPI(aY2, 2);
#undef EPI
}

// ===== tower fp8: th = relu(yq@tw1q/2048 + tb1); logits += th . tw2 =====
__global__ __launch_bounds__(256, 2) void gemm_tower(
    const u8* __restrict__ yq,       // [3][15360][512] fp8 (x32), permuted
    const u8* __restrict__ tw1q,     // [3][512 col][512 k] fp8 (x64), permuted
    const float* __restrict__ tb1, const float* __restrict__ tw2,
    float* __restrict__ logits) {
  int t = blockIdx.z;
  const u8* A = yq + (size_t)t * NROWS * 512;
  const u8* BT = tw1q + (size_t)t * 262144;

  int nwg = gridDim.x, cpx = nwg >> 3;
  int bid = blockIdx.x;
  int swz = (bid & 7) * cpx + (bid >> 3);
  int bx = swz >> 2, by = swz & 3;
  int brow = bx * 64, bcol = by * 128;

  __shared__ __align__(16) u8 SB8[3][12288];

  int tid = threadIdx.x, lane = tid & 63, w = tid >> 6;
  int l = lane & 15, q = lane >> 4;

  int srow = tid >> 2, sc = tid & 3;
  int scX = sc ^ ((srow >> 1) & 3);
  const u8* Ag = A + (size_t)(brow + srow) * 512 + scX * 16;
  const u8* Bg0 = BT + (size_t)(bcol + srow) * 512 + scX * 16;
  const u8* Bg1 = Bg0 + (size_t)64 * 512;
  int lo = w * 1024;

#define STAGET(buf, kt)                                \
  do {                                                 \
    gload16(Ag + (kt) * 64, (buf) + lo);               \
    gload16(Bg0 + (kt) * 64, (buf) + 4096 + lo);       \
    gload16(Bg1 + (kt) * 64, (buf) + 8192 + lo);       \
  } while (0)

  f32x4 P[4][2];
#pragma unroll
  for (int mi = 0; mi < 4; mi++)
#pragma unroll
    for (int ni = 0; ni < 2; ni++) {
      P[mi][ni][0] = 0.f; P[mi][ni][1] = 0.f; P[mi][ni][2] = 0.f; P[mi][ni][3] = 0.f;
    }

  int xg = q ^ ((l >> 1) & 3);

  STAGET(SB8[0], 0);
  STAGET(SB8[1], 1);
  asm volatile("s_waitcnt vmcnt(3)" ::: "memory");
  __builtin_amdgcn_s_barrier();

  u8 *bc = SB8[0], *bn = SB8[1], *bq = SB8[2];
#pragma unroll
  for (int kt = 0; kt < 8; ++kt) {
    if (kt < 6) STAGET(bq, kt + 2);
    i64x2 bfv[2], afv[4];
#pragma unroll
    for (int ni = 0; ni < 2; ni++) {
      int col = w * 32 + ni * 16 + l;
      bfv[ni] = *(const i64x2*)&bc[4096 + col * 64 + xg * 16];
    }
#pragma unroll
    for (int mi = 0; mi < 4; mi++) {
      int row = mi * 16 + l;
      afv[mi] = *(const i64x2*)&bc[row * 64 + xg * 16];
    }
    __builtin_amdgcn_s_setprio(1);
#pragma unroll
    for (int ks = 0; ks < 2; ++ks)
#pragma unroll
      for (int mi = 0; mi < 4; mi++)
#pragma unroll
        for (int ni = 0; ni < 2; ni++)
          P[mi][ni] = __builtin_amdgcn_mfma_f32_16x16x32_fp8_fp8(
              afv[mi][ks], bfv[ni][ks], P[mi][ni], 0, 0, 0);
    __builtin_amdgcn_s_setprio(0);
    asm volatile("s_waitcnt lgkmcnt(0)" ::: "memory");
    if (kt < 6)
      asm volatile("s_waitcnt vmcnt(3)" ::: "memory");
    else
      asm volatile("s_waitcnt vmcnt(0)" ::: "memory");
    __builtin_amdgcn_s_barrier();
    u8* t_ = bc; bc = bn; bn = bq; bq = t_;
  }
#undef STAGET

  float bvs[2], tws[2];
#pragma unroll
  for (int ni = 0; ni < 2; ni++) {
    int col = bcol + w * 32 + ni * 16 + l;
    bvs[ni] = tb1[t * 512 + col];
    tws[ni] = tw2[t * 512 + col];
  }
#pragma unroll
  for (int mi = 0; mi < 4; mi++) {
#pragma unroll
    for (int rr = 0; rr < 4; rr++) {
      float s = 0.f;
#pragma unroll
      for (int ni = 0; ni < 2; ni++) {
        float v = P[mi][ni][rr] * 4.8828125e-4f + bvs[ni];
        v = fmaxf(v, 0.f);
        s += v * tws[ni];
      }
      s += __shfl_xor(s, 1, 64);
      s += __shfl_xor(s, 2, 64);
      s += __shfl_xor(s, 4, 64);
      s += __shfl_xor(s, 8, 64);
      if (l == 0) {
        int row = brow + mi * 16 + q * 4 + rr;
        int b = row / CDIM, c = row % CDIM;
        atomicAdd(&logits[(size_t)(b * TDIM + t) * CDIM + c], s);
      }
    }
  }
}

// ---------------- gate: MFMA skinny GEMM [64 rows/block x 32] + top3 softmax ----
__global__ __launch_bounds__(256) void gate_kernel(const u16* __restrict__ h,
                                                   const u16* __restrict__ WgT,
                                                   float* __restrict__ gates) {
  __shared__ u16 Wl[16 * 32 * 32];
  __shared__ float Gl[4][16][33];
  int tid = threadIdx.x, lane = tid & 63, w = tid >> 6;
  int l = lane & 15, q = lane >> 4;

  for (int idx = tid; idx < 2048; idx += 256) {
    int kt = idx >> 7, col = (idx >> 2) & 31, c = idx & 3;
    int sc = c ^ ((col >> 1) & 3);
    *(u16x8*)&Wl[kt * 1024 + col * 32 + c * 8] =
        *(const u16x8*)&WgT[(size_t)col * 512 + kt * 32 + sc * 8];
  }
  __syncthreads();

  int r = blockIdx.x * 64 + w * 16 + l;
  int ch = q ^ ((l >> 1) & 3);

  f32x4 acc0, acc1;
  acc0[0] = acc0[1] = acc0[2] = acc0[3] = 0.f;
  acc1 = acc0;
#pragma unroll
  for (int kt = 0; kt < 16; ++kt) {
    bf16x8 av = *(const bf16x8*)&h[(size_t)r * 512 + kt * 32 + q * 8];
    bf16x8 b0 = *(const bf16x8*)&Wl[kt * 1024 + l * 32 + ch * 8];
    bf16x8 b1 = *(const bf16x8*)&Wl[kt * 1024 + (16 + l) * 32 + ch * 8];
    acc0 = __builtin_amdgcn_mfma_f32_16x16x32_bf16(av, b0, acc0, 0, 0, 0);
    acc1 = __builtin_amdgcn_mfma_f32_16x16x32_bf16(av, b1, acc1, 0, 0, 0);
  }

#pragma unroll
  for (int rr = 0; rr < 4; rr++) {
    Gl[w][q * 4 + rr][l] = acc0[rr];
    Gl[w][q * 4 + rr][16 + l] = acc1[rr];
  }
  __syncthreads();

  if (lane < 16) {
    int R = blockIdx.x * 64 + w * 16 + lane;
    int b = R / CDIM, c = R % CDIM;
    for (int t = 0; t < 3; t++) {
      float g[6];
#pragma unroll
      for (int e = 0; e < 6; e++) g[e] = Gl[w][lane][t * 6 + e];
      float out[6] = {0, 0, 0, 0, 0, 0};
      int idx[3]; float val[3];
      unsigned used = 0;
      for (int kk = 0; kk < 3; kk++) {
        int best = 0; float bv = -1e30f;
        for (int e = 0; e < 6; e++)
          if (!((used >> e) & 1) && g[e] > bv) { bv = g[e]; best = e; }
        used |= 1u << best; idx[kk] = best; val[kk] = bv;
      }
      float mx = val[0];
      float s = 0.f, ex[3];
      for (int kk = 0; kk < 3; kk++) { ex[kk] = expf(val[kk] - mx); s += ex[kk]; }
      for (int kk = 0; kk < 3; kk++) out[idx[kk]] = ex[kk] / s;
      float* gp = &gates[(size_t)((b * TDIM + t) * CDIM + c) * EDIM];
      for (int e = 0; e < 6; e++) gp[e] = out[e];
    }
  }
}

// ---------------- loss: one wave per b ----------------
__global__ __launch_bounds__(64) void loss_kernel(const float* __restrict__ scores,
                                                  const float* __restrict__ logits,
                                                  const float* __restrict__ gates,
                                                  const float* __restrict__ tb2,
                                                  float* __restrict__ out) {
  int b = blockIdx.x;
  int lane = threadIdx.x;
  float bce_sum = 0.f;
  float aux = 0.f;
  for (int t = 0; t < 3; t++) {
    float sc = (lane < CDIM) ? scores[(size_t)(b * TDIM + t) * CDIM + lane] : -1e30f;
    float mx = sc;
    for (int off = 32; off; off >>= 1) mx = fmaxf(mx, __shfl_xor(mx, off, 64));
    float lab = (lane < CDIM && sc == mx) ? 1.f : 0.f;
    float lg = (lane < CDIM) ? (logits[(size_t)(b * TDIM + t) * CDIM + lane] + tb2[t]) : 0.f;
    float bce = (lane < CDIM) ? (fmaxf(lg, 0.f) - lg * lab + log1pf(expf(-fabsf(lg)))) : 0.f;
    for (int off = 32; off; off >>= 1) bce += __shfl_xor(bce, off, 64);
    bce_sum += bce / (float)CDIM;

    float impv[6];
    float meansum = 0.f;
#pragma unroll
    for (int e = 0; e < 6; e++) {
      float gsum = (lane < CDIM) ? gates[(size_t)((b * TDIM + t) * CDIM + lane) * EDIM + e] : 0.f;
      for (int off = 32; off; off >>= 1) gsum += __shfl_xor(gsum, off, 64);
      impv[e] = gsum;
      meansum += gsum;
    }
    float mean = meansum / 6.f;
    float var = 0.f;
#pragma unroll
    for (int e = 0; e < 6; e++) { float d = impv[e] - mean; var += d * d; }
    var /= 6.f;
    aux += var / (mean * mean + 1e-10f);
  }
  float res = bce_sum / 3.f + 0.01f * aux;
  if (lane == 0) atomicAdd(out, res / (float)BDIM);
}

// ---------------- host ----------------
extern "C" void kernel_launch(void* const* d_in, const int* in_sizes, int n_in,
                              void* d_out, int out_size, void* d_ws, size_t ws_size,
                              hipStream_t stream) {
  const float* X = (const float*)d_in[0];
  const float* scores = (const float*)d_in[1];
  const float* fc1_w = (const float*)d_in[2];
  const float* fc1_b = (const float*)d_in[3];
  const float* fc2_w = (const float*)d_in[4];
  const float* fc2_b = (const float*)d_in[5];
  const float* w_gate = (const float*)d_in[6];
  const float* ew1 = (const float*)d_in[7];
  const float* eb1 = (const float*)d_in[8];
  const float* ew2 = (const float*)d_in[9];
  const float* eb2 = (const float*)d_in[10];
  const float* tw1 = (const float*)d_in[11];
  const float* tb1 = (const float*)d_in[12];
  const float* tw2 = (const float*)d_in[13];
  const float* tb2 = (const float*)d_in[14];
  float* out = (float*)d_out;

  // workspace layout (all disjoint)
  u8* fc1q = (u8*)d_ws;                          // 262144
  u8* fc2q = fc1q + 262144;                      // 262144
  u8* w1q = fc2q + 262144;                       // 6*262144
  u8* w2q = w1q + (size_t)6 * 262144;            // 6*262144
  u8* tw1q = w2q + (size_t)6 * 262144;           // 3*262144
  u16* WgT = (u16*)(tw1q + (size_t)3 * 262144);  // 32*512
  u8* Xq = (u8*)(WgT + (size_t)32 * 512);        // [15360][512]
  u8* A1q = Xq + (size_t)NROWS * 512;            // [15360][512]
  u8* hq = A1q + (size_t)NROWS * 512;            // [15360][512]
  u16* h = (u16*)(hq + (size_t)NROWS * 512);     // [15360][512] bf16
  u8* ehq = (u8*)(h + (size_t)NROWS * 512);      // [15360][3072]
  u8* yq = ehq + (size_t)NROWS * 3072;           // [3][15360][512]
  float* gates = (float*)(yq + (size_t)TDIM * NROWS * 512);
  float* logits = gates + (size_t)BDIM * TDIM * CDIM * EDIM;

  hipMemsetAsync(d_out, 0, sizeof(float) * out_size, stream);

  // merged prep: X -> fp8, all weights -> fp8, gate weights, zero logits
  prep_kernel<<<5005, 256, 0, stream>>>(X, Xq, fc1_w, fc2_w, ew1, ew2, tw1,
                                        fc1q, fc2q, w1q, w2q, tw1q, w_gate, WgT, logits);

  // shared bottom fp8 (960 blocks of 64x128, 8 K-steps)
  gemm_s8<0><<<dim3(960), 256, 0, stream>>>(Xq, fc1q, fc1_b, A1q, nullptr);
  gemm_s8<1><<<dim3(960), 256, 0, stream>>>(A1q, fc2q, fc2_b, hq, h);

  // gating (bf16 h)
  gate_kernel<<<240, 256, 0, stream>>>(h, WgT, gates);

  // experts W1 fp8: merged N=3072 (1440 blocks of 128x256, 8 K-steps) -> ehq
  gemm256q<<<dim3(1440), 512, 0, stream>>>(hq, w1q, eb1, ehq, 12);

  // experts W2 + gated combine, fp8 (960 blocks of 64x128, 48 K-steps) -> yq
  gemm_w2c<<<dim3(960), 256, 0, stream>>>(ehq, w2q, eb2, gates, yq);

  // towers fp8 (960 x 3 blocks of 64x128, 8 K-steps) -> logits (atomic)
  gemm_tower<<<dim3(960, 1, 3), 256, 0, stream>>>(yq, tw1q, tb1, tw2, logits);

  // loss
  loss_kernel<<<BDIM, 64, 0, stream>>>(scores, logits, gates, tb2, out);
}

// Round 15
// 205.858 us; speedup vs baseline: 1.5663x; 1.0018x over previous
//
#include <hip/hip_runtime.h>
#include <hip/hip_bf16.h>
#include <cstdint>
#include <cstddef>

typedef unsigned short u16;
typedef unsigned char u8;
typedef long i64;
typedef __bf16 bf16x8 __attribute__((ext_vector_type(8)));
typedef float f32x4 __attribute__((ext_vector_type(4)));
typedef u16 u16x8 __attribute__((ext_vector_type(8)));
typedef u8 u8x16 __attribute__((ext_vector_type(16)));
typedef i64 i64x2 __attribute__((ext_vector_type(2)));

#define NROWS 15360   // B*C = 512*30
#define KDIM 512
#define BDIM 512
#define CDIM 30
#define TDIM 3
#define EDIM 6

typedef __attribute__((address_space(1))) const unsigned int gu32;
typedef __attribute__((address_space(3))) unsigned int lu32;

__device__ __forceinline__ void gload16(const void* g, void* l) {
  __builtin_amdgcn_global_load_lds((gu32*)g, (lu32*)l, 16, 0, 0);
}

__device__ __forceinline__ float bf2f(u16 u) {
  union { unsigned i; float f; } v; v.i = ((unsigned)u) << 16; return v.f;
}
__device__ __forceinline__ u16 f2bf(float f) {
  union { float f; unsigned i; } v; v.f = f;
  unsigned r = v.i + 0x7fffu + ((v.i >> 16) & 1u);
  return (u16)(r >> 16);
}
// fp8 e4m3fn encode, software fallback
__device__ __forceinline__ u8 f2fp8_sw(float v) {
  union { float f; unsigned u; } x; x.f = v;
  unsigned s = (x.u >> 24) & 0x80;
  x.u &= 0x7fffffffu;
  if (x.f < 0.0009765625f) return (u8)s;
  if (x.f > 448.f) return (u8)(s | 0x7e);
  int e; float m = frexpf(x.f, &e);
  if (e < -5) {
    int qq = (int)(x.f * 512.f + 0.5f);
    return (u8)(s | qq);
  }
  int qq = (int)(m * 16.f + 0.5f);
  if (qq == 16) { qq = 8; e++; }
  int E = e + 6;
  if (E >= 16 || (E == 15 && qq - 8 == 7)) return (u8)(s | 0x7e);
  return (u8)(s | (E << 3) | (qq - 8));
}
__device__ __forceinline__ unsigned cvt2fp8(float a, float b) {
#if __has_builtin(__builtin_amdgcn_cvt_pk_fp8_f32)
  return (unsigned)__builtin_amdgcn_cvt_pk_fp8_f32(a, b, 0, false) & 0xffffu;
#else
  return (unsigned)f2fp8_sw(a) | ((unsigned)f2fp8_sw(b) << 8);
#endif
}
// within-64B-group byte permutation: chunk q = {ks0 granule q (8B)} ++ {ks1 granule q (8B)}
__device__ __forceinline__ int permpos(int j) {
  return ((j & 24) << 1) + ((j & 32) >> 2) + (j & 7);
}

// ---------------- merged prep ----------------
__global__ __launch_bounds__(256) void prep_kernel(
    const float* __restrict__ X, u8* __restrict__ Xq,
    const float* __restrict__ fc1, const float* __restrict__ fc2,
    const float* __restrict__ ew1, const float* __restrict__ ew2,
    const float* __restrict__ tw1,
    u8* __restrict__ fc1q, u8* __restrict__ fc2q,
    u8* __restrict__ w1q, u8* __restrict__ w2q, u8* __restrict__ tw1q,
    const float* __restrict__ wg, u16* __restrict__ WgT,
    float* __restrict__ logits) {
  int bid = blockIdx.x;
  if (bid < 3840) {
    int i = bid * 256 + threadIdx.x;          // granule id (8 elems)
    float4 a = *(const float4*)(X + (size_t)i * 8);
    float4 b = *(const float4*)(X + (size_t)i * 8 + 4);
    unsigned p0 = cvt2fp8(a.x * 16.f, a.y * 16.f);
    unsigned p1 = cvt2fp8(a.z * 16.f, a.w * 16.f);
    unsigned p2 = cvt2fp8(b.x * 16.f, b.y * 16.f);
    unsigned p3 = cvt2fp8(b.z * 16.f, b.w * 16.f);
    int row = i >> 6, g = i & 63;
    int pos = (g >> 3) * 64 + (g & 3) * 16 + (g & 4) * 2;  // permpos of granule start
    u8* dst = Xq + (size_t)row * 512 + pos;
    *(unsigned*)dst = p0 | (p1 << 16);
    *(unsigned*)(dst + 4) = p2 | (p3 << 16);
  } else if (bid < 4928) {
    int id = bid - 3840;
    int mid = id >> 6, tile = id & 63;
    const float* src;
    if (mid == 0) src = fc1;
    else if (mid == 1) src = fc2;
    else if (mid < 8) src = ew1 + (size_t)(mid - 2) * 262144;
    else if (mid < 14) src = ew2 + (size_t)(mid - 8) * 262144;
    else src = tw1 + (size_t)(mid - 14) * 262144;
    int tr = (tile >> 3) * 64, tc = (tile & 7) * 64;
    __shared__ float t[64][65];
    int c = threadIdx.x & 63, r0 = threadIdx.x >> 6;
#pragma unroll
    for (int i = 0; i < 16; i++) {
      int r = r0 + i * 4;
      t[r][c] = src[(size_t)(tr + r) * 512 + tc + c];
    }
    __syncthreads();
    u8* dq;
    if (mid == 0) dq = fc1q;
    else if (mid == 1) dq = fc2q;
    else if (mid < 8) dq = w1q + (size_t)(mid - 2) * 262144;
    else if (mid < 14) dq = w2q + (size_t)(mid - 8) * 262144;
    else dq = tw1q + (size_t)(mid - 14) * 262144;
    int pc = tr + permpos(c);   // tr is a multiple of 64
#pragma unroll
    for (int i = 0; i < 16; i++) {
      int r = r0 + i * 4;
      dq[(size_t)(tc + r) * 512 + pc] = (u8)(cvt2fp8(t[c][r] * 64.f, 0.f) & 0xff);
    }
  } else if (bid < 4960) {
    int col = bid - 4928;
    for (int k = threadIdx.x; k < 512; k += 256) {
      u16 v = 0;
      if (col < 18) {
        int t = col / 6, e = col % 6;
        v = f2bf(wg[(size_t)(t * 512 + k) * 6 + e]);
      }
      WgT[(size_t)col * 512 + k] = v;
    }
  } else {
    int i = (bid - 4960) * 1024 + threadIdx.x * 4;
    float4 z; z.x = 0.f; z.y = 0.f; z.z = 0.f; z.w = 0.f;
    *(float4*)(logits + i) = z;
  }
}

// ===== generic fp8 GEMM, BM=64 BN=128 BK=64, 8 K-steps (tower-proven template) =====
// DUAL=0: Cq = fp8(relu(P/1024 + bias) * 16)  (fc1 -> A1q)
// DUAL=1: Ch = bf16(P/1024 + bias), Cq = fp8(Ch * 16)  (fc2 -> h, hq; no relu)
template <int DUAL>
__global__ __launch_bounds__(256, 2) void gemm_s8(
    const u8* __restrict__ Aq,
    const u8* __restrict__ Bq,
    const float* __restrict__ bias,
    u8* __restrict__ Cq,
    u16* __restrict__ Ch) {
  int nwg = gridDim.x, cpx = nwg >> 3;
  int bid = blockIdx.x;
  int swz = (bid & 7) * cpx + (bid >> 3);
  int bx = swz >> 2, by = swz & 3;
  int brow = bx * 64, bcol = by * 128;

  __shared__ __align__(16) u8 SB8[3][12288];

  int tid = threadIdx.x, lane = tid & 63, w = tid >> 6;
  int l = lane & 15, q = lane >> 4;

  int srow = tid >> 2, sc = tid & 3;
  int scX = sc ^ ((srow >> 1) & 3);
  const u8* Ag = Aq + (size_t)(brow + srow) * 512 + scX * 16;
  const u8* Bg0 = Bq + (size_t)(bcol + srow) * 512 + scX * 16;
  const u8* Bg1 = Bg0 + (size_t)64 * 512;
  int lo = w * 1024;

#define STAGES(buf, kt)                                \
  do {                                                 \
    gload16(Ag + (kt) * 64, (buf) + lo);               \
    gload16(Bg0 + (kt) * 64, (buf) + 4096 + lo);       \
    gload16(Bg1 + (kt) * 64, (buf) + 8192 + lo);       \
  } while (0)

  f32x4 P[4][2];
#pragma unroll
  for (int mi = 0; mi < 4; mi++)
#pragma unroll
    for (int ni = 0; ni < 2; ni++) {
      P[mi][ni][0] = 0.f; P[mi][ni][1] = 0.f; P[mi][ni][2] = 0.f; P[mi][ni][3] = 0.f;
    }

  int xg = q ^ ((l >> 1) & 3);

  STAGES(SB8[0], 0);
  STAGES(SB8[1], 1);
  asm volatile("s_waitcnt vmcnt(3)" ::: "memory");
  __builtin_amdgcn_s_barrier();

  u8 *bc = SB8[0], *bn = SB8[1], *bq = SB8[2];
#pragma unroll
  for (int kt = 0; kt < 8; ++kt) {
    if (kt < 6) STAGES(bq, kt + 2);
    i64x2 bfv[2], afv[4];
#pragma unroll
    for (int ni = 0; ni < 2; ni++) {
      int col = w * 32 + ni * 16 + l;
      bfv[ni] = *(const i64x2*)&bc[4096 + col * 64 + xg * 16];
    }
#pragma unroll
    for (int mi = 0; mi < 4; mi++) {
      int row = mi * 16 + l;
      afv[mi] = *(const i64x2*)&bc[row * 64 + xg * 16];
    }
    __builtin_amdgcn_s_setprio(1);
#pragma unroll
    for (int ks = 0; ks < 2; ++ks)
#pragma unroll
      for (int mi = 0; mi < 4; mi++)
#pragma unroll
        for (int ni = 0; ni < 2; ni++)
          P[mi][ni] = __builtin_amdgcn_mfma_f32_16x16x32_fp8_fp8(
              afv[mi][ks], bfv[ni][ks], P[mi][ni], 0, 0, 0);
    __builtin_amdgcn_s_setprio(0);
    asm volatile("s_waitcnt lgkmcnt(0)" ::: "memory");
    if (kt < 6)
      asm volatile("s_waitcnt vmcnt(3)" ::: "memory");
    else
      asm volatile("s_waitcnt vmcnt(0)" ::: "memory");
    __builtin_amdgcn_s_barrier();
    u8* t_ = bc; bc = bn; bn = bq; bq = t_;
  }
#undef STAGES

  float bvs[2];
#pragma unroll
  for (int ni = 0; ni < 2; ni++) bvs[ni] = bias[bcol + w * 32 + ni * 16 + l];

  u8* S8 = (u8*)&SB8[0][0];   // 64*144 = 9216 B
#pragma unroll
  for (int mi = 0; mi < 4; mi++) {
    int rl = mi * 16 + q * 4;
#pragma unroll
    for (int ni = 0; ni < 2; ni++) {
      int colL = w * 32 + ni * 16 + l;
      int pc = (colL & 64) + permpos(colL & 63);
      float v[4];
#pragma unroll
      for (int rr = 0; rr < 4; rr++) {
        float x = P[mi][ni][rr] * 9.765625e-4f + bvs[ni];
        if (!DUAL) x = fmaxf(x, 0.f);
        v[rr] = x;
      }
      unsigned p01 = cvt2fp8(v[0] * 16.f, v[1] * 16.f);
      unsigned p23 = cvt2fp8(v[2] * 16.f, v[3] * 16.f);
      S8[(rl + 0) * 144 + pc] = (u8)(p01 & 0xff);
      S8[(rl + 1) * 144 + pc] = (u8)(p01 >> 8);
      S8[(rl + 2) * 144 + pc] = (u8)(p23 & 0xff);
      S8[(rl + 3) * 144 + pc] = (u8)(p23 >> 8);
    }
  }
  __syncthreads();
  {
    int row_ = tid >> 2, cc_ = tid & 3;
#pragma unroll
    for (int j = 0; j < 2; j++)
      *(u8x16*)&Cq[(size_t)(brow + row_) * 512 + bcol + j * 64 + cc_ * 16] =
          *(const u8x16*)&S8[row_ * 144 + j * 64 + cc_ * 16];
  }
  if (DUAL) {
    __syncthreads();
    u16* Sst = (u16*)&SB8[0][0];
#pragma unroll
    for (int mi = 0; mi < 4; mi++) {
      int rl = mi * 16 + q * 4;
#pragma unroll
      for (int ni = 0; ni < 2; ni++) {
        int colL = w * 32 + ni * 16 + l;
#pragma unroll
        for (int rr = 0; rr < 4; rr++) {
          float x = P[mi][ni][rr] * 9.765625e-4f + bvs[ni];
          Sst[(rl + rr) * 136 + colL] = f2bf(x);
        }
      }
    }
    __syncthreads();
    int row_ = tid >> 2, cc_ = tid & 3;
#pragma unroll
    for (int j = 0; j < 4; j++)
      *(u16x8*)&Ch[(size_t)(brow + row_) * 512 + bcol + cc_ * 32 + j * 8] =
          *(const u16x8*)&Sst[row_ * 136 + cc_ * 32 + j * 8];
  }
}

// ===== W1 fp8: 128x256 tile, BK=64, 8 K-steps, triple-buffer counted vmcnt =====
__global__ __launch_bounds__(512, 4) void gemm256q(
    const u8* __restrict__ Aq,
    const u8* __restrict__ Bq,
    const float* __restrict__ bias,
    u8* __restrict__ Cq,
    int nby) {
  int nwg = gridDim.x;
  int cpx = nwg >> 3;
  int bid = blockIdx.x;
  int swz = (bid & 7) * cpx + (bid >> 3);
  int bx = swz / nby, by = swz % nby;
  int brow = bx * 128, bcol = by * 256;

  __shared__ __align__(16) u8 SB8[3][24576];  // A 0..8191, B 8192..24575

  int tid = threadIdx.x, lane = tid & 63, w = tid >> 6;
  int wm = w >> 2, wn = w & 3;
  int l = lane & 15, q = lane >> 4;

  int srow = tid >> 2, sc = tid & 3;
  int scX = sc ^ ((srow >> 1) & 3);
  const u8* Ag = Aq + (size_t)(brow + srow) * 512 + scX * 16;
  const u8* Bg0 = Bq + (size_t)(bcol + srow) * 512 + scX * 16;
  const u8* Bg1 = Bg0 + (size_t)128 * 512;
  int lo = w * 1024;

#define STAGEQ(buf, kt)                                \
  do {                                                 \
    gload16(Ag + (kt) * 64, (buf) + lo);               \
    gload16(Bg0 + (kt) * 64, (buf) + 8192 + lo);       \
    gload16(Bg1 + (kt) * 64, (buf) + 16384 + lo);      \
  } while (0)

  f32x4 acc[4][4];
#pragma unroll
  for (int m = 0; m < 4; m++)
#pragma unroll
    for (int n = 0; n < 4; n++) {
      acc[m][n][0] = 0.f; acc[m][n][1] = 0.f; acc[m][n][2] = 0.f; acc[m][n][3] = 0.f;
    }

  int xg = q ^ ((l >> 1) & 3);

  STAGEQ(SB8[0], 0);
  STAGEQ(SB8[1], 1);
  asm volatile("s_waitcnt vmcnt(3)" ::: "memory");
  __builtin_amdgcn_s_barrier();

  u8 *bc = SB8[0], *bn = SB8[1], *bq = SB8[2];
#pragma unroll
  for (int kt = 0; kt < 8; ++kt) {
    if (kt < 6) STAGEQ(bq, kt + 2);
    i64x2 afv[4], bfv[4];
#pragma unroll
    for (int mi = 0; mi < 4; mi++) {
      int row = wm * 64 + mi * 16 + l;
      afv[mi] = *(const i64x2*)&bc[row * 64 + xg * 16];
    }
#pragma unroll
    for (int ni = 0; ni < 4; ni++) {
      int col = wn * 64 + ni * 16 + l;
      bfv[ni] = *(const i64x2*)&bc[8192 + col * 64 + xg * 16];
    }
    __builtin_amdgcn_s_setprio(1);
#pragma unroll
    for (int ks = 0; ks < 2; ++ks)
#pragma unroll
      for (int mi = 0; mi < 4; mi++)
#pragma unroll
        for (int ni = 0; ni < 4; ni++)
          acc[mi][ni] = __builtin_amdgcn_mfma_f32_16x16x32_fp8_fp8(
              afv[mi][ks], bfv[ni][ks], acc[mi][ni], 0, 0, 0);
    __builtin_amdgcn_s_setprio(0);
    asm volatile("s_waitcnt lgkmcnt(0)" ::: "memory");
    if (kt < 6)
      asm volatile("s_waitcnt vmcnt(3)" ::: "memory");
    else
      asm volatile("s_waitcnt vmcnt(0)" ::: "memory");
    __builtin_amdgcn_s_barrier();
    u8* t_ = bc; bc = bn; bn = bq; bq = t_;
  }
#undef STAGEQ

  u8* S8 = (u8*)&SB8[0][0];
  float bvs[4];
#pragma unroll
  for (int n = 0; n < 4; n++) bvs[n] = bias[bcol + wn * 64 + n * 16 + l];
#pragma unroll
  for (int m = 0; m < 4; m++) {
    int rl = wm * 64 + m * 16 + q * 4;
#pragma unroll
    for (int n = 0; n < 4; n++) {
      int pc = wn * 64 + permpos(n * 16 + l);
      float v0 = fmaxf(acc[m][n][0] * 9.765625e-4f + bvs[n], 0.f) * 16.f;
      float v1 = fmaxf(acc[m][n][1] * 9.765625e-4f + bvs[n], 0.f) * 16.f;
      float v2 = fmaxf(acc[m][n][2] * 9.765625e-4f + bvs[n], 0.f) * 16.f;
      float v3 = fmaxf(acc[m][n][3] * 9.765625e-4f + bvs[n], 0.f) * 16.f;
      unsigned p01 = cvt2fp8(v0, v1);
      unsigned p23 = cvt2fp8(v2, v3);
      S8[(rl + 0) * 264 + pc] = (u8)(p01 & 0xff);
      S8[(rl + 1) * 264 + pc] = (u8)(p01 >> 8);
      S8[(rl + 2) * 264 + pc] = (u8)(p23 & 0xff);
      S8[(rl + 3) * 264 + pc] = (u8)(p23 >> 8);
    }
  }
  __syncthreads();
  int row = tid >> 2, cc = tid & 3;
#pragma unroll
  for (int j = 0; j < 4; j++)
    *(u8x16*)&Cq[(size_t)(brow + row) * 3072 + bcol + cc * 64 + j * 16] =
        *(const u8x16*)&S8[row * 264 + cc * 64 + j * 16];
}

// ===== fused W2 + gated combine, fp8: BM=128, BN=128, 512 thr (8 waves 2Mx4N) =====
// Wave tile 64x32; K = 48 steps (6 experts x 8). LDS: 3 bufs x 16KB + gates 4.6KB.
// Grid 480 = exactly 2 blocks/CU -> 16 waves/CU. Accumulators: P[4][2] + 3x aY[4][2].
__global__ __launch_bounds__(512, 2) void gemm_w2c(
    const u8* __restrict__ eh,       // [15360][3072] fp8 (x16), permuted
    const u8* __restrict__ W2q,      // [6][512 col][512 k] fp8 (x64), permuted
    const float* __restrict__ eb2,   // [6][512]
    const float* __restrict__ gates, // [(b*3+t)*30+c][6]
    u8* __restrict__ yq) {           // [3][15360][512] fp8 (x32), permuted
  int nwg = gridDim.x, cpx = nwg >> 3;
  int bid = blockIdx.x;
  int swz = (bid & 7) * cpx + (bid >> 3);
  int bx = swz >> 2, by = swz & 3;     // 120 row-blocks x 4 col-blocks
  int brow = bx * 128, bcol = by * 128;

  __shared__ __align__(16) u8 SB8[3][16384];  // per buf: A 0..8191 (128x64), B 8192..16383
  __shared__ u16 glds[128 * 18];

  int tid = threadIdx.x, lane = tid & 63, w = tid >> 6;
  int wm = w >> 2, wn = w & 3;
  int l = lane & 15, q = lane >> 4;

  for (int i = tid; i < 128 * 18; i += 512) {
    int r = i / 18, te = i % 18;
    int gr = brow + r, b = gr / CDIM, c = gr % CDIM;
    int t = te / 6, e = te % 6;
    glds[i] = f2bf(gates[((size_t)(b * TDIM + t) * CDIM + c) * EDIM + e]);
  }
  float b2all[2][6];
#pragma unroll
  for (int ni = 0; ni < 2; ni++) {
    int col = bcol + wn * 32 + ni * 16 + l;
#pragma unroll
    for (int e = 0; e < 6; e++) b2all[ni][e] = eb2[e * 512 + col];
  }

  int srow = tid >> 2, sc = tid & 3;   // srow 0..127
  int scX = sc ^ ((srow >> 1) & 3);
  const u8* Ag = eh + (size_t)(brow + srow) * 3072 + scX * 16;
  const u8* Bg = W2q + (size_t)(bcol + srow) * 512 + scX * 16;
  int lo = w * 1024;

#define STAGEW(buf, s2)                                                   \
  do {                                                                    \
    int _e2 = (s2) >> 3, _k2 = (s2) & 7;                                  \
    gload16(Ag + _e2 * 512 + _k2 * 64, (buf) + lo);                       \
    gload16(Bg + (size_t)_e2 * 262144 + _k2 * 64, (buf) + 8192 + lo);     \
  } while (0)

  f32x4 P[4][2], aY0[4][2], aY1[4][2], aY2[4][2];
#pragma unroll
  for (int mi = 0; mi < 4; mi++)
#pragma unroll
    for (int ni = 0; ni < 2; ni++) {
      P[mi][ni][0] = P[mi][ni][1] = P[mi][ni][2] = P[mi][ni][3] = 0.f;
      aY0[mi][ni] = P[mi][ni]; aY1[mi][ni] = P[mi][ni]; aY2[mi][ni] = P[mi][ni];
    }

  int xg = q ^ ((l >> 1) & 3);

  STAGEW(SB8[0], 0);
  STAGEW(SB8[1], 1);
  asm volatile("s_waitcnt vmcnt(2)" ::: "memory");
  __builtin_amdgcn_s_barrier();

  u8 *bc = SB8[0], *bn = SB8[1], *bq = SB8[2];
  for (int e = 0; e < 6; ++e) {
#pragma unroll
    for (int kt = 0; kt < 8; ++kt) {
      int s = e * 8 + kt;
      if (s < 46) STAGEW(bq, s + 2);
      i64x2 bfv[2], afv[4];
#pragma unroll
      for (int ni = 0; ni < 2; ni++) {
        int col = wn * 32 + ni * 16 + l;
        bfv[ni] = *(const i64x2*)&bc[8192 + col * 64 + xg * 16];
      }
#pragma unroll
      for (int mi = 0; mi < 4; mi++) {
        int row = wm * 64 + mi * 16 + l;
        afv[mi] = *(const i64x2*)&bc[row * 64 + xg * 16];
      }
      __builtin_amdgcn_s_setprio(1);
#pragma unroll
      for (int ks = 0; ks < 2; ++ks)
#pragma unroll
        for (int mi = 0; mi < 4; mi++)
#pragma unroll
          for (int ni = 0; ni < 2; ni++)
            P[mi][ni] = __builtin_amdgcn_mfma_f32_16x16x32_fp8_fp8(
                afv[mi][ks], bfv[ni][ks], P[mi][ni], 0, 0, 0);
      __builtin_amdgcn_s_setprio(0);
      asm volatile("s_waitcnt lgkmcnt(0)" ::: "memory");
      if (s < 46)
        asm volatile("s_waitcnt vmcnt(2)" ::: "memory");
      else
        asm volatile("s_waitcnt vmcnt(0)" ::: "memory");
      __builtin_amdgcn_s_barrier();
      u8* t_ = bc; bc = bn; bn = bq; bq = t_;
    }
    // expert boundary: descale (1/(16*64)), add bias, fold with gates
#pragma unroll
    for (int mi = 0; mi < 4; mi++) {
#pragma unroll
      for (int rr = 0; rr < 4; rr++) {
        int row = wm * 64 + mi * 16 + q * 4 + rr;
        float g0 = bf2f(glds[row * 18 + e]);
        float g1 = bf2f(glds[row * 18 + 6 + e]);
        float g2 = bf2f(glds[row * 18 + 12 + e]);
#pragma unroll
        for (int ni = 0; ni < 2; ni++) {
          float p = P[mi][ni][rr] * 9.765625e-4f + b2all[ni][e];
          aY0[mi][ni][rr] += g0 * p;
          aY1[mi][ni][rr] += g1 * p;
          aY2[mi][ni][rr] += g2 * p;
          P[mi][ni][rr] = 0.f;
        }
      }
    }
  }
#undef STAGEW

  // epilogue: per task, y -> fp8(x32) at permuted col -> coalesced 16B stores
  u8* S8 = (u8*)&SB8[0][0];   // 128*144 = 18432 B < 48 KB
#define EPI(AY, t)                                                          \
  do {                                                                      \
    _Pragma("unroll") for (int mi = 0; mi < 4; mi++) {                      \
      int rl = wm * 64 + mi * 16 + q * 4;                                   \
      _Pragma("unroll") for (int ni = 0; ni < 2; ni++) {                    \
        int colL = wn * 32 + ni * 16 + l;                                   \
        int pc = (colL & 64) + permpos(colL & 63);                          \
        unsigned p01 = cvt2fp8(AY[mi][ni][0] * 32.f, AY[mi][ni][1] * 32.f); \
        unsigned p23 = cvt2fp8(AY[mi][ni][2] * 32.f, AY[mi][ni][3] * 32.f); \
        S8[(rl + 0) * 144 + pc] = (u8)(p01 & 0xff);                         \
        S8[(rl + 1) * 144 + pc] = (u8)(p01 >> 8);                           \
        S8[(rl + 2) * 144 + pc] = (u8)(p23 & 0xff);                         \
        S8[(rl + 3) * 144 + pc] = (u8)(p23 >> 8);                           \
      }                                                                     \
    }                                                                       \
    __syncthreads();                                                        \
    {                                                                       \
      int row_ = tid >> 2, cc_ = tid & 3;                                   \
      _Pragma("unroll") for (int j = 0; j < 2; j++)                         \
        *(u8x16*)&yq[((size_t)(t) * NROWS + brow + row_) * 512 + bcol +     \
                     cc_ * 32 + j * 16] =                                   \
            *(const u8x16*)&S8[row_ * 144 + cc_ * 32 + j * 16];             \
    }                                                                       \
    __syncthreads();                                                        \
  } while (0)
  EPI(aY0, 0);
  EPI(aY1, 1);
  EPI(aY2, 2);
#undef EPI
}

// ===== tower fp8: th = relu(yq@tw1q/2048 + tb1); logits += th . tw2 =====
__global__ __launch_bounds__(256, 2) void gemm_tower(
    const u8* __restrict__ yq,
    const u8* __restrict__ tw1q,
    const float* __restrict__ tb1, const float* __restrict__ tw2,
    float* __restrict__ logits) {
  int t = blockIdx.z;
  const u8* A = yq + (size_t)t * NROWS * 512;
  const u8* BT = tw1q + (size_t)t * 262144;

  int nwg = gridDim.x, cpx = nwg >> 3;
  int bid = blockIdx.x;
  int swz = (bid & 7) * cpx + (bid >> 3);
  int bx = swz >> 2, by = swz & 3;
  int brow = bx * 64, bcol = by * 128;

  __shared__ __align__(16) u8 SB8[3][12288];

  int tid = threadIdx.x, lane = tid & 63, w = tid >> 6;
  int l = lane & 15, q = lane >> 4;

  int srow = tid >> 2, sc = tid & 3;
  int scX = sc ^ ((srow >> 1) & 3);
  const u8* Ag = A + (size_t)(brow + srow) * 512 + scX * 16;
  const u8* Bg0 = BT + (size_t)(bcol + srow) * 512 + scX * 16;
  const u8* Bg1 = Bg0 + (size_t)64 * 512;
  int lo = w * 1024;

#define STAGET(buf, kt)                                \
  do {                                                 \
    gload16(Ag + (kt) * 64, (buf) + lo);               \
    gload16(Bg0 + (kt) * 64, (buf) + 4096 + lo);       \
    gload16(Bg1 + (kt) * 64, (buf) + 8192 + lo);       \
  } while (0)

  f32x4 P[4][2];
#pragma unroll
  for (int mi = 0; mi < 4; mi++)
#pragma unroll
    for (int ni = 0; ni < 2; ni++) {
      P[mi][ni][0] = 0.f; P[mi][ni][1] = 0.f; P[mi][ni][2] = 0.f; P[mi][ni][3] = 0.f;
    }

  int xg = q ^ ((l >> 1) & 3);

  STAGET(SB8[0], 0);
  STAGET(SB8[1], 1);
  asm volatile("s_waitcnt vmcnt(3)" ::: "memory");
  __builtin_amdgcn_s_barrier();

  u8 *bc = SB8[0], *bn = SB8[1], *bq = SB8[2];
#pragma unroll
  for (int kt = 0; kt < 8; ++kt) {
    if (kt < 6) STAGET(bq, kt + 2);
    i64x2 bfv[2], afv[4];
#pragma unroll
    for (int ni = 0; ni < 2; ni++) {
      int col = w * 32 + ni * 16 + l;
      bfv[ni] = *(const i64x2*)&bc[4096 + col * 64 + xg * 16];
    }
#pragma unroll
    for (int mi = 0; mi < 4; mi++) {
      int row = mi * 16 + l;
      afv[mi] = *(const i64x2*)&bc[row * 64 + xg * 16];
    }
    __builtin_amdgcn_s_setprio(1);
#pragma unroll
    for (int ks = 0; ks < 2; ++ks)
#pragma unroll
      for (int mi = 0; mi < 4; mi++)
#pragma unroll
        for (int ni = 0; ni < 2; ni++)
          P[mi][ni] = __builtin_amdgcn_mfma_f32_16x16x32_fp8_fp8(
              afv[mi][ks], bfv[ni][ks], P[mi][ni], 0, 0, 0);
    __builtin_amdgcn_s_setprio(0);
    asm volatile("s_waitcnt lgkmcnt(0)" ::: "memory");
    if (kt < 6)
      asm volatile("s_waitcnt vmcnt(3)" ::: "memory");
    else
      asm volatile("s_waitcnt vmcnt(0)" ::: "memory");
    __builtin_amdgcn_s_barrier();
    u8* t_ = bc; bc = bn; bn = bq; bq = t_;
  }
#undef STAGET

  float bvs[2], tws[2];
#pragma unroll
  for (int ni = 0; ni < 2; ni++) {
    int col = bcol + w * 32 + ni * 16 + l;
    bvs[ni] = tb1[t * 512 + col];
    tws[ni] = tw2[t * 512 + col];
  }
#pragma unroll
  for (int mi = 0; mi < 4; mi++) {
#pragma unroll
    for (int rr = 0; rr < 4; rr++) {
      float s = 0.f;
#pragma unroll
      for (int ni = 0; ni < 2; ni++) {
        float v = P[mi][ni][rr] * 4.8828125e-4f + bvs[ni];
        v = fmaxf(v, 0.f);
        s += v * tws[ni];
      }
      s += __shfl_xor(s, 1, 64);
      s += __shfl_xor(s, 2, 64);
      s += __shfl_xor(s, 4, 64);
      s += __shfl_xor(s, 8, 64);
      if (l == 0) {
        int row = brow + mi * 16 + q * 4 + rr;
        int b = row / CDIM, c = row % CDIM;
        atomicAdd(&logits[(size_t)(b * TDIM + t) * CDIM + c], s);
      }
    }
  }
}

// ---------------- gate: MFMA skinny GEMM [64 rows/block x 32] + top3 softmax ----
__global__ __launch_bounds__(256) void gate_kernel(const u16* __restrict__ h,
                                                   const u16* __restrict__ WgT,
                                                   float* __restrict__ gates) {
  __shared__ u16 Wl[16 * 32 * 32];
  __shared__ float Gl[4][16][33];
  int tid = threadIdx.x, lane = tid & 63, w = tid >> 6;
  int l = lane & 15, q = lane >> 4;

  for (int idx = tid; idx < 2048; idx += 256) {
    int kt = idx >> 7, col = (idx >> 2) & 31, c = idx & 3;
    int sc = c ^ ((col >> 1) & 3);
    *(u16x8*)&Wl[kt * 1024 + col * 32 + c * 8] =
        *(const u16x8*)&WgT[(size_t)col * 512 + kt * 32 + sc * 8];
  }
  __syncthreads();

  int r = blockIdx.x * 64 + w * 16 + l;
  int ch = q ^ ((l >> 1) & 3);

  f32x4 acc0, acc1;
  acc0[0] = acc0[1] = acc0[2] = acc0[3] = 0.f;
  acc1 = acc0;
#pragma unroll
  for (int kt = 0; kt < 16; ++kt) {
    bf16x8 av = *(const bf16x8*)&h[(size_t)r * 512 + kt * 32 + q * 8];
    bf16x8 b0 = *(const bf16x8*)&Wl[kt * 1024 + l * 32 + ch * 8];
    bf16x8 b1 = *(const bf16x8*)&Wl[kt * 1024 + (16 + l) * 32 + ch * 8];
    acc0 = __builtin_amdgcn_mfma_f32_16x16x32_bf16(av, b0, acc0, 0, 0, 0);
    acc1 = __builtin_amdgcn_mfma_f32_16x16x32_bf16(av, b1, acc1, 0, 0, 0);
  }

#pragma unroll
  for (int rr = 0; rr < 4; rr++) {
    Gl[w][q * 4 + rr][l] = acc0[rr];
    Gl[w][q * 4 + rr][16 + l] = acc1[rr];
  }
  __syncthreads();

  if (lane < 16) {
    int R = blockIdx.x * 64 + w * 16 + lane;
    int b = R / CDIM, c = R % CDIM;
    for (int t = 0; t < 3; t++) {
      float g[6];
#pragma unroll
      for (int e = 0; e < 6; e++) g[e] = Gl[w][lane][t * 6 + e];
      float out[6] = {0, 0, 0, 0, 0, 0};
      int idx[3]; float val[3];
      unsigned used = 0;
      for (int kk = 0; kk < 3; kk++) {
        int best = 0; float bv = -1e30f;
        for (int e = 0; e < 6; e++)
          if (!((used >> e) & 1) && g[e] > bv) { bv = g[e]; best = e; }
        used |= 1u << best; idx[kk] = best; val[kk] = bv;
      }
      float mx = val[0];
      float s = 0.f, ex[3];
      for (int kk = 0; kk < 3; kk++) { ex[kk] = expf(val[kk] - mx); s += ex[kk]; }
      for (int kk = 0; kk < 3; kk++) out[idx[kk]] = ex[kk] / s;
      float* gp = &gates[(size_t)((b * TDIM + t) * CDIM + c) * EDIM];
      for (int e = 0; e < 6; e++) gp[e] = out[e];
    }
  }
}

// ---------------- loss: one wave per b ----------------
__global__ __launch_bounds__(64) void loss_kernel(const float* __restrict__ scores,
                                                  const float* __restrict__ logits,
                                                  const float* __restrict__ gates,
                                                  const float* __restrict__ tb2,
                                                  float* __restrict__ out) {
  int b = blockIdx.x;
  int lane = threadIdx.x;
  float bce_sum = 0.f;
  float aux = 0.f;
  for (int t = 0; t < 3; t++) {
    float sc = (lane < CDIM) ? scores[(size_t)(b * TDIM + t) * CDIM + lane] : -1e30f;
    float mx = sc;
    for (int off = 32; off; off >>= 1) mx = fmaxf(mx, __shfl_xor(mx, off, 64));
    float lab = (lane < CDIM && sc == mx) ? 1.f : 0.f;
    float lg = (lane < CDIM) ? (logits[(size_t)(b * TDIM + t) * CDIM + lane] + tb2[t]) : 0.f;
    float bce = (lane < CDIM) ? (fmaxf(lg, 0.f) - lg * lab + log1pf(expf(-fabsf(lg)))) : 0.f;
    for (int off = 32; off; off >>= 1) bce += __shfl_xor(bce, off, 64);
    bce_sum += bce / (float)CDIM;

    float impv[6];
    float meansum = 0.f;
#pragma unroll
    for (int e = 0; e < 6; e++) {
      float gsum = (lane < CDIM) ? gates[(size_t)((b * TDIM + t) * CDIM + lane) * EDIM + e] : 0.f;
      for (int off = 32; off; off >>= 1) gsum += __shfl_xor(gsum, off, 64);
      impv[e] = gsum;
      meansum += gsum;
    }
    float mean = meansum / 6.f;
    float var = 0.f;
#pragma unroll
    for (int e = 0; e < 6; e++) { float d = impv[e] - mean; var += d * d; }
    var /= 6.f;
    aux += var / (mean * mean + 1e-10f);
  }
  float res = bce_sum / 3.f + 0.01f * aux;
  if (lane == 0) atomicAdd(out, res / (float)BDIM);
}

// ---------------- host ----------------
extern "C" void kernel_launch(void* const* d_in, const int* in_sizes, int n_in,
                              void* d_out, int out_size, void* d_ws, size_t ws_size,
                              hipStream_t stream) {
  const float* X = (const float*)d_in[0];
  const float* scores = (const float*)d_in[1];
  const float* fc1_w = (const float*)d_in[2];
  const float* fc1_b = (const float*)d_in[3];
  const float* fc2_w = (const float*)d_in[4];
  const float* fc2_b = (const float*)d_in[5];
  const float* w_gate = (const float*)d_in[6];
  const float* ew1 = (const float*)d_in[7];
  const float* eb1 = (const float*)d_in[8];
  const float* ew2 = (const float*)d_in[9];
  const float* eb2 = (const float*)d_in[10];
  const float* tw1 = (const float*)d_in[11];
  const float* tb1 = (const float*)d_in[12];
  const float* tw2 = (const float*)d_in[13];
  const float* tb2 = (const float*)d_in[14];
  float* out = (float*)d_out;

  // workspace layout (all disjoint)
  u8* fc1q = (u8*)d_ws;                          // 262144
  u8* fc2q = fc1q + 262144;                      // 262144
  u8* w1q = fc2q + 262144;                       // 6*262144
  u8* w2q = w1q + (size_t)6 * 262144;            // 6*262144
  u8* tw1q = w2q + (size_t)6 * 262144;           // 3*262144
  u16* WgT = (u16*)(tw1q + (size_t)3 * 262144);  // 32*512
  u8* Xq = (u8*)(WgT + (size_t)32 * 512);        // [15360][512]
  u8* A1q = Xq + (size_t)NROWS * 512;            // [15360][512]
  u8* hq = A1q + (size_t)NROWS * 512;            // [15360][512]
  u16* h = (u16*)(hq + (size_t)NROWS * 512);     // [15360][512] bf16
  u8* ehq = (u8*)(h + (size_t)NROWS * 512);      // [15360][3072]
  u8* yq = ehq + (size_t)NROWS * 3072;           // [3][15360][512]
  float* gates = (float*)(yq + (size_t)TDIM * NROWS * 512);
  float* logits = gates + (size_t)BDIM * TDIM * CDIM * EDIM;

  hipMemsetAsync(d_out, 0, sizeof(float) * out_size, stream);

  // merged prep: X -> fp8, all weights -> fp8, gate weights, zero logits
  prep_kernel<<<5005, 256, 0, stream>>>(X, Xq, fc1_w, fc2_w, ew1, ew2, tw1,
                                        fc1q, fc2q, w1q, w2q, tw1q, w_gate, WgT, logits);

  // shared bottom fp8 (960 blocks of 64x128, 8 K-steps)
  gemm_s8<0><<<dim3(960), 256, 0, stream>>>(Xq, fc1q, fc1_b, A1q, nullptr);
  gemm_s8<1><<<dim3(960), 256, 0, stream>>>(A1q, fc2q, fc2_b, hq, h);

  // gating (bf16 h)
  gate_kernel<<<240, 256, 0, stream>>>(h, WgT, gates);

  // experts W1 fp8: merged N=3072 (1440 blocks of 128x256, 8 K-steps) -> ehq
  gemm256q<<<dim3(1440), 512, 0, stream>>>(hq, w1q, eb1, ehq, 12);

  // experts W2 + gated combine, fp8 (480 blocks of 128x128, 48 K-steps) -> yq
  gemm_w2c<<<dim3(480), 512, 0, stream>>>(ehq, w2q, eb2, gates, yq);

  // towers fp8 (960 x 3 blocks of 64x128, 8 K-steps) -> logits (atomic)
  gemm_tower<<<dim3(960, 1, 3), 256, 0, stream>>>(yq, tw1q, tb1, tw2, logits);

  // loss
  loss_kernel<<<BDIM, 64, 0, stream>>>(scores, logits, gates, tb2, out);
}

// Round 16
// 200.314 us; speedup vs baseline: 1.6097x; 1.0277x over previous
//
#include <hip/hip_runtime.h>
#include <hip/hip_bf16.h>
#include <cstdint>
#include <cstddef>

typedef unsigned short u16;
typedef unsigned char u8;
typedef long i64;
typedef __bf16 bf16x8 __attribute__((ext_vector_type(8)));
typedef float f32x4 __attribute__((ext_vector_type(4)));
typedef u16 u16x8 __attribute__((ext_vector_type(8)));
typedef u8 u8x16 __attribute__((ext_vector_type(16)));
typedef i64 i64x2 __attribute__((ext_vector_type(2)));

#define NROWS 15360   // B*C = 512*30
#define KDIM 512
#define BDIM 512
#define CDIM 30
#define TDIM 3
#define EDIM 6

typedef __attribute__((address_space(1))) const unsigned int gu32;
typedef __attribute__((address_space(3))) unsigned int lu32;

__device__ __forceinline__ void gload16(const void* g, void* l) {
  __builtin_amdgcn_global_load_lds((gu32*)g, (lu32*)l, 16, 0, 0);
}

__device__ __forceinline__ float bf2f(u16 u) {
  union { unsigned i; float f; } v; v.i = ((unsigned)u) << 16; return v.f;
}
__device__ __forceinline__ u16 f2bf(float f) {
  union { float f; unsigned i; } v; v.f = f;
  unsigned r = v.i + 0x7fffu + ((v.i >> 16) & 1u);
  return (u16)(r >> 16);
}
// fp8 e4m3fn encode, software fallback
__device__ __forceinline__ u8 f2fp8_sw(float v) {
  union { float f; unsigned u; } x; x.f = v;
  unsigned s = (x.u >> 24) & 0x80;
  x.u &= 0x7fffffffu;
  if (x.f < 0.0009765625f) return (u8)s;
  if (x.f > 448.f) return (u8)(s | 0x7e);
  int e; float m = frexpf(x.f, &e);
  if (e < -5) {
    int qq = (int)(x.f * 512.f + 0.5f);
    return (u8)(s | qq);
  }
  int qq = (int)(m * 16.f + 0.5f);
  if (qq == 16) { qq = 8; e++; }
  int E = e + 6;
  if (E >= 16 || (E == 15 && qq - 8 == 7)) return (u8)(s | 0x7e);
  return (u8)(s | (E << 3) | (qq - 8));
}
__device__ __forceinline__ unsigned cvt2fp8(float a, float b) {
#if __has_builtin(__builtin_amdgcn_cvt_pk_fp8_f32)
  return (unsigned)__builtin_amdgcn_cvt_pk_fp8_f32(a, b, 0, false) & 0xffffu;
#else
  return (unsigned)f2fp8_sw(a) | ((unsigned)f2fp8_sw(b) << 8);
#endif
}
// within-64B-group byte permutation: chunk q = {ks0 granule q (8B)} ++ {ks1 granule q (8B)}
__device__ __forceinline__ int permpos(int j) {
  return ((j & 24) << 1) + ((j & 32) >> 2) + (j & 7);
}

// ---------------- merged prep ----------------
// bid 0..3839: cvt X fp32 -> fp8 x16 permuted
// bid 3840..4927: weight tiles -> fp8 x64 permuted (fc1,fc2,w1,w2,tw1)
// bid 4928..4959: gate weight col -> wgq fp8 x64 permuted (cols 18..31 zero)
// bid 4960..5004: zero logits
__global__ __launch_bounds__(256) void prep_kernel(
    const float* __restrict__ X, u8* __restrict__ Xq,
    const float* __restrict__ fc1, const float* __restrict__ fc2,
    const float* __restrict__ ew1, const float* __restrict__ ew2,
    const float* __restrict__ tw1,
    u8* __restrict__ fc1q, u8* __restrict__ fc2q,
    u8* __restrict__ w1q, u8* __restrict__ w2q, u8* __restrict__ tw1q,
    const float* __restrict__ wg, u8* __restrict__ wgq,
    float* __restrict__ logits) {
  int bid = blockIdx.x;
  if (bid < 3840) {
    int i = bid * 256 + threadIdx.x;          // granule id (8 elems)
    float4 a = *(const float4*)(X + (size_t)i * 8);
    float4 b = *(const float4*)(X + (size_t)i * 8 + 4);
    unsigned p0 = cvt2fp8(a.x * 16.f, a.y * 16.f);
    unsigned p1 = cvt2fp8(a.z * 16.f, a.w * 16.f);
    unsigned p2 = cvt2fp8(b.x * 16.f, b.y * 16.f);
    unsigned p3 = cvt2fp8(b.z * 16.f, b.w * 16.f);
    int row = i >> 6, g = i & 63;
    int pos = (g >> 3) * 64 + (g & 3) * 16 + (g & 4) * 2;  // permpos of granule start
    u8* dst = Xq + (size_t)row * 512 + pos;
    *(unsigned*)dst = p0 | (p1 << 16);
    *(unsigned*)(dst + 4) = p2 | (p3 << 16);
  } else if (bid < 4928) {
    int id = bid - 3840;
    int mid = id >> 6, tile = id & 63;
    const float* src;
    if (mid == 0) src = fc1;
    else if (mid == 1) src = fc2;
    else if (mid < 8) src = ew1 + (size_t)(mid - 2) * 262144;
    else if (mid < 14) src = ew2 + (size_t)(mid - 8) * 262144;
    else src = tw1 + (size_t)(mid - 14) * 262144;
    int tr = (tile >> 3) * 64, tc = (tile & 7) * 64;
    __shared__ float t[64][65];
    int c = threadIdx.x & 63, r0 = threadIdx.x >> 6;
#pragma unroll
    for (int i = 0; i < 16; i++) {
      int r = r0 + i * 4;
      t[r][c] = src[(size_t)(tr + r) * 512 + tc + c];
    }
    __syncthreads();
    u8* dq;
    if (mid == 0) dq = fc1q;
    else if (mid == 1) dq = fc2q;
    else if (mid < 8) dq = w1q + (size_t)(mid - 2) * 262144;
    else if (mid < 14) dq = w2q + (size_t)(mid - 8) * 262144;
    else dq = tw1q + (size_t)(mid - 14) * 262144;
    int pc = tr + permpos(c);   // tr is a multiple of 64
#pragma unroll
    for (int i = 0; i < 16; i++) {
      int r = r0 + i * 4;
      dq[(size_t)(tc + r) * 512 + pc] = (u8)(cvt2fp8(t[c][r] * 64.f, 0.f) & 0xff);
    }
  } else if (bid < 4960) {
    int col = bid - 4928;  // 0..31
    for (int k = threadIdx.x; k < 512; k += 256) {
      float v = 0.f;
      if (col < 18) {
        int t = col / 6, e = col % 6;
        v = wg[(size_t)(t * 512 + k) * 6 + e];
      }
      int pos = (k & ~63) + permpos(k & 63);
      wgq[(size_t)col * 512 + pos] = (u8)(cvt2fp8(v * 64.f, 0.f) & 0xff);
    }
  } else {
    int i = (bid - 4960) * 1024 + threadIdx.x * 4;
    float4 z; z.x = 0.f; z.y = 0.f; z.z = 0.f; z.w = 0.f;
    *(float4*)(logits + i) = z;
  }
}

// ===== generic fp8 GEMM, BM=64 BN=128 BK=64, 8 K-steps (tower-proven template) =====
// Cq = fp8((relu?)(P/1024 + bias) * 16)
template <int RELU>
__global__ __launch_bounds__(256, 2) void gemm_s8(
    const u8* __restrict__ Aq,
    const u8* __restrict__ Bq,
    const float* __restrict__ bias,
    u8* __restrict__ Cq) {
  int nwg = gridDim.x, cpx = nwg >> 3;
  int bid = blockIdx.x;
  int swz = (bid & 7) * cpx + (bid >> 3);
  int bx = swz >> 2, by = swz & 3;
  int brow = bx * 64, bcol = by * 128;

  __shared__ __align__(16) u8 SB8[3][12288];

  int tid = threadIdx.x, lane = tid & 63, w = tid >> 6;
  int l = lane & 15, q = lane >> 4;

  int srow = tid >> 2, sc = tid & 3;
  int scX = sc ^ ((srow >> 1) & 3);
  const u8* Ag = Aq + (size_t)(brow + srow) * 512 + scX * 16;
  const u8* Bg0 = Bq + (size_t)(bcol + srow) * 512 + scX * 16;
  const u8* Bg1 = Bg0 + (size_t)64 * 512;
  int lo = w * 1024;

#define STAGES(buf, kt)                                \
  do {                                                 \
    gload16(Ag + (kt) * 64, (buf) + lo);               \
    gload16(Bg0 + (kt) * 64, (buf) + 4096 + lo);       \
    gload16(Bg1 + (kt) * 64, (buf) + 8192 + lo);       \
  } while (0)

  f32x4 P[4][2];
#pragma unroll
  for (int mi = 0; mi < 4; mi++)
#pragma unroll
    for (int ni = 0; ni < 2; ni++) {
      P[mi][ni][0] = 0.f; P[mi][ni][1] = 0.f; P[mi][ni][2] = 0.f; P[mi][ni][3] = 0.f;
    }

  int xg = q ^ ((l >> 1) & 3);

  STAGES(SB8[0], 0);
  STAGES(SB8[1], 1);
  asm volatile("s_waitcnt vmcnt(3)" ::: "memory");
  __builtin_amdgcn_s_barrier();

  u8 *bc = SB8[0], *bn = SB8[1], *bq = SB8[2];
#pragma unroll
  for (int kt = 0; kt < 8; ++kt) {
    if (kt < 6) STAGES(bq, kt + 2);
    i64x2 bfv[2], afv[4];
#pragma unroll
    for (int ni = 0; ni < 2; ni++) {
      int col = w * 32 + ni * 16 + l;
      bfv[ni] = *(const i64x2*)&bc[4096 + col * 64 + xg * 16];
    }
#pragma unroll
    for (int mi = 0; mi < 4; mi++) {
      int row = mi * 16 + l;
      afv[mi] = *(const i64x2*)&bc[row * 64 + xg * 16];
    }
    __builtin_amdgcn_s_setprio(1);
#pragma unroll
    for (int ks = 0; ks < 2; ++ks)
#pragma unroll
      for (int mi = 0; mi < 4; mi++)
#pragma unroll
        for (int ni = 0; ni < 2; ni++)
          P[mi][ni] = __builtin_amdgcn_mfma_f32_16x16x32_fp8_fp8(
              afv[mi][ks], bfv[ni][ks], P[mi][ni], 0, 0, 0);
    __builtin_amdgcn_s_setprio(0);
    asm volatile("s_waitcnt lgkmcnt(0)" ::: "memory");
    if (kt < 6)
      asm volatile("s_waitcnt vmcnt(3)" ::: "memory");
    else
      asm volatile("s_waitcnt vmcnt(0)" ::: "memory");
    __builtin_amdgcn_s_barrier();
    u8* t_ = bc; bc = bn; bn = bq; bq = t_;
  }
#undef STAGES

  float bvs[2];
#pragma unroll
  for (int ni = 0; ni < 2; ni++) bvs[ni] = bias[bcol + w * 32 + ni * 16 + l];

  u8* S8 = (u8*)&SB8[0][0];   // 64*144 = 9216 B
#pragma unroll
  for (int mi = 0; mi < 4; mi++) {
    int rl = mi * 16 + q * 4;
#pragma unroll
    for (int ni = 0; ni < 2; ni++) {
      int colL = w * 32 + ni * 16 + l;
      int pc = (colL & 64) + permpos(colL & 63);
      float v[4];
#pragma unroll
      for (int rr = 0; rr < 4; rr++) {
        float x = P[mi][ni][rr] * 9.765625e-4f + bvs[ni];
        if (RELU) x = fmaxf(x, 0.f);
        v[rr] = x;
      }
      unsigned p01 = cvt2fp8(v[0] * 16.f, v[1] * 16.f);
      unsigned p23 = cvt2fp8(v[2] * 16.f, v[3] * 16.f);
      S8[(rl + 0) * 144 + pc] = (u8)(p01 & 0xff);
      S8[(rl + 1) * 144 + pc] = (u8)(p01 >> 8);
      S8[(rl + 2) * 144 + pc] = (u8)(p23 & 0xff);
      S8[(rl + 3) * 144 + pc] = (u8)(p23 >> 8);
    }
  }
  __syncthreads();
  {
    int row_ = tid >> 2, cc_ = tid & 3;
#pragma unroll
    for (int j = 0; j < 2; j++)
      *(u8x16*)&Cq[(size_t)(brow + row_) * 512 + bcol + j * 64 + cc_ * 16] =
          *(const u8x16*)&S8[row_ * 144 + j * 64 + cc_ * 16];
  }
}

// ===== gate fp8: glog = hq @ wgq / 1024, top3 softmax -> gates =====
// 240 blocks x 256 thr; block = 64 rows. A 64x64B, B 32x64B per K-step, 8 steps,
// double-buffered. Same staging/read swizzle geometry as gemm_s8 (2-way-free).
__global__ __launch_bounds__(256) void gate_kernel(const u8* __restrict__ hq,
                                                   const u8* __restrict__ wgq,
                                                   float* __restrict__ gates) {
  __shared__ __align__(16) u8 SBg[2][6144];  // per buf: A 0..4095, B 4096..6143
  __shared__ float Gl[4][16][33];
  int tid = threadIdx.x, lane = tid & 63, w = tid >> 6;
  int l = lane & 15, q = lane >> 4;
  int brow = blockIdx.x * 64;

  int srow = tid >> 2, sc = tid & 3;
  int scA = sc ^ ((srow >> 1) & 3);
  const u8* Ag = hq + (size_t)(brow + srow) * 512 + scA * 16;
  int Brow = srow & 31;
  int scB = sc ^ ((Brow >> 1) & 3);
  const u8* Bg = wgq + (size_t)Brow * 512 + scB * 16;
  int loA = w * 1024;
  int loB = 4096 + w * 1024;   // only waves 0,1

#define STAGEG(buf, kt)                                \
  do {                                                 \
    gload16(Ag + (kt) * 64, (buf) + loA);              \
    if (w < 2) gload16(Bg + (kt) * 64, (buf) + loB);   \
  } while (0)

  f32x4 acc0, acc1;
  acc0[0] = acc0[1] = acc0[2] = acc0[3] = 0.f;
  acc1 = acc0;
  int xg = q ^ ((l >> 1) & 3);
  int arow = w * 16 + l;

  STAGEG(SBg[0], 0);
  asm volatile("s_waitcnt vmcnt(0)" ::: "memory");
  __builtin_amdgcn_s_barrier();

#pragma unroll
  for (int s = 0; s < 8; ++s) {
    u8* bc = SBg[s & 1];
    if (s < 7) STAGEG(SBg[(s + 1) & 1], s + 1);
    i64x2 a = *(const i64x2*)&bc[arow * 64 + xg * 16];
    i64x2 b0 = *(const i64x2*)&bc[4096 + l * 64 + xg * 16];
    i64x2 b1 = *(const i64x2*)&bc[4096 + (16 + l) * 64 + xg * 16];
#pragma unroll
    for (int ks = 0; ks < 2; ++ks) {
      acc0 = __builtin_amdgcn_mfma_f32_16x16x32_fp8_fp8(a[ks], b0[ks], acc0, 0, 0, 0);
      acc1 = __builtin_amdgcn_mfma_f32_16x16x32_fp8_fp8(a[ks], b1[ks], acc1, 0, 0, 0);
    }
    asm volatile("s_waitcnt lgkmcnt(0)" ::: "memory");
    asm volatile("s_waitcnt vmcnt(0)" ::: "memory");
    __builtin_amdgcn_s_barrier();
  }
#undef STAGEG

  // acc layout: row = q*4+rr, col = l (+16 for acc1); descale 1/1024
#pragma unroll
  for (int rr = 0; rr < 4; rr++) {
    Gl[w][q * 4 + rr][l] = acc0[rr] * 9.765625e-4f;
    Gl[w][q * 4 + rr][16 + l] = acc1[rr] * 9.765625e-4f;
  }
  __syncthreads();

  if (lane < 16) {
    int R = brow + w * 16 + lane;
    int b = R / CDIM, c = R % CDIM;
    for (int t = 0; t < 3; t++) {
      float g[6];
#pragma unroll
      for (int e = 0; e < 6; e++) g[e] = Gl[w][lane][t * 6 + e];
      float out[6] = {0, 0, 0, 0, 0, 0};
      int idx[3]; float val[3];
      unsigned used = 0;
      for (int kk = 0; kk < 3; kk++) {
        int best = 0; float bv = -1e30f;
        for (int e = 0; e < 6; e++)
          if (!((used >> e) & 1) && g[e] > bv) { bv = g[e]; best = e; }
        used |= 1u << best; idx[kk] = best; val[kk] = bv;
      }
      float mx = val[0];
      float s = 0.f, ex[3];
      for (int kk = 0; kk < 3; kk++) { ex[kk] = expf(val[kk] - mx); s += ex[kk]; }
      for (int kk = 0; kk < 3; kk++) out[idx[kk]] = ex[kk] / s;
      float* gp = &gates[(size_t)((b * TDIM + t) * CDIM + c) * EDIM];
      for (int e = 0; e < 6; e++) gp[e] = out[e];
    }
  }
}

// ===== W1 fp8: 128x256 tile, BK=64, 8 K-steps, triple-buffer counted vmcnt =====
__global__ __launch_bounds__(512, 4) void gemm256q(
    const u8* __restrict__ Aq,
    const u8* __restrict__ Bq,
    const float* __restrict__ bias,
    u8* __restrict__ Cq,
    int nby) {
  int nwg = gridDim.x;
  int cpx = nwg >> 3;
  int bid = blockIdx.x;
  int swz = (bid & 7) * cpx + (bid >> 3);
  int bx = swz / nby, by = swz % nby;
  int brow = bx * 128, bcol = by * 256;

  __shared__ __align__(16) u8 SB8[3][24576];  // A 0..8191, B 8192..24575

  int tid = threadIdx.x, lane = tid & 63, w = tid >> 6;
  int wm = w >> 2, wn = w & 3;
  int l = lane & 15, q = lane >> 4;

  int srow = tid >> 2, sc = tid & 3;
  int scX = sc ^ ((srow >> 1) & 3);
  const u8* Ag = Aq + (size_t)(brow + srow) * 512 + scX * 16;
  const u8* Bg0 = Bq + (size_t)(bcol + srow) * 512 + scX * 16;
  const u8* Bg1 = Bg0 + (size_t)128 * 512;
  int lo = w * 1024;

#define STAGEQ(buf, kt)                                \
  do {                                                 \
    gload16(Ag + (kt) * 64, (buf) + lo);               \
    gload16(Bg0 + (kt) * 64, (buf) + 8192 + lo);       \
    gload16(Bg1 + (kt) * 64, (buf) + 16384 + lo);      \
  } while (0)

  f32x4 acc[4][4];
#pragma unroll
  for (int m = 0; m < 4; m++)
#pragma unroll
    for (int n = 0; n < 4; n++) {
      acc[m][n][0] = 0.f; acc[m][n][1] = 0.f; acc[m][n][2] = 0.f; acc[m][n][3] = 0.f;
    }

  int xg = q ^ ((l >> 1) & 3);

  STAGEQ(SB8[0], 0);
  STAGEQ(SB8[1], 1);
  asm volatile("s_waitcnt vmcnt(3)" ::: "memory");
  __builtin_amdgcn_s_barrier();

  u8 *bc = SB8[0], *bn = SB8[1], *bq = SB8[2];
#pragma unroll
  for (int kt = 0; kt < 8; ++kt) {
    if (kt < 6) STAGEQ(bq, kt + 2);
    i64x2 afv[4], bfv[4];
#pragma unroll
    for (int mi = 0; mi < 4; mi++) {
      int row = wm * 64 + mi * 16 + l;
      afv[mi] = *(const i64x2*)&bc[row * 64 + xg * 16];
    }
#pragma unroll
    for (int ni = 0; ni < 4; ni++) {
      int col = wn * 64 + ni * 16 + l;
      bfv[ni] = *(const i64x2*)&bc[8192 + col * 64 + xg * 16];
    }
    __builtin_amdgcn_s_setprio(1);
#pragma unroll
    for (int ks = 0; ks < 2; ++ks)
#pragma unroll
      for (int mi = 0; mi < 4; mi++)
#pragma unroll
        for (int ni = 0; ni < 4; ni++)
          acc[mi][ni] = __builtin_amdgcn_mfma_f32_16x16x32_fp8_fp8(
              afv[mi][ks], bfv[ni][ks], acc[mi][ni], 0, 0, 0);
    __builtin_amdgcn_s_setprio(0);
    asm volatile("s_waitcnt lgkmcnt(0)" ::: "memory");
    if (kt < 6)
      asm volatile("s_waitcnt vmcnt(3)" ::: "memory");
    else
      asm volatile("s_waitcnt vmcnt(0)" ::: "memory");
    __builtin_amdgcn_s_barrier();
    u8* t_ = bc; bc = bn; bn = bq; bq = t_;
  }
#undef STAGEQ

  u8* S8 = (u8*)&SB8[0][0];
  float bvs[4];
#pragma unroll
  for (int n = 0; n < 4; n++) bvs[n] = bias[bcol + wn * 64 + n * 16 + l];
#pragma unroll
  for (int m = 0; m < 4; m++) {
    int rl = wm * 64 + m * 16 + q * 4;
#pragma unroll
    for (int n = 0; n < 4; n++) {
      int pc = wn * 64 + permpos(n * 16 + l);
      float v0 = fmaxf(acc[m][n][0] * 9.765625e-4f + bvs[n], 0.f) * 16.f;
      float v1 = fmaxf(acc[m][n][1] * 9.765625e-4f + bvs[n], 0.f) * 16.f;
      float v2 = fmaxf(acc[m][n][2] * 9.765625e-4f + bvs[n], 0.f) * 16.f;
      float v3 = fmaxf(acc[m][n][3] * 9.765625e-4f + bvs[n], 0.f) * 16.f;
      unsigned p01 = cvt2fp8(v0, v1);
      unsigned p23 = cvt2fp8(v2, v3);
      S8[(rl + 0) * 264 + pc] = (u8)(p01 & 0xff);
      S8[(rl + 1) * 264 + pc] = (u8)(p01 >> 8);
      S8[(rl + 2) * 264 + pc] = (u8)(p23 & 0xff);
      S8[(rl + 3) * 264 + pc] = (u8)(p23 >> 8);
    }
  }
  __syncthreads();
  int row = tid >> 2, cc = tid & 3;
#pragma unroll
  for (int j = 0; j < 4; j++)
    *(u8x16*)&Cq[(size_t)(brow + row) * 3072 + bcol + cc * 64 + j * 16] =
        *(const u8x16*)&S8[row * 264 + cc * 64 + j * 16];
}

// ===== fused W2 + gated combine, fp8 (R14-proven: BM=64, BN=128, 960 blocks) =====
// launch_bounds MUST stay (256,2): (256,4) caps VGPR at 64 -> accumulator spill (R8).
__global__ __launch_bounds__(256, 2) void gemm_w2c(
    const u8* __restrict__ eh,       // [15360][3072] fp8 (x16), permuted
    const u8* __restrict__ W2q,      // [6][512 col][512 k] fp8 (x64), permuted
    const float* __restrict__ eb2,   // [6][512]
    const float* __restrict__ gates, // [(b*3+t)*30+c][6]
    u8* __restrict__ yq) {           // [3][15360][512] fp8 (x32), permuted
  int nwg = gridDim.x, cpx = nwg >> 3;
  int bid = blockIdx.x;
  int swz = (bid & 7) * cpx + (bid >> 3);
  int bx = swz >> 2, by = swz & 3;
  int brow = bx * 64, bcol = by * 128;

  __shared__ __align__(16) u8 SB8[3][12288];
  __shared__ u16 glds[64 * 18];

  int tid = threadIdx.x, lane = tid & 63, w = tid >> 6;
  int l = lane & 15, q = lane >> 4;

  for (int i = tid; i < 64 * 18; i += 256) {
    int r = i / 18, te = i % 18;
    int gr = brow + r, b = gr / CDIM, c = gr % CDIM;
    int t = te / 6, e = te % 6;
    glds[i] = f2bf(gates[((size_t)(b * TDIM + t) * CDIM + c) * EDIM + e]);
  }
  float b2all[2][6];
#pragma unroll
  for (int ni = 0; ni < 2; ni++) {
    int col = bcol + w * 32 + ni * 16 + l;
#pragma unroll
    for (int e = 0; e < 6; e++) b2all[ni][e] = eb2[e * 512 + col];
  }

  int srow = tid >> 2, sc = tid & 3;
  int scX = sc ^ ((srow >> 1) & 3);
  const u8* Ag = eh + (size_t)(brow + srow) * 3072 + scX * 16;
  const u8* Bg0 = W2q + (size_t)(bcol + srow) * 512 + scX * 16;
  const u8* Bg1 = Bg0 + (size_t)64 * 512;
  int lo = w * 1024;

#define STAGEW(buf, s2)                                                   \
  do {                                                                    \
    int _e2 = (s2) >> 3, _k2 = (s2) & 7;                                  \
    gload16(Ag + _e2 * 512 + _k2 * 64, (buf) + lo);                       \
    gload16(Bg0 + (size_t)_e2 * 262144 + _k2 * 64, (buf) + 4096 + lo);    \
    gload16(Bg1 + (size_t)_e2 * 262144 + _k2 * 64, (buf) + 8192 + lo);    \
  } while (0)

  f32x4 P[4][2], aY0[4][2], aY1[4][2], aY2[4][2];
#pragma unroll
  for (int mi = 0; mi < 4; mi++)
#pragma unroll
    for (int ni = 0; ni < 2; ni++) {
      P[mi][ni][0] = P[mi][ni][1] = P[mi][ni][2] = P[mi][ni][3] = 0.f;
      aY0[mi][ni] = P[mi][ni]; aY1[mi][ni] = P[mi][ni]; aY2[mi][ni] = P[mi][ni];
    }

  int xg = q ^ ((l >> 1) & 3);

  STAGEW(SB8[0], 0);
  STAGEW(SB8[1], 1);
  asm volatile("s_waitcnt vmcnt(3)" ::: "memory");
  __builtin_amdgcn_s_barrier();

  u8 *bc = SB8[0], *bn = SB8[1], *bq = SB8[2];
  for (int e = 0; e < 6; ++e) {
#pragma unroll
    for (int kt = 0; kt < 8; ++kt) {
      int s = e * 8 + kt;
      if (s < 46) STAGEW(bq, s + 2);
      i64x2 bfv[2], afv[4];
#pragma unroll
      for (int ni = 0; ni < 2; ni++) {
        int col = w * 32 + ni * 16 + l;
        bfv[ni] = *(const i64x2*)&bc[4096 + col * 64 + xg * 16];
      }
#pragma unroll
      for (int mi = 0; mi < 4; mi++) {
        int row = mi * 16 + l;
        afv[mi] = *(const i64x2*)&bc[row * 64 + xg * 16];
      }
      __builtin_amdgcn_s_setprio(1);
#pragma unroll
      for (int ks = 0; ks < 2; ++ks)
#pragma unroll
        for (int mi = 0; mi < 4; mi++)
#pragma unroll
          for (int ni = 0; ni < 2; ni++)
            P[mi][ni] = __builtin_amdgcn_mfma_f32_16x16x32_fp8_fp8(
                afv[mi][ks], bfv[ni][ks], P[mi][ni], 0, 0, 0);
      __builtin_amdgcn_s_setprio(0);
      asm volatile("s_waitcnt lgkmcnt(0)" ::: "memory");
      if (s < 46)
        asm volatile("s_waitcnt vmcnt(3)" ::: "memory");
      else
        asm volatile("s_waitcnt vmcnt(0)" ::: "memory");
      __builtin_amdgcn_s_barrier();
      u8* t_ = bc; bc = bn; bn = bq; bq = t_;
    }
#pragma unroll
    for (int mi = 0; mi < 4; mi++) {
#pragma unroll
      for (int rr = 0; rr < 4; rr++) {
        int row = mi * 16 + q * 4 + rr;
        float g0 = bf2f(glds[row * 18 + e]);
        float g1 = bf2f(glds[row * 18 + 6 + e]);
        float g2 = bf2f(glds[row * 18 + 12 + e]);
#pragma unroll
        for (int ni = 0; ni < 2; ni++) {
          float p = P[mi][ni][rr] * 9.765625e-4f + b2all[ni][e];
          aY0[mi][ni][rr] += g0 * p;
          aY1[mi][ni][rr] += g1 * p;
          aY2[mi][ni][rr] += g2 * p;
          P[mi][ni][rr] = 0.f;
        }
      }
    }
  }
#undef STAGEW

  u8* S8 = (u8*)&SB8[0][0];
#define EPI(AY, t)                                                          \
  do {                                                                      \
    _Pragma("unroll") for (int mi = 0; mi < 4; mi++) {                      \
      int rl = mi * 16 + q * 4;                                             \
      _Pragma("unroll") for (int ni = 0; ni < 2; ni++) {                    \
        int colL = w * 32 + ni * 16 + l;                                    \
        int pc = (colL & 64) + permpos(colL & 63);                          \
        unsigned p01 = cvt2fp8(AY[mi][ni][0] * 32.f, AY[mi][ni][1] * 32.f); \
        unsigned p23 = cvt2fp8(AY[mi][ni][2] * 32.f, AY[mi][ni][3] * 32.f); \
        S8[(rl + 0) * 144 + pc] = (u8)(p01 & 0xff);                         \
        S8[(rl + 1) * 144 + pc] = (u8)(p01 >> 8);                          \
        S8[(rl + 2) * 144 + pc] = (u8)(p23 & 0xff);                         \
        S8[(rl + 3) * 144 + pc] = (u8)(p23 >> 8);                          \
      }                                                                     \
    }                                                                       \
    __syncthreads();                                                        \
    {                                                                       \
      int row_ = tid >> 2, cc_ = tid & 3;                                   \
      _Pragma("unroll") for (int j = 0; j < 2; j++)                         \
        *(u8x16*)&yq[((size_t)(t) * NROWS + brow + row_) * 512 + bcol +     \
                     j * 64 + cc_ * 16] =                                   \
            *(const u8x16*)&S8[row_ * 144 + j * 64 + cc_ * 16];             \
    }                                                                       \
    __syncthreads();                                                        \
  } while (0)
  EPI(aY0, 0);
  EPI(aY1, 1);
  EPI(aY2, 2);
#undef EPI
}

// ===== tower fp8: th = relu(yq@tw1q/2048 + tb1); logits += th . tw2 =====
__global__ __launch_bounds__(256, 2) void gemm_tower(
    const u8* __restrict__ yq,
    const u8* __restrict__ tw1q,
    const float* __restrict__ tb1, const float* __restrict__ tw2,
    float* __restrict__ logits) {
  int t = blockIdx.z;
  const u8* A = yq + (size_t)t * NROWS * 512;
  const u8* BT = tw1q + (size_t)t * 262144;

  int nwg = gridDim.x, cpx = nwg >> 3;
  int bid = blockIdx.x;
  int swz = (bid & 7) * cpx + (bid >> 3);
  int bx = swz >> 2, by = swz & 3;
  int brow = bx * 64, bcol = by * 128;

  __shared__ __align__(16) u8 SB8[3][12288];

  int tid = threadIdx.x, lane = tid & 63, w = tid >> 6;
  int l = lane & 15, q = lane >> 4;

  int srow = tid >> 2, sc = tid & 3;
  int scX = sc ^ ((srow >> 1) & 3);
  const u8* Ag = A + (size_t)(brow + srow) * 512 + scX * 16;
  const u8* Bg0 = BT + (size_t)(bcol + srow) * 512 + scX * 16;
  const u8* Bg1 = Bg0 + (size_t)64 * 512;
  int lo = w * 1024;

#define STAGET(buf, kt)                                \
  do {                                                 \
    gload16(Ag + (kt) * 64, (buf) + lo);               \
    gload16(Bg0 + (kt) * 64, (buf) + 4096 + lo);       \
    gload16(Bg1 + (kt) * 64, (buf) + 8192 + lo);       \
  } while (0)

  f32x4 P[4][2];
#pragma unroll
  for (int mi = 0; mi < 4; mi++)
#pragma unroll
    for (int ni = 0; ni < 2; ni++) {
      P[mi][ni][0] = 0.f; P[mi][ni][1] = 0.f; P[mi][ni][2] = 0.f; P[mi][ni][3] = 0.f;
    }

  int xg = q ^ ((l >> 1) & 3);

  STAGET(SB8[0], 0);
  STAGET(SB8[1], 1);
  asm volatile("s_waitcnt vmcnt(3)" ::: "memory");
  __builtin_amdgcn_s_barrier();

  u8 *bc = SB8[0], *bn = SB8[1], *bq = SB8[2];
#pragma unroll
  for (int kt = 0; kt < 8; ++kt) {
    if (kt < 6) STAGET(bq, kt + 2);
    i64x2 bfv[2], afv[4];
#pragma unroll
    for (int ni = 0; ni < 2; ni++) {
      int col = w * 32 + ni * 16 + l;
      bfv[ni] = *(const i64x2*)&bc[4096 + col * 64 + xg * 16];
    }
#pragma unroll
    for (int mi = 0; mi < 4; mi++) {
      int row = mi * 16 + l;
      afv[mi] = *(const i64x2*)&bc[row * 64 + xg * 16];
    }
    __builtin_amdgcn_s_setprio(1);
#pragma unroll
    for (int ks = 0; ks < 2; ++ks)
#pragma unroll
      for (int mi = 0; mi < 4; mi++)
#pragma unroll
        for (int ni = 0; ni < 2; ni++)
          P[mi][ni] = __builtin_amdgcn_mfma_f32_16x16x32_fp8_fp8(
              afv[mi][ks], bfv[ni][ks], P[mi][ni], 0, 0, 0);
    __builtin_amdgcn_s_setprio(0);
    asm volatile("s_waitcnt lgkmcnt(0)" ::: "memory");
    if (kt < 6)
      asm volatile("s_waitcnt vmcnt(3)" ::: "memory");
    else
      asm volatile("s_waitcnt vmcnt(0)" ::: "memory");
    __builtin_amdgcn_s_barrier();
    u8* t_ = bc; bc = bn; bn = bq; bq = t_;
  }
#undef STAGET

  float bvs[2], tws[2];
#pragma unroll
  for (int ni = 0; ni < 2; ni++) {
    int col = bcol + w * 32 + ni * 16 + l;
    bvs[ni] = tb1[t * 512 + col];
    tws[ni] = tw2[t * 512 + col];
  }
#pragma unroll
  for (int mi = 0; mi < 4; mi++) {
#pragma unroll
    for (int rr = 0; rr < 4; rr++) {
      float s = 0.f;
#pragma unroll
      for (int ni = 0; ni < 2; ni++) {
        float v = P[mi][ni][rr] * 4.8828125e-4f + bvs[ni];
        v = fmaxf(v, 0.f);
        s += v * tws[ni];
      }
      s += __shfl_xor(s, 1, 64);
      s += __shfl_xor(s, 2, 64);
      s += __shfl_xor(s, 4, 64);
      s += __shfl_xor(s, 8, 64);
      if (l == 0) {
        int row = brow + mi * 16 + q * 4 + rr;
        int b = row / CDIM, c = row % CDIM;
        atomicAdd(&logits[(size_t)(b * TDIM + t) * CDIM + c], s);
      }
    }
  }
}

// ---------------- loss: one wave per b ----------------
__global__ __launch_bounds__(64) void loss_kernel(const float* __restrict__ scores,
                                                  const float* __restrict__ logits,
                                                  const float* __restrict__ gates,
                                                  const float* __restrict__ tb2,
                                                  float* __restrict__ out) {
  int b = blockIdx.x;
  int lane = threadIdx.x;
  float bce_sum = 0.f;
  float aux = 0.f;
  for (int t = 0; t < 3; t++) {
    float sc = (lane < CDIM) ? scores[(size_t)(b * TDIM + t) * CDIM + lane] : -1e30f;
    float mx = sc;
    for (int off = 32; off; off >>= 1) mx = fmaxf(mx, __shfl_xor(mx, off, 64));
    float lab = (lane < CDIM && sc == mx) ? 1.f : 0.f;
    float lg = (lane < CDIM) ? (logits[(size_t)(b * TDIM + t) * CDIM + lane] + tb2[t]) : 0.f;
    float bce = (lane < CDIM) ? (fmaxf(lg, 0.f) - lg * lab + log1pf(expf(-fabsf(lg)))) : 0.f;
    for (int off = 32; off; off >>= 1) bce += __shfl_xor(bce, off, 64);
    bce_sum += bce / (float)CDIM;

    float impv[6];
    float meansum = 0.f;
#pragma unroll
    for (int e = 0; e < 6; e++) {
      float gsum = (lane < CDIM) ? gates[(size_t)((b * TDIM + t) * CDIM + lane) * EDIM + e] : 0.f;
      for (int off = 32; off; off >>= 1) gsum += __shfl_xor(gsum, off, 64);
      impv[e] = gsum;
      meansum += gsum;
    }
    float mean = meansum / 6.f;
    float var = 0.f;
#pragma unroll
    for (int e = 0; e < 6; e++) { float d = impv[e] - mean; var += d * d; }
    var /= 6.f;
    aux += var / (mean * mean + 1e-10f);
  }
  float res = bce_sum / 3.f + 0.01f * aux;
  if (lane == 0) atomicAdd(out, res / (float)BDIM);
}

// ---------------- host ----------------
extern "C" void kernel_launch(void* const* d_in, const int* in_sizes, int n_in,
                              void* d_out, int out_size, void* d_ws, size_t ws_size,
                              hipStream_t stream) {
  const float* X = (const float*)d_in[0];
  const float* scores = (const float*)d_in[1];
  const float* fc1_w = (const float*)d_in[2];
  const float* fc1_b = (const float*)d_in[3];
  const float* fc2_w = (const float*)d_in[4];
  const float* fc2_b = (const float*)d_in[5];
  const float* w_gate = (const float*)d_in[6];
  const float* ew1 = (const float*)d_in[7];
  const float* eb1 = (const float*)d_in[8];
  const float* ew2 = (const float*)d_in[9];
  const float* eb2 = (const float*)d_in[10];
  const float* tw1 = (const float*)d_in[11];
  const float* tb1 = (const float*)d_in[12];
  const float* tw2 = (const float*)d_in[13];
  const float* tb2 = (const float*)d_in[14];
  float* out = (float*)d_out;

  // workspace layout (all disjoint)
  u8* fc1q = (u8*)d_ws;                          // 262144
  u8* fc2q = fc1q + 262144;                      // 262144
  u8* w1q = fc2q + 262144;                       // 6*262144
  u8* w2q = w1q + (size_t)6 * 262144;            // 6*262144
  u8* tw1q = w2q + (size_t)6 * 262144;           // 3*262144
  u8* wgq = tw1q + (size_t)3 * 262144;           // 32*512
  u8* Xq = wgq + (size_t)32 * 512;               // [15360][512]
  u8* A1q = Xq + (size_t)NROWS * 512;            // [15360][512]
  u8* hq = A1q + (size_t)NROWS * 512;            // [15360][512]
  u8* ehq = hq + (size_t)NROWS * 512;            // [15360][3072]
  u8* yq = ehq + (size_t)NROWS * 3072;           // [3][15360][512]
  float* gates = (float*)(yq + (size_t)TDIM * NROWS * 512);
  float* logits = gates + (size_t)BDIM * TDIM * CDIM * EDIM;

  hipMemsetAsync(d_out, 0, sizeof(float) * out_size, stream);

  // merged prep: X -> fp8, all weights + gate weights -> fp8, zero logits
  prep_kernel<<<5005, 256, 0, stream>>>(X, Xq, fc1_w, fc2_w, ew1, ew2, tw1,
                                        fc1q, fc2q, w1q, w2q, tw1q, w_gate, wgq, logits);

  // shared bottom fp8 (960 blocks of 64x128, 8 K-steps)
  gemm_s8<1><<<dim3(960), 256, 0, stream>>>(Xq, fc1q, fc1_b, A1q);   // relu
  gemm_s8<0><<<dim3(960), 256, 0, stream>>>(A1q, fc2q, fc2_b, hq);   // no relu

  // gating fp8 (240 blocks)
  gate_kernel<<<240, 256, 0, stream>>>(hq, wgq, gates);

  // experts W1 fp8: merged N=3072 (1440 blocks of 128x256, 8 K-steps) -> ehq
  gemm256q<<<dim3(1440), 512, 0, stream>>>(hq, w1q, eb1, ehq, 12);

  // experts W2 + gated combine, fp8 (960 blocks of 64x128, 48 K-steps) -> yq
  gemm_w2c<<<dim3(960), 256, 0, stream>>>(ehq, w2q, eb2, gates, yq);

  // towers fp8 (960 x 3 blocks of 64x128, 8 K-steps) -> logits (atomic)
  gemm_tower<<<dim3(960, 1, 3), 256, 0, stream>>>(yq, tw1q, tb1, tw2, logits);

  // loss
  loss_kernel<<<BDIM, 64, 0, stream>>>(scores, logits, gates, tb2, out);
}